// Round 6
// baseline (2221.506 us; speedup 1.0000x reference)
//
#include <hip/hip_runtime.h>
#include <hip/hip_bf16.h>
#include <math.h>

// Problem constants
#define BB 2
#define TT 4096
#define DM 1024
#define DSTATE 128
#define DI 2048
#define HD 64
#define NH 32
#define DIP 4384   // 2*DI + 2*DSTATE + NH
#define CD 2304    // DI + 2*DSTATE

// Chunked scan parameters
#define NC 8
#define CL 512
#define SELEMS ((size_t)BB * NH * HD * DSTATE)   // 524288

#define NP1 4480   // DIP padded to multiple of 128 for MFMA staging

typedef __attribute__((ext_vector_type(8))) short bf16x8;
typedef __attribute__((ext_vector_type(4))) float f32x4;

__device__ inline void gload16(const void* g, void* l) {
    __builtin_amdgcn_global_load_lds(
        (const __attribute__((address_space(1))) void*)g,
        (__attribute__((address_space(3))) void*)l, 16, 0, 0);
}

// ---------------- Kernel 1: LayerNorm statistics ----------------
__global__ __launch_bounds__(64) void ln_stats_kernel(const float* __restrict__ x,
                                                      float* __restrict__ mu,
                                                      float* __restrict__ rs) {
    int t = blockIdx.x * 64 + threadIdx.x;
    int b = blockIdx.y;
    const float* xb = x + (size_t)b * DM * TT + t;
    float s = 0.f, ss = 0.f;
#pragma unroll 8
    for (int d = 0; d < DM; d++) {
        float v = xb[(size_t)d * TT];
        s += v;
        ss += v * v;
    }
    float m = s * (1.f / DM);
    float var = ss * (1.f / DM) - m * m;
    int idx = b * TT + t;
    mu[idx] = m;
    rs[idx] = rsqrtf(var + 1e-5f);
}

// ---------------- Kernel 1b: xn = LN(x) transposed to (m, k) in bf16 ----------------
__global__ __launch_bounds__(256) void xn_kernel(const float* __restrict__ x,
                                                 const float* __restrict__ mu,
                                                 const float* __restrict__ rs,
                                                 const float* __restrict__ ln_w,
                                                 const float* __restrict__ ln_b,
                                                 __hip_bfloat16* __restrict__ xn) {
    __shared__ float tile[64][65];
    int tid = threadIdx.x;
    int t0 = blockIdx.x * 64, d0 = blockIdx.y * 64, b = blockIdx.z;
#pragma unroll
    for (int i = 0; i < 64; i += 4) {
        int dl = i + (tid >> 6);
        tile[dl][tid & 63] = x[(size_t)b * DM * TT + (size_t)(d0 + dl) * TT + t0 + (tid & 63)];
    }
    __syncthreads();
#pragma unroll
    for (int i = 0; i < 64; i += 8) {
        int tl = i + (tid >> 5);
        int kk = (tid & 31) * 2;
        int m = b * TT + t0 + tl;
        float mu_m = mu[m], rs_m = rs[m];
        float v0 = (tile[kk][tl] - mu_m) * rs_m * ln_w[d0 + kk] + ln_b[d0 + kk];
        float v1 = (tile[kk + 1][tl] - mu_m) * rs_m * ln_w[d0 + kk + 1] + ln_b[d0 + kk + 1];
        __hip_bfloat162 pk;
        pk.x = __float2bfloat16(v0);
        pk.y = __float2bfloat16(v1);
        *(__hip_bfloat162*)(xn + (size_t)m * DM + d0 + kk) = pk;
    }
}

// ---------------- convert f32 -> bf16 with zero-padding ----------------
__global__ __launch_bounds__(256) void cvt_pad_kernel(const float* __restrict__ src,
                                                      __hip_bfloat16* __restrict__ dst,
                                                      int src_n, int tot_n) {
    int i = (blockIdx.x * 256 + threadIdx.x) * 4;
    if (i >= tot_n) return;
    float4 v = (i < src_n) ? *(const float4*)(src + i) : make_float4(0.f, 0.f, 0.f, 0.f);
    __hip_bfloat162 p0, p1;
    p0.x = __float2bfloat16(v.x); p0.y = __float2bfloat16(v.y);
    p1.x = __float2bfloat16(v.z); p1.y = __float2bfloat16(v.w);
    *(__hip_bfloat162*)(dst + i) = p0;
    *(__hip_bfloat162*)(dst + i + 2) = p1;
}

// ---------------- Kernel 2: GEMM1 bf16 MFMA ----------------
__global__ __launch_bounds__(256) void gemm1_mfma(const __hip_bfloat16* __restrict__ Wb,
                                                  const __hip_bfloat16* __restrict__ xn,
                                                  float* __restrict__ zx) {
    __shared__ short As[128][64];
    __shared__ short Bs[128][64];
    int tid = threadIdx.x;
    int lane = tid & 63;
    int wave = tid >> 6;
    int wr = wave >> 1, wc = wave & 1;
    int j0 = blockIdx.x * 128;
    int m0 = blockIdx.y * 128;
    int srow = tid >> 3;
    int skc = (tid & 7) * 8;

    f32x4 acc[4][4] = {};

    for (int k0 = 0; k0 < DM; k0 += 64) {
        __syncthreads();
#pragma unroll
        for (int q = 0; q < 4; q++) {
            gload16(Wb + (size_t)(j0 + q * 32 + srow) * DM + k0 + skc,
                    ((short*)As) + q * 2048 + wave * 512);
            gload16(xn + (size_t)(m0 + q * 32 + srow) * DM + k0 + skc,
                    ((short*)Bs) + q * 2048 + wave * 512);
        }
        asm volatile("s_waitcnt vmcnt(0)" ::: "memory");
        __syncthreads();
#pragma unroll
        for (int ks = 0; ks < 2; ks++) {
            bf16x8 af[4], bfr[4];
#pragma unroll
            for (int i = 0; i < 4; i++)
                af[i] = *(const bf16x8*)&As[wr * 64 + i * 16 + (lane & 15)][ks * 32 + (lane >> 4) * 8];
#pragma unroll
            for (int n = 0; n < 4; n++)
                bfr[n] = *(const bf16x8*)&Bs[wc * 64 + n * 16 + (lane & 15)][ks * 32 + (lane >> 4) * 8];
#pragma unroll
            for (int i = 0; i < 4; i++)
#pragma unroll
                for (int n = 0; n < 4; n++)
                    acc[i][n] = __builtin_amdgcn_mfma_f32_16x16x32_bf16(af[i], bfr[n], acc[i][n], 0, 0, 0);
        }
    }
#pragma unroll
    for (int i = 0; i < 4; i++) {
        int j = j0 + wr * 64 + i * 16 + ((lane >> 4) << 2);
        if (j < DIP) {
#pragma unroll
            for (int n = 0; n < 4; n++) {
                int m = m0 + wc * 64 + n * 16 + (lane & 15);
                *(f32x4*)(zx + (size_t)m * DIP + j) = acc[i][n];
            }
        }
    }
}

// ---------------- Kernel 2b: f32 strip GEMM for dt columns ----------------
__global__ __launch_bounds__(256) void gemm1_kernel(const float* __restrict__ x,
                                                    const float* __restrict__ mu,
                                                    const float* __restrict__ rs,
                                                    const float* __restrict__ ln_w,
                                                    const float* __restrict__ ln_b,
                                                    const float* __restrict__ Win,
                                                    float* __restrict__ zx,
                                                    int jbase) {
    __shared__ float As[16][64];
    __shared__ float Ws[64][17];
    int tid = threadIdx.x;
    int tx = tid & 15;
    int ty = tid >> 4;
    int j0 = jbase + blockIdx.x * 64;
    int m0 = blockIdx.y * 64;
    int b = m0 >> 12;
    int t0 = m0 & 4095;
    const float* Xb = x + (size_t)b * DM * TT + t0;

    int lr = tid >> 4;
    int lc = (tid & 15) * 4;
    int wr = tid >> 2;
    int wc = (tid & 3) * 4;

    float acc[4][4] = {};
    for (int k0 = 0; k0 < DM; k0 += 16) {
        float4 xv = *(const float4*)(Xb + (size_t)(k0 + lr) * TT + lc);
        float4 muv = *(const float4*)(&mu[m0 + lc]);
        float4 rsv = *(const float4*)(&rs[m0 + lc]);
        float lw = ln_w[k0 + lr], lb = ln_b[k0 + lr];
        As[lr][lc]     = (xv.x - muv.x) * rsv.x * lw + lb;
        As[lr][lc + 1] = (xv.y - muv.y) * rsv.y * lw + lb;
        As[lr][lc + 2] = (xv.z - muv.z) * rsv.z * lw + lb;
        As[lr][lc + 3] = (xv.w - muv.w) * rsv.w * lw + lb;

        int j = j0 + wr;
        float4 wv = make_float4(0.f, 0.f, 0.f, 0.f);
        if (j < DIP) wv = *(const float4*)(Win + (size_t)j * DM + k0 + wc);
        Ws[wr][wc] = wv.x; Ws[wr][wc + 1] = wv.y; Ws[wr][wc + 2] = wv.z; Ws[wr][wc + 3] = wv.w;
        __syncthreads();
#pragma unroll
        for (int kk = 0; kk < 16; kk++) {
            float4 a4 = *(const float4*)&As[kk][ty * 4];
            float a[4] = {a4.x, a4.y, a4.z, a4.w};
            float bv[4];
#pragma unroll
            for (int n = 0; n < 4; n++) bv[n] = Ws[tx * 4 + n][kk];
#pragma unroll
            for (int i = 0; i < 4; i++)
#pragma unroll
                for (int n = 0; n < 4; n++)
                    acc[i][n] = fmaf(a[i], bv[n], acc[i][n]);
        }
        __syncthreads();
    }
#pragma unroll
    for (int i = 0; i < 4; i++) {
        int m = m0 + ty * 4 + i;
        int j = j0 + tx * 4;
        if (j < DIP) {
            float4 v = make_float4(acc[i][0], acc[i][1], acc[i][2], acc[i][3]);
            *(float4*)(zx + (size_t)m * DIP + j) = v;
        }
    }
}

// ---------------- Kernel 3: causal depthwise conv(4) + SiLU ----------------
__global__ __launch_bounds__(256) void conv_kernel(const float* __restrict__ zx,
                                                   const float* __restrict__ cw,
                                                   const float* __restrict__ cb,
                                                   float* __restrict__ xBC) {
    int i = blockIdx.x * 256 + threadIdx.x;
    int c = i % CD;
    int t = (i / CD) & (TT - 1);
    int b = i / (CD * TT);
    const float* src = zx + (size_t)b * TT * DIP + DI + c;
    float acc = cb[c];
#pragma unroll
    for (int k = 0; k < 4; k++) {
        int ts = t - 3 + k;
        if (ts >= 0) acc = fmaf(cw[c * 4 + k], src[(size_t)ts * DIP], acc);
    }
    float sg = 1.f / (1.f + expf(-acc));
    xBC[(size_t)i] = acc * sg;
}

// ---------------- Kernel 4: dt softplus + dA ----------------
__global__ __launch_bounds__(256) void dt_kernel(const float* __restrict__ zx,
                                                 const float* __restrict__ dt_bias,
                                                 const float* __restrict__ A_log,
                                                 float* __restrict__ dtv,
                                                 float* __restrict__ dAb) {
    int i = blockIdx.x * 256 + threadIdx.x;
    int hh = i & (NH - 1);
    int m = i >> 5;
    float raw = zx[(size_t)m * DIP + (DI + CD) + hh] + dt_bias[hh];
    float dt = (raw > 20.f) ? raw : log1pf(expf(raw));
    float dA = expf(-expf(A_log[hh]) * dt);
    dtv[i] = dt;
    dAb[i] = dA;
}

// ---------------- Kernel 5a: chunk reduce (lane = p, h[128] in registers) ----------------
// Block = (chunk, head, batch), 1 wave. B row (512B) broadcast via LDS.
__global__ __launch_bounds__(64, 1) void scan_reduce_kernel(const float* __restrict__ xBC,
                                                            const float* __restrict__ dAb,
                                                            const float* __restrict__ dtg,
                                                            float* __restrict__ S,
                                                            float* __restrict__ P) {
    int lane = threadIdx.x;
    int c = blockIdx.x, hh = blockIdx.y, b = blockIdx.z;
    int p = lane;
    int tbeg = c * CL, tend = tbeg + CL;

    __shared__ alignas(16) float lb[128];
    float h[128];
#pragma unroll
    for (int i = 0; i < 128; i++) h[i] = 0.f;
    float cd = 1.f;

    const float* base = xBC + (size_t)b * TT * CD;
    const float* dab = dAb + (size_t)b * TT * NH + hh;
    const float* dtb = dtg + (size_t)b * TT * NH + hh;

    const float* r0 = base + (size_t)tbeg * CD;
    float2 rB = *(const float2*)(r0 + DI + lane * 2);
    float xv = r0[hh * HD + p];
    float dav = dab[(size_t)tbeg * NH];
    float dtv_ = dtb[(size_t)tbeg * NH];

    for (int t = tbeg; t < tend; t++) {
        *(float2*)&lb[lane * 2] = rB;

        int tn = (t + 1 < tend) ? (t + 1) : t;
        const float* rn = base + (size_t)tn * CD;
        float2 nB = *(const float2*)(rn + DI + lane * 2);
        float nx = rn[hh * HD + p];
        float nda = dab[(size_t)tn * NH];
        float ndt = dtb[(size_t)tn * NH];

        float xdt = xv * dtv_;
#pragma unroll
        for (int g = 0; g < 32; g++) {
            float4 Bv = *(float4*)&lb[4 * g];
            h[4 * g + 0] = fmaf(h[4 * g + 0], dav, xdt * Bv.x);
            h[4 * g + 1] = fmaf(h[4 * g + 1], dav, xdt * Bv.y);
            h[4 * g + 2] = fmaf(h[4 * g + 2], dav, xdt * Bv.z);
            h[4 * g + 3] = fmaf(h[4 * g + 3], dav, xdt * Bv.w);
        }
        cd *= dav;

        rB = nB; xv = nx; dav = nda; dtv_ = ndt;
    }

    float* Sp = S + (size_t)c * SELEMS + (((size_t)(b * NH + hh) * HD + p) * DSTATE);
#pragma unroll
    for (int g = 0; g < 32; g++)
        *(float4*)(Sp + 4 * g) = make_float4(h[4 * g], h[4 * g + 1], h[4 * g + 2], h[4 * g + 3]);
    if (lane == 0) P[(c * BB + b) * NH + hh] = cd;
}

// ---------------- Kernel 5b: sequential chunk combine ----------------
__global__ __launch_bounds__(256) void scan_combine_kernel(const float* __restrict__ h0,
                                                           const float* __restrict__ P,
                                                           float* __restrict__ S,
                                                           float* __restrict__ hT) {
    size_t tid = (size_t)blockIdx.x * 256 + threadIdx.x;
    int hh = (int)((tid >> 13) & 31);
    int b = (int)(tid >> 18);
    float h = h0[tid];
#pragma unroll
    for (int c = 0; c < NC; c++) {
        float s = S[(size_t)c * SELEMS + tid];
        S[(size_t)c * SELEMS + tid] = h;
        h = fmaf(P[(c * BB + b) * NH + hh], h, s);
    }
    hT[tid] = h;
}

// ---------------- Kernel 5c: chunk emit (lane = p, h[128] in registers) ----------------
// B||C row (1KB) broadcast via LDS; y store coalesced 256B/wave into zx cols [2048,4096).
__global__ __launch_bounds__(64, 1) void scan_emit_kernel(const float* __restrict__ xBC,
                                                          const float* __restrict__ dAb,
                                                          const float* __restrict__ dtg,
                                                          const float* __restrict__ S,
                                                          const float* __restrict__ Dp,
                                                          float* __restrict__ zx) {
    int lane = threadIdx.x;
    int c = blockIdx.x, hh = blockIdx.y, b = blockIdx.z;
    int p = lane;
    int tbeg = c * CL, tend = tbeg + CL;

    __shared__ alignas(16) float lb[256];
    float h[128];
    const float* Sp = S + (size_t)c * SELEMS + (((size_t)(b * NH + hh) * HD + p) * DSTATE);
#pragma unroll
    for (int g = 0; g < 32; g++) {
        float4 v = *(const float4*)(Sp + 4 * g);
        h[4 * g + 0] = v.x; h[4 * g + 1] = v.y; h[4 * g + 2] = v.z; h[4 * g + 3] = v.w;
    }

    float Dh = Dp[hh];
    const float* base = xBC + (size_t)b * TT * CD;
    const float* dab = dAb + (size_t)b * TT * NH + hh;
    const float* dtb = dtg + (size_t)b * TT * NH + hh;
    float* yb = zx + (size_t)b * TT * DIP + DI + hh * HD + p;

    const float* r0 = base + (size_t)tbeg * CD;
    float4 rBC = *(const float4*)(r0 + DI + lane * 4);
    float xv = r0[hh * HD + p];
    float dav = dab[(size_t)tbeg * NH];
    float dtv_ = dtb[(size_t)tbeg * NH];

    for (int t = tbeg; t < tend; t++) {
        *(float4*)&lb[lane * 4] = rBC;

        int tn = (t + 1 < tend) ? (t + 1) : t;
        const float* rn = base + (size_t)tn * CD;
        float4 nBC = *(const float4*)(rn + DI + lane * 4);
        float nx = rn[hh * HD + p];
        float nda = dab[(size_t)tn * NH];
        float ndt = dtb[(size_t)tn * NH];

        float xdt = xv * dtv_;
        float ps0 = 0.f, ps1 = 0.f, ps2 = 0.f, ps3 = 0.f;
#pragma unroll
        for (int g = 0; g < 32; g++) {
            float4 Bv = *(float4*)&lb[4 * g];
            float4 Cv = *(float4*)&lb[128 + 4 * g];
            float h0v = fmaf(h[4 * g + 0], dav, xdt * Bv.x); h[4 * g + 0] = h0v; ps0 = fmaf(h0v, Cv.x, ps0);
            float h1v = fmaf(h[4 * g + 1], dav, xdt * Bv.y); h[4 * g + 1] = h1v; ps1 = fmaf(h1v, Cv.y, ps1);
            float h2v = fmaf(h[4 * g + 2], dav, xdt * Bv.z); h[4 * g + 2] = h2v; ps2 = fmaf(h2v, Cv.z, ps2);
            float h3v = fmaf(h[4 * g + 3], dav, xdt * Bv.w); h[4 * g + 3] = h3v; ps3 = fmaf(h3v, Cv.w, ps3);
        }
        float ps = (ps0 + ps1) + (ps2 + ps3);
        yb[(size_t)t * DIP] = ps + Dh * xv;

        rBC = nBC; xv = nx; dav = nda; dtv_ = ndt;
    }
}

// ---------------- Kernel 6: gating + RMSNorm -> bf16 g ----------------
__global__ __launch_bounds__(256) void gate_rms_kernel(const float* __restrict__ zx,
                                                       const float* __restrict__ rw,
                                                       __hip_bfloat16* __restrict__ gq) {
    int m = blockIdx.x;
    int tid = threadIdx.x;
    const float* yr = zx + (size_t)m * DIP + DI;
    const float* zr = zx + (size_t)m * DIP;
    int base = tid * 8;
    float gv[8];
    float ss = 0.f;
    float4 ya = *(const float4*)(yr + base);
    float4 yb4 = *(const float4*)(yr + base + 4);
    float4 za = *(const float4*)(zr + base);
    float4 zb4 = *(const float4*)(zr + base + 4);
    float yv[8] = {ya.x, ya.y, ya.z, ya.w, yb4.x, yb4.y, yb4.z, yb4.w};
    float zv[8] = {za.x, za.y, za.z, za.w, zb4.x, zb4.y, zb4.z, zb4.w};
#pragma unroll
    for (int i = 0; i < 8; i++) {
        float sg = 1.f / (1.f + expf(-zv[i]));
        float gg = yv[i] * zv[i] * sg;
        gv[i] = gg;
        ss += gg * gg;
    }
#pragma unroll
    for (int off = 1; off < 64; off <<= 1) ss += __shfl_xor(ss, off);
    __shared__ float red[4];
    int w = tid >> 6;
    if ((tid & 63) == 0) red[w] = ss;
    __syncthreads();
    float tot = red[0] + red[1] + red[2] + red[3];
    float r = rsqrtf(tot * (1.f / DI) + 1e-5f);
#pragma unroll
    for (int i = 0; i < 8; i += 2) {
        __hip_bfloat162 p;
        p.x = __float2bfloat16(gv[i] * r * rw[base + i]);
        p.y = __float2bfloat16(gv[i + 1] * r * rw[base + i + 1]);
        *(__hip_bfloat162*)(gq + (size_t)m * DI + base + i) = p;
    }
}

// ---------------- Kernel 7: GEMM2 bf16 MFMA (transposed store) ----------------
__global__ __launch_bounds__(256) void gemm2_mfma(const __hip_bfloat16* __restrict__ gq,
                                                  const __hip_bfloat16* __restrict__ Wob,
                                                  float* __restrict__ out) {
    __shared__ short As[128][64];
    __shared__ short Bs[128][64];
    int tid = threadIdx.x;
    int lane = tid & 63;
    int wave = tid >> 6;
    int wr = wave >> 1, wc = wave & 1;
    int m0 = blockIdx.x * 128;
    int j0 = blockIdx.y * 128;
    int srow = tid >> 3;
    int skc = (tid & 7) * 8;

    f32x4 acc[4][4] = {};

    for (int k0 = 0; k0 < DI; k0 += 64) {
        __syncthreads();
#pragma unroll
        for (int q = 0; q < 4; q++) {
            gload16(gq + (size_t)(m0 + q * 32 + srow) * DI + k0 + skc,
                    ((short*)As) + q * 2048 + wave * 512);
            gload16(Wob + (size_t)(j0 + q * 32 + srow) * DI + k0 + skc,
                    ((short*)Bs) + q * 2048 + wave * 512);
        }
        asm volatile("s_waitcnt vmcnt(0)" ::: "memory");
        __syncthreads();
#pragma unroll
        for (int ks = 0; ks < 2; ks++) {
            bf16x8 af[4], bfr[4];
#pragma unroll
            for (int i = 0; i < 4; i++)
                af[i] = *(const bf16x8*)&As[wr * 64 + i * 16 + (lane & 15)][ks * 32 + (lane >> 4) * 8];
#pragma unroll
            for (int n = 0; n < 4; n++)
                bfr[n] = *(const bf16x8*)&Bs[wc * 64 + n * 16 + (lane & 15)][ks * 32 + (lane >> 4) * 8];
#pragma unroll
            for (int i = 0; i < 4; i++)
#pragma unroll
                for (int n = 0; n < 4; n++)
                    acc[i][n] = __builtin_amdgcn_mfma_f32_16x16x32_bf16(af[i], bfr[n], acc[i][n], 0, 0, 0);
        }
    }
#pragma unroll
    for (int i = 0; i < 4; i++) {
        int m = m0 + wr * 64 + i * 16 + ((lane >> 4) << 2);
        int b = m >> 12;
        int t = m & 4095;
#pragma unroll
        for (int n = 0; n < 4; n++) {
            int j = j0 + wc * 64 + n * 16 + (lane & 15);
            *(f32x4*)(out + (size_t)b * DM * TT + (size_t)j * TT + t) = acc[i][n];
        }
    }
}

extern "C" void kernel_launch(void* const* d_in, const int* in_sizes, int n_in,
                              void* d_out, int out_size, void* d_ws, size_t ws_size,
                              hipStream_t stream) {
    const float* x       = (const float*)d_in[0];
    const float* ln_w    = (const float*)d_in[1];
    const float* ln_b    = (const float*)d_in[2];
    const float* W_in    = (const float*)d_in[3];
    const float* conv_w  = (const float*)d_in[4];
    const float* conv_b  = (const float*)d_in[5];
    const float* dt_bias = (const float*)d_in[6];
    const float* A_log   = (const float*)d_in[7];
    const float* Dp      = (const float*)d_in[8];
    const float* rms_w   = (const float*)d_in[9];
    const float* W_out   = (const float*)d_in[10];
    const float* h0      = (const float*)d_in[11];

    float* out = (float*)d_out;
    float* hT = out + (size_t)BB * DM * TT;

    char* ws = (char*)d_ws;
    // Total footprint: 238,094,336 bytes (identical to proven round-4/5 layout).
    float* mu  = (float*)(ws + 0);            //      32,768
    float* rs  = (float*)(ws + 32768);        //      32,768
    float* zx  = (float*)(ws + 65536);        // 143,654,912  (B,T,4384) f32
    float* xBC = (float*)(ws + 143720448);    //  75,497,472  (phase B)
    __hip_bfloat16* Wb  = (__hip_bfloat16*)(ws + 143720448);              // phase A
    __hip_bfloat16* gq  = (__hip_bfloat16*)(ws + 143720448);              // phase C
    __hip_bfloat16* Wob = (__hip_bfloat16*)(ws + 143720448 + 41943040);   // phase C
    float* dAb = (float*)(ws + 219217920);    //   1,048,576
    float* dtv = (float*)(ws + 220266496);    //   1,048,576
    __hip_bfloat16* xnb = (__hip_bfloat16*)(ws + 221315072);   // 16,777,216 (shares with S)
    float* S   = (float*)(ws + 221315072);
    float* P   = (float*)(ws + 238092288);    //       2,048

    ln_stats_kernel<<<dim3(TT / 64, BB), 64, 0, stream>>>(x, mu, rs);
    xn_kernel<<<dim3(TT / 64, DM / 64, BB), 256, 0, stream>>>(x, mu, rs, ln_w, ln_b, xnb);
    cvt_pad_kernel<<<(NP1 * DM) / 1024, 256, 0, stream>>>(W_in, Wb, DIP * DM, NP1 * DM);
    gemm1_mfma<<<dim3(NP1 / 128, (BB * TT) / 128), 256, 0, stream>>>(Wb, xnb, zx);
    gemm1_kernel<<<dim3(1, (BB * TT) / 64), 256, 0, stream>>>(x, mu, rs, ln_w, ln_b, W_in, zx, 4352);
    conv_kernel<<<(BB * TT * CD) / 256, 256, 0, stream>>>(zx, conv_w, conv_b, xBC);
    dt_kernel<<<(BB * TT * NH) / 256, 256, 0, stream>>>(zx, dt_bias, A_log, dtv, dAb);
    scan_reduce_kernel<<<dim3(NC, NH, BB), 64, 0, stream>>>(xBC, dAb, dtv, S, P);
    scan_combine_kernel<<<(int)(SELEMS / 256), 256, 0, stream>>>(h0, P, S, hT);
    scan_emit_kernel<<<dim3(NC, NH, BB), 64, 0, stream>>>(xBC, dAb, dtv, S, Dp, zx);
    cvt_pad_kernel<<<(DM * DI) / 1024, 256, 0, stream>>>(W_out, Wob, DM * DI, DM * DI);
    gate_rms_kernel<<<BB * TT, 256, 0, stream>>>(zx, rms_w, gq);
    gemm2_mfma<<<dim3((BB * TT) / 128, DM / 128), 256, 0, stream>>>(gq, Wob, out);
}

// Round 7
// 1262.316 us; speedup vs baseline: 1.7599x; 1.7599x over previous
//
#include <hip/hip_runtime.h>
#include <hip/hip_bf16.h>
#include <math.h>

// Problem constants
#define BB 2
#define TT 4096
#define DM 1024
#define DSTATE 128
#define DI 2048
#define HD 64
#define NH 32
#define DIP 4384   // 2*DI + 2*DSTATE + NH
#define CD 2304    // DI + 2*DSTATE

// Chunked scan parameters
#define NC 8
#define CL 512
#define SELEMS ((size_t)BB * NH * HD * DSTATE)   // 524288

#define NP1 4480   // DIP padded to multiple of 128 for MFMA staging

typedef __attribute__((ext_vector_type(8))) short bf16x8;
typedef __attribute__((ext_vector_type(4))) float f32x4;

__device__ inline void gload16(const void* g, void* l) {
    __builtin_amdgcn_global_load_lds(
        (const __attribute__((address_space(1))) void*)g,
        (__attribute__((address_space(3))) void*)l, 16, 0, 0);
}

// ---------------- Kernel 1: LayerNorm statistics ----------------
__global__ __launch_bounds__(64) void ln_stats_kernel(const float* __restrict__ x,
                                                      float* __restrict__ mu,
                                                      float* __restrict__ rs) {
    int t = blockIdx.x * 64 + threadIdx.x;
    int b = blockIdx.y;
    const float* xb = x + (size_t)b * DM * TT + t;
    float s = 0.f, ss = 0.f;
#pragma unroll 8
    for (int d = 0; d < DM; d++) {
        float v = xb[(size_t)d * TT];
        s += v;
        ss += v * v;
    }
    float m = s * (1.f / DM);
    float var = ss * (1.f / DM) - m * m;
    int idx = b * TT + t;
    mu[idx] = m;
    rs[idx] = rsqrtf(var + 1e-5f);
}

// ---------------- Kernel 1b: xn = LN(x) transposed to (m, k) in bf16 ----------------
__global__ __launch_bounds__(256) void xn_kernel(const float* __restrict__ x,
                                                 const float* __restrict__ mu,
                                                 const float* __restrict__ rs,
                                                 const float* __restrict__ ln_w,
                                                 const float* __restrict__ ln_b,
                                                 __hip_bfloat16* __restrict__ xn) {
    __shared__ float tile[64][65];
    int tid = threadIdx.x;
    int t0 = blockIdx.x * 64, d0 = blockIdx.y * 64, b = blockIdx.z;
#pragma unroll
    for (int i = 0; i < 64; i += 4) {
        int dl = i + (tid >> 6);
        tile[dl][tid & 63] = x[(size_t)b * DM * TT + (size_t)(d0 + dl) * TT + t0 + (tid & 63)];
    }
    __syncthreads();
#pragma unroll
    for (int i = 0; i < 64; i += 8) {
        int tl = i + (tid >> 5);
        int kk = (tid & 31) * 2;
        int m = b * TT + t0 + tl;
        float mu_m = mu[m], rs_m = rs[m];
        float v0 = (tile[kk][tl] - mu_m) * rs_m * ln_w[d0 + kk] + ln_b[d0 + kk];
        float v1 = (tile[kk + 1][tl] - mu_m) * rs_m * ln_w[d0 + kk + 1] + ln_b[d0 + kk + 1];
        __hip_bfloat162 pk;
        pk.x = __float2bfloat16(v0);
        pk.y = __float2bfloat16(v1);
        *(__hip_bfloat162*)(xn + (size_t)m * DM + d0 + kk) = pk;
    }
}

// ---------------- convert f32 -> bf16 with zero-padding ----------------
__global__ __launch_bounds__(256) void cvt_pad_kernel(const float* __restrict__ src,
                                                      __hip_bfloat16* __restrict__ dst,
                                                      int src_n, int tot_n) {
    int i = (blockIdx.x * 256 + threadIdx.x) * 4;
    if (i >= tot_n) return;
    float4 v = (i < src_n) ? *(const float4*)(src + i) : make_float4(0.f, 0.f, 0.f, 0.f);
    __hip_bfloat162 p0, p1;
    p0.x = __float2bfloat16(v.x); p0.y = __float2bfloat16(v.y);
    p1.x = __float2bfloat16(v.z); p1.y = __float2bfloat16(v.w);
    *(__hip_bfloat162*)(dst + i) = p0;
    *(__hip_bfloat162*)(dst + i + 2) = p1;
}

// ---------------- Kernel 2: GEMM1 bf16 MFMA ----------------
__global__ __launch_bounds__(256) void gemm1_mfma(const __hip_bfloat16* __restrict__ Wb,
                                                  const __hip_bfloat16* __restrict__ xn,
                                                  float* __restrict__ zx) {
    __shared__ short As[128][64];
    __shared__ short Bs[128][64];
    int tid = threadIdx.x;
    int lane = tid & 63;
    int wave = tid >> 6;
    int wr = wave >> 1, wc = wave & 1;
    int j0 = blockIdx.x * 128;
    int m0 = blockIdx.y * 128;
    int srow = tid >> 3;
    int skc = (tid & 7) * 8;

    f32x4 acc[4][4] = {};

    for (int k0 = 0; k0 < DM; k0 += 64) {
        __syncthreads();
#pragma unroll
        for (int q = 0; q < 4; q++) {
            gload16(Wb + (size_t)(j0 + q * 32 + srow) * DM + k0 + skc,
                    ((short*)As) + q * 2048 + wave * 512);
            gload16(xn + (size_t)(m0 + q * 32 + srow) * DM + k0 + skc,
                    ((short*)Bs) + q * 2048 + wave * 512);
        }
        asm volatile("s_waitcnt vmcnt(0)" ::: "memory");
        __syncthreads();
#pragma unroll
        for (int ks = 0; ks < 2; ks++) {
            bf16x8 af[4], bfr[4];
#pragma unroll
            for (int i = 0; i < 4; i++)
                af[i] = *(const bf16x8*)&As[wr * 64 + i * 16 + (lane & 15)][ks * 32 + (lane >> 4) * 8];
#pragma unroll
            for (int n = 0; n < 4; n++)
                bfr[n] = *(const bf16x8*)&Bs[wc * 64 + n * 16 + (lane & 15)][ks * 32 + (lane >> 4) * 8];
#pragma unroll
            for (int i = 0; i < 4; i++)
#pragma unroll
                for (int n = 0; n < 4; n++)
                    acc[i][n] = __builtin_amdgcn_mfma_f32_16x16x32_bf16(af[i], bfr[n], acc[i][n], 0, 0, 0);
        }
    }
#pragma unroll
    for (int i = 0; i < 4; i++) {
        int j = j0 + wr * 64 + i * 16 + ((lane >> 4) << 2);
        if (j < DIP) {
#pragma unroll
            for (int n = 0; n < 4; n++) {
                int m = m0 + wc * 64 + n * 16 + (lane & 15);
                *(f32x4*)(zx + (size_t)m * DIP + j) = acc[i][n];
            }
        }
    }
}

// ---------------- Kernel 2b: f32 strip GEMM for dt columns ----------------
__global__ __launch_bounds__(256) void gemm1_kernel(const float* __restrict__ x,
                                                    const float* __restrict__ mu,
                                                    const float* __restrict__ rs,
                                                    const float* __restrict__ ln_w,
                                                    const float* __restrict__ ln_b,
                                                    const float* __restrict__ Win,
                                                    float* __restrict__ zx,
                                                    int jbase) {
    __shared__ float As[16][64];
    __shared__ float Ws[64][17];
    int tid = threadIdx.x;
    int tx = tid & 15;
    int ty = tid >> 4;
    int j0 = jbase + blockIdx.x * 64;
    int m0 = blockIdx.y * 64;
    int b = m0 >> 12;
    int t0 = m0 & 4095;
    const float* Xb = x + (size_t)b * DM * TT + t0;

    int lr = tid >> 4;
    int lc = (tid & 15) * 4;
    int wr = tid >> 2;
    int wc = (tid & 3) * 4;

    float acc[4][4] = {};
    for (int k0 = 0; k0 < DM; k0 += 16) {
        float4 xv = *(const float4*)(Xb + (size_t)(k0 + lr) * TT + lc);
        float4 muv = *(const float4*)(&mu[m0 + lc]);
        float4 rsv = *(const float4*)(&rs[m0 + lc]);
        float lw = ln_w[k0 + lr], lb = ln_b[k0 + lr];
        As[lr][lc]     = (xv.x - muv.x) * rsv.x * lw + lb;
        As[lr][lc + 1] = (xv.y - muv.y) * rsv.y * lw + lb;
        As[lr][lc + 2] = (xv.z - muv.z) * rsv.z * lw + lb;
        As[lr][lc + 3] = (xv.w - muv.w) * rsv.w * lw + lb;

        int j = j0 + wr;
        float4 wv = make_float4(0.f, 0.f, 0.f, 0.f);
        if (j < DIP) wv = *(const float4*)(Win + (size_t)j * DM + k0 + wc);
        Ws[wr][wc] = wv.x; Ws[wr][wc + 1] = wv.y; Ws[wr][wc + 2] = wv.z; Ws[wr][wc + 3] = wv.w;
        __syncthreads();
#pragma unroll
        for (int kk = 0; kk < 16; kk++) {
            float4 a4 = *(const float4*)&As[kk][ty * 4];
            float a[4] = {a4.x, a4.y, a4.z, a4.w};
            float bv[4];
#pragma unroll
            for (int n = 0; n < 4; n++) bv[n] = Ws[tx * 4 + n][kk];
#pragma unroll
            for (int i = 0; i < 4; i++)
#pragma unroll
                for (int n = 0; n < 4; n++)
                    acc[i][n] = fmaf(a[i], bv[n], acc[i][n]);
        }
        __syncthreads();
    }
#pragma unroll
    for (int i = 0; i < 4; i++) {
        int m = m0 + ty * 4 + i;
        int j = j0 + tx * 4;
        if (j < DIP) {
            float4 v = make_float4(acc[i][0], acc[i][1], acc[i][2], acc[i][3]);
            *(float4*)(zx + (size_t)m * DIP + j) = v;
        }
    }
}

// ---------------- Kernel 3: causal depthwise conv(4) + SiLU ----------------
__global__ __launch_bounds__(256) void conv_kernel(const float* __restrict__ zx,
                                                   const float* __restrict__ cw,
                                                   const float* __restrict__ cb,
                                                   float* __restrict__ xBC) {
    int i = blockIdx.x * 256 + threadIdx.x;
    int c = i % CD;
    int t = (i / CD) & (TT - 1);
    int b = i / (CD * TT);
    const float* src = zx + (size_t)b * TT * DIP + DI + c;
    float acc = cb[c];
#pragma unroll
    for (int k = 0; k < 4; k++) {
        int ts = t - 3 + k;
        if (ts >= 0) acc = fmaf(cw[c * 4 + k], src[(size_t)ts * DIP], acc);
    }
    float sg = 1.f / (1.f + expf(-acc));
    xBC[(size_t)i] = acc * sg;
}

// ---------------- Kernel 4: dt softplus + dA ----------------
__global__ __launch_bounds__(256) void dt_kernel(const float* __restrict__ zx,
                                                 const float* __restrict__ dt_bias,
                                                 const float* __restrict__ A_log,
                                                 float* __restrict__ dtv,
                                                 float* __restrict__ dAb) {
    int i = blockIdx.x * 256 + threadIdx.x;
    int hh = i & (NH - 1);
    int m = i >> 5;
    float raw = zx[(size_t)m * DIP + (DI + CD) + hh] + dt_bias[hh];
    float dt = (raw > 20.f) ? raw : log1pf(expf(raw));
    float dA = expf(-expf(A_log[hh]) * dt);
    dtv[i] = dt;
    dAb[i] = dA;
}

// ---------------- Kernel 5a: chunk reduce v2 ----------------
// Block 256 = 4 waves per (chunk, head, batch). Thread owns 4p x 8n: h[4][8] in regs.
// B row (512B) staged per-t into double-buffered LDS by 8 lanes/wave.
__global__ __launch_bounds__(256, 2) void scan_reduce_kernel(const float* __restrict__ xBC,
                                                             const float* __restrict__ dAb,
                                                             const float* __restrict__ dtg,
                                                             float* __restrict__ S,
                                                             float* __restrict__ P) {
    int tid = threadIdx.x;
    int wave = tid >> 6, lane = tid & 63;
    int pg = lane >> 4, ng = lane & 15;
    int c = blockIdx.x, hh = blockIdx.y, b = blockIdx.z;
    int p0 = wave * 16 + pg * 4;
    int n0 = ng * 8;
    int tbeg = c * CL, tend = tbeg + CL;

    __shared__ alignas(16) float lbB[2][128];

    float h[4][8];
#pragma unroll
    for (int pp = 0; pp < 4; pp++)
#pragma unroll
        for (int nn = 0; nn < 8; nn++) h[pp][nn] = 0.f;
    float cd = 1.f;

    const float* base = xBC + (size_t)b * TT * CD;
    const float* dab = dAb + (size_t)b * TT * NH + hh;
    const float* dtb = dtg + (size_t)b * TT * NH + hh;

    int sidx = wave * 8 + (lane & 7);       // 32 stagers, float4 each
    bool stager = (lane < 8);

    if (stager) {
        float4 v = *(const float4*)(base + (size_t)tbeg * CD + DI + sidx * 4);
        *(float4*)&lbB[0][sidx * 4] = v;
    }
    float4 xv = *(const float4*)(base + (size_t)tbeg * CD + hh * HD + p0);
    float da = dab[(size_t)tbeg * NH];
    float dt = dtb[(size_t)tbeg * NH];
    __syncthreads();

    int buf = 0;
    for (int t = tbeg; t < tend; t++) {
        int tn = (t + 1 < tend) ? t + 1 : t;
        const float* rn = base + (size_t)tn * CD;
        float4 sv;
        if (stager) sv = *(const float4*)(rn + DI + sidx * 4);
        float4 nx = *(const float4*)(rn + hh * HD + p0);
        float nda = dab[(size_t)tn * NH];
        float ndt = dtb[(size_t)tn * NH];

        float Bv[8];
        *(float4*)&Bv[0] = *(float4*)&lbB[buf][n0];
        *(float4*)&Bv[4] = *(float4*)&lbB[buf][n0 + 4];
        float xdt[4] = {xv.x * dt, xv.y * dt, xv.z * dt, xv.w * dt};
#pragma unroll
        for (int pp = 0; pp < 4; pp++)
#pragma unroll
            for (int nn = 0; nn < 8; nn++)
                h[pp][nn] = fmaf(h[pp][nn], da, xdt[pp] * Bv[nn]);
        cd *= da;

        if (stager) *(float4*)&lbB[buf ^ 1][sidx * 4] = sv;
        __syncthreads();
        buf ^= 1;
        xv = nx; da = nda; dt = ndt;
    }

    float* Sp = S + (size_t)c * SELEMS + ((size_t)(b * NH + hh) * HD) * DSTATE;
#pragma unroll
    for (int pp = 0; pp < 4; pp++) {
        float* q = Sp + (size_t)(p0 + pp) * DSTATE + n0;
        *(float4*)q = make_float4(h[pp][0], h[pp][1], h[pp][2], h[pp][3]);
        *(float4*)(q + 4) = make_float4(h[pp][4], h[pp][5], h[pp][6], h[pp][7]);
    }
    if (tid == 0) P[(c * BB + b) * NH + hh] = cd;
}

// ---------------- Kernel 5b: sequential chunk combine ----------------
__global__ __launch_bounds__(256) void scan_combine_kernel(const float* __restrict__ h0,
                                                           const float* __restrict__ P,
                                                           float* __restrict__ S,
                                                           float* __restrict__ hT) {
    size_t tid = (size_t)blockIdx.x * 256 + threadIdx.x;
    int hh = (int)((tid >> 13) & 31);
    int b = (int)(tid >> 18);
    float h = h0[tid];
#pragma unroll
    for (int c = 0; c < NC; c++) {
        float s = S[(size_t)c * SELEMS + tid];
        S[(size_t)c * SELEMS + tid] = h;
        h = fmaf(P[(c * BB + b) * NH + hh], h, s);
    }
    hT[tid] = h;
}

// ---------------- Kernel 5c: chunk emit v2 ----------------
// Same decomposition as reduce; B||C row (1KB) staged per-t by 16 lanes/wave.
// ps reduced over the 16 ng-lanes; y -> zx cols [2048,4096).
__global__ __launch_bounds__(256, 2) void scan_emit_kernel(const float* __restrict__ xBC,
                                                           const float* __restrict__ dAb,
                                                           const float* __restrict__ dtg,
                                                           const float* __restrict__ S,
                                                           const float* __restrict__ Dp,
                                                           float* __restrict__ zx) {
    int tid = threadIdx.x;
    int wave = tid >> 6, lane = tid & 63;
    int pg = lane >> 4, ng = lane & 15;
    int c = blockIdx.x, hh = blockIdx.y, b = blockIdx.z;
    int p0 = wave * 16 + pg * 4;
    int n0 = ng * 8;
    int tbeg = c * CL, tend = tbeg + CL;

    __shared__ alignas(16) float lbBC[2][256];

    float h[4][8];
    const float* Sp = S + (size_t)c * SELEMS + ((size_t)(b * NH + hh) * HD) * DSTATE;
#pragma unroll
    for (int pp = 0; pp < 4; pp++) {
        const float* q = Sp + (size_t)(p0 + pp) * DSTATE + n0;
        float4 v0 = *(const float4*)q;
        float4 v1 = *(const float4*)(q + 4);
        h[pp][0] = v0.x; h[pp][1] = v0.y; h[pp][2] = v0.z; h[pp][3] = v0.w;
        h[pp][4] = v1.x; h[pp][5] = v1.y; h[pp][6] = v1.z; h[pp][7] = v1.w;
    }

    float Dh = Dp[hh];
    const float* base = xBC + (size_t)b * TT * CD;
    const float* dab = dAb + (size_t)b * TT * NH + hh;
    const float* dtb = dtg + (size_t)b * TT * NH + hh;
    float* yb = zx + (size_t)b * TT * DIP + DI + hh * HD + p0;

    int sidx = wave * 16 + (lane & 15);     // 64 stagers, float4 each
    bool stager = (lane < 16);

    if (stager) {
        float4 v = *(const float4*)(base + (size_t)tbeg * CD + DI + sidx * 4);
        *(float4*)&lbBC[0][sidx * 4] = v;
    }
    float4 xv = *(const float4*)(base + (size_t)tbeg * CD + hh * HD + p0);
    float da = dab[(size_t)tbeg * NH];
    float dt = dtb[(size_t)tbeg * NH];
    __syncthreads();

    int buf = 0;
    for (int t = tbeg; t < tend; t++) {
        int tn = (t + 1 < tend) ? t + 1 : t;
        const float* rn = base + (size_t)tn * CD;
        float4 sv;
        if (stager) sv = *(const float4*)(rn + DI + sidx * 4);
        float4 nx = *(const float4*)(rn + hh * HD + p0);
        float nda = dab[(size_t)tn * NH];
        float ndt = dtb[(size_t)tn * NH];

        float Bv[8], Cv[8];
        *(float4*)&Bv[0] = *(float4*)&lbBC[buf][n0];
        *(float4*)&Bv[4] = *(float4*)&lbBC[buf][n0 + 4];
        *(float4*)&Cv[0] = *(float4*)&lbBC[buf][128 + n0];
        *(float4*)&Cv[4] = *(float4*)&lbBC[buf][128 + n0 + 4];
        float xdt[4] = {xv.x * dt, xv.y * dt, xv.z * dt, xv.w * dt};
        float ps[4] = {0.f, 0.f, 0.f, 0.f};
#pragma unroll
        for (int pp = 0; pp < 4; pp++)
#pragma unroll
            for (int nn = 0; nn < 8; nn++) {
                float hv = fmaf(h[pp][nn], da, xdt[pp] * Bv[nn]);
                h[pp][nn] = hv;
                ps[pp] = fmaf(hv, Cv[nn], ps[pp]);
            }
#pragma unroll
        for (int pp = 0; pp < 4; pp++) {
            ps[pp] += __shfl_xor(ps[pp], 1);
            ps[pp] += __shfl_xor(ps[pp], 2);
            ps[pp] += __shfl_xor(ps[pp], 4);
            ps[pp] += __shfl_xor(ps[pp], 8);
        }
        if (ng == 0) {
            float4 yo = make_float4(ps[0] + Dh * xv.x, ps[1] + Dh * xv.y,
                                    ps[2] + Dh * xv.z, ps[3] + Dh * xv.w);
            *(float4*)(yb + (size_t)t * DIP) = yo;
        }

        if (stager) *(float4*)&lbBC[buf ^ 1][sidx * 4] = sv;
        __syncthreads();
        buf ^= 1;
        xv = nx; da = nda; dt = ndt;
    }
}

// ---------------- Kernel 6: gating + RMSNorm -> bf16 g ----------------
__global__ __launch_bounds__(256) void gate_rms_kernel(const float* __restrict__ zx,
                                                       const float* __restrict__ rw,
                                                       __hip_bfloat16* __restrict__ gq) {
    int m = blockIdx.x;
    int tid = threadIdx.x;
    const float* yr = zx + (size_t)m * DIP + DI;
    const float* zr = zx + (size_t)m * DIP;
    int base = tid * 8;
    float gv[8];
    float ss = 0.f;
    float4 ya = *(const float4*)(yr + base);
    float4 yb4 = *(const float4*)(yr + base + 4);
    float4 za = *(const float4*)(zr + base);
    float4 zb4 = *(const float4*)(zr + base + 4);
    float yv[8] = {ya.x, ya.y, ya.z, ya.w, yb4.x, yb4.y, yb4.z, yb4.w};
    float zv[8] = {za.x, za.y, za.z, za.w, zb4.x, zb4.y, zb4.z, zb4.w};
#pragma unroll
    for (int i = 0; i < 8; i++) {
        float sg = 1.f / (1.f + expf(-zv[i]));
        float gg = yv[i] * zv[i] * sg;
        gv[i] = gg;
        ss += gg * gg;
    }
#pragma unroll
    for (int off = 1; off < 64; off <<= 1) ss += __shfl_xor(ss, off);
    __shared__ float red[4];
    int w = tid >> 6;
    if ((tid & 63) == 0) red[w] = ss;
    __syncthreads();
    float tot = red[0] + red[1] + red[2] + red[3];
    float r = rsqrtf(tot * (1.f / DI) + 1e-5f);
#pragma unroll
    for (int i = 0; i < 8; i += 2) {
        __hip_bfloat162 p;
        p.x = __float2bfloat16(gv[i] * r * rw[base + i]);
        p.y = __float2bfloat16(gv[i + 1] * r * rw[base + i + 1]);
        *(__hip_bfloat162*)(gq + (size_t)m * DI + base + i) = p;
    }
}

// ---------------- Kernel 7: GEMM2 bf16 MFMA (transposed store) ----------------
__global__ __launch_bounds__(256) void gemm2_mfma(const __hip_bfloat16* __restrict__ gq,
                                                  const __hip_bfloat16* __restrict__ Wob,
                                                  float* __restrict__ out) {
    __shared__ short As[128][64];
    __shared__ short Bs[128][64];
    int tid = threadIdx.x;
    int lane = tid & 63;
    int wave = tid >> 6;
    int wr = wave >> 1, wc = wave & 1;
    int m0 = blockIdx.x * 128;
    int j0 = blockIdx.y * 128;
    int srow = tid >> 3;
    int skc = (tid & 7) * 8;

    f32x4 acc[4][4] = {};

    for (int k0 = 0; k0 < DI; k0 += 64) {
        __syncthreads();
#pragma unroll
        for (int q = 0; q < 4; q++) {
            gload16(gq + (size_t)(m0 + q * 32 + srow) * DI + k0 + skc,
                    ((short*)As) + q * 2048 + wave * 512);
            gload16(Wob + (size_t)(j0 + q * 32 + srow) * DI + k0 + skc,
                    ((short*)Bs) + q * 2048 + wave * 512);
        }
        asm volatile("s_waitcnt vmcnt(0)" ::: "memory");
        __syncthreads();
#pragma unroll
        for (int ks = 0; ks < 2; ks++) {
            bf16x8 af[4], bfr[4];
#pragma unroll
            for (int i = 0; i < 4; i++)
                af[i] = *(const bf16x8*)&As[wr * 64 + i * 16 + (lane & 15)][ks * 32 + (lane >> 4) * 8];
#pragma unroll
            for (int n = 0; n < 4; n++)
                bfr[n] = *(const bf16x8*)&Bs[wc * 64 + n * 16 + (lane & 15)][ks * 32 + (lane >> 4) * 8];
#pragma unroll
            for (int i = 0; i < 4; i++)
#pragma unroll
                for (int n = 0; n < 4; n++)
                    acc[i][n] = __builtin_amdgcn_mfma_f32_16x16x32_bf16(af[i], bfr[n], acc[i][n], 0, 0, 0);
        }
    }
#pragma unroll
    for (int i = 0; i < 4; i++) {
        int m = m0 + wr * 64 + i * 16 + ((lane >> 4) << 2);
        int b = m >> 12;
        int t = m & 4095;
#pragma unroll
        for (int n = 0; n < 4; n++) {
            int j = j0 + wc * 64 + n * 16 + (lane & 15);
            *(f32x4*)(out + (size_t)b * DM * TT + (size_t)j * TT + t) = acc[i][n];
        }
    }
}

extern "C" void kernel_launch(void* const* d_in, const int* in_sizes, int n_in,
                              void* d_out, int out_size, void* d_ws, size_t ws_size,
                              hipStream_t stream) {
    const float* x       = (const float*)d_in[0];
    const float* ln_w    = (const float*)d_in[1];
    const float* ln_b    = (const float*)d_in[2];
    const float* W_in    = (const float*)d_in[3];
    const float* conv_w  = (const float*)d_in[4];
    const float* conv_b  = (const float*)d_in[5];
    const float* dt_bias = (const float*)d_in[6];
    const float* A_log   = (const float*)d_in[7];
    const float* Dp      = (const float*)d_in[8];
    const float* rms_w   = (const float*)d_in[9];
    const float* W_out   = (const float*)d_in[10];
    const float* h0      = (const float*)d_in[11];

    float* out = (float*)d_out;
    float* hT = out + (size_t)BB * DM * TT;

    char* ws = (char*)d_ws;
    // Total footprint: 238,094,336 bytes (identical to proven round-4/5 layout).
    float* mu  = (float*)(ws + 0);            //      32,768
    float* rs  = (float*)(ws + 32768);        //      32,768
    float* zx  = (float*)(ws + 65536);        // 143,654,912  (B,T,4384) f32
    float* xBC = (float*)(ws + 143720448);    //  75,497,472  (phase B)
    __hip_bfloat16* Wb  = (__hip_bfloat16*)(ws + 143720448);              // phase A
    __hip_bfloat16* gq  = (__hip_bfloat16*)(ws + 143720448);              // phase C
    __hip_bfloat16* Wob = (__hip_bfloat16*)(ws + 143720448 + 41943040);   // phase C
    float* dAb = (float*)(ws + 219217920);    //   1,048,576
    float* dtv = (float*)(ws + 220266496);    //   1,048,576
    __hip_bfloat16* xnb = (__hip_bfloat16*)(ws + 221315072);   // 16,777,216 (shares with S)
    float* S   = (float*)(ws + 221315072);
    float* P   = (float*)(ws + 238092288);    //       2,048

    ln_stats_kernel<<<dim3(TT / 64, BB), 64, 0, stream>>>(x, mu, rs);
    xn_kernel<<<dim3(TT / 64, DM / 64, BB), 256, 0, stream>>>(x, mu, rs, ln_w, ln_b, xnb);
    cvt_pad_kernel<<<(NP1 * DM) / 1024, 256, 0, stream>>>(W_in, Wb, DIP * DM, NP1 * DM);
    gemm1_mfma<<<dim3(NP1 / 128, (BB * TT) / 128), 256, 0, stream>>>(Wb, xnb, zx);
    gemm1_kernel<<<dim3(1, (BB * TT) / 64), 256, 0, stream>>>(x, mu, rs, ln_w, ln_b, W_in, zx, 4352);
    conv_kernel<<<(BB * TT * CD) / 256, 256, 0, stream>>>(zx, conv_w, conv_b, xBC);
    dt_kernel<<<(BB * TT * NH) / 256, 256, 0, stream>>>(zx, dt_bias, A_log, dtv, dAb);
    scan_reduce_kernel<<<dim3(NC, NH, BB), 256, 0, stream>>>(xBC, dAb, dtv, S, P);
    scan_combine_kernel<<<(int)(SELEMS / 256), 256, 0, stream>>>(h0, P, S, hT);
    scan_emit_kernel<<<dim3(NC, NH, BB), 256, 0, stream>>>(xBC, dAb, dtv, S, Dp, zx);
    cvt_pad_kernel<<<(DM * DI) / 1024, 256, 0, stream>>>(W_out, Wob, DM * DI, DM * DI);
    gate_rms_kernel<<<BB * TT, 256, 0, stream>>>(zx, rms_w, gq);
    gemm2_mfma<<<dim3((BB * TT) / 128, DM / 128), 256, 0, stream>>>(gq, Wob, out);
}

// Round 8
// 901.006 us; speedup vs baseline: 2.4656x; 1.4010x over previous
//
#include <hip/hip_runtime.h>
#include <hip/hip_bf16.h>
#include <math.h>

// Problem constants
#define BB 2
#define TT 4096
#define DM 1024
#define DSTATE 128
#define DI 2048
#define HD 64
#define NH 32
#define DIP 4384   // 2*DI + 2*DSTATE + NH
#define CD 2304    // DI + 2*DSTATE

// Chunked scan parameters
#define NC 8
#define CL 512
#define KT 8       // timesteps per LDS stage group
#define SELEMS ((size_t)BB * NH * HD * DSTATE)   // 524288

#define NP1 4480   // DIP padded to multiple of 128 for MFMA staging

typedef __attribute__((ext_vector_type(8))) short bf16x8;
typedef __attribute__((ext_vector_type(4))) float f32x4;

__device__ inline void gload16(const void* g, void* l) {
    __builtin_amdgcn_global_load_lds(
        (const __attribute__((address_space(1))) void*)g,
        (__attribute__((address_space(3))) void*)l, 16, 0, 0);
}

// ---------------- Kernel 1: LayerNorm statistics ----------------
__global__ __launch_bounds__(64) void ln_stats_kernel(const float* __restrict__ x,
                                                      float* __restrict__ mu,
                                                      float* __restrict__ rs) {
    int t = blockIdx.x * 64 + threadIdx.x;
    int b = blockIdx.y;
    const float* xb = x + (size_t)b * DM * TT + t;
    float s = 0.f, ss = 0.f;
#pragma unroll 8
    for (int d = 0; d < DM; d++) {
        float v = xb[(size_t)d * TT];
        s += v;
        ss += v * v;
    }
    float m = s * (1.f / DM);
    float var = ss * (1.f / DM) - m * m;
    int idx = b * TT + t;
    mu[idx] = m;
    rs[idx] = rsqrtf(var + 1e-5f);
}

// ---------------- Kernel 1b: xn = LN(x) transposed to (m, k) in bf16 ----------------
__global__ __launch_bounds__(256) void xn_kernel(const float* __restrict__ x,
                                                 const float* __restrict__ mu,
                                                 const float* __restrict__ rs,
                                                 const float* __restrict__ ln_w,
                                                 const float* __restrict__ ln_b,
                                                 __hip_bfloat16* __restrict__ xn) {
    __shared__ float tile[64][65];
    int tid = threadIdx.x;
    int t0 = blockIdx.x * 64, d0 = blockIdx.y * 64, b = blockIdx.z;
#pragma unroll
    for (int i = 0; i < 64; i += 4) {
        int dl = i + (tid >> 6);
        tile[dl][tid & 63] = x[(size_t)b * DM * TT + (size_t)(d0 + dl) * TT + t0 + (tid & 63)];
    }
    __syncthreads();
#pragma unroll
    for (int i = 0; i < 64; i += 8) {
        int tl = i + (tid >> 5);
        int kk = (tid & 31) * 2;
        int m = b * TT + t0 + tl;
        float mu_m = mu[m], rs_m = rs[m];
        float v0 = (tile[kk][tl] - mu_m) * rs_m * ln_w[d0 + kk] + ln_b[d0 + kk];
        float v1 = (tile[kk + 1][tl] - mu_m) * rs_m * ln_w[d0 + kk + 1] + ln_b[d0 + kk + 1];
        __hip_bfloat162 pk;
        pk.x = __float2bfloat16(v0);
        pk.y = __float2bfloat16(v1);
        *(__hip_bfloat162*)(xn + (size_t)m * DM + d0 + kk) = pk;
    }
}

// ---------------- convert f32 -> bf16 with zero-padding ----------------
__global__ __launch_bounds__(256) void cvt_pad_kernel(const float* __restrict__ src,
                                                      __hip_bfloat16* __restrict__ dst,
                                                      int src_n, int tot_n) {
    int i = (blockIdx.x * 256 + threadIdx.x) * 4;
    if (i >= tot_n) return;
    float4 v = (i < src_n) ? *(const float4*)(src + i) : make_float4(0.f, 0.f, 0.f, 0.f);
    __hip_bfloat162 p0, p1;
    p0.x = __float2bfloat16(v.x); p0.y = __float2bfloat16(v.y);
    p1.x = __float2bfloat16(v.z); p1.y = __float2bfloat16(v.w);
    *(__hip_bfloat162*)(dst + i) = p0;
    *(__hip_bfloat162*)(dst + i + 2) = p1;
}

// ---------------- Kernel 2: GEMM1 bf16 MFMA ----------------
__global__ __launch_bounds__(256) void gemm1_mfma(const __hip_bfloat16* __restrict__ Wb,
                                                  const __hip_bfloat16* __restrict__ xn,
                                                  float* __restrict__ zx) {
    __shared__ short As[128][64];
    __shared__ short Bs[128][64];
    int tid = threadIdx.x;
    int lane = tid & 63;
    int wave = tid >> 6;
    int wr = wave >> 1, wc = wave & 1;
    int j0 = blockIdx.x * 128;
    int m0 = blockIdx.y * 128;
    int srow = tid >> 3;
    int skc = (tid & 7) * 8;

    f32x4 acc[4][4] = {};

    for (int k0 = 0; k0 < DM; k0 += 64) {
        __syncthreads();
#pragma unroll
        for (int q = 0; q < 4; q++) {
            gload16(Wb + (size_t)(j0 + q * 32 + srow) * DM + k0 + skc,
                    ((short*)As) + q * 2048 + wave * 512);
            gload16(xn + (size_t)(m0 + q * 32 + srow) * DM + k0 + skc,
                    ((short*)Bs) + q * 2048 + wave * 512);
        }
        asm volatile("s_waitcnt vmcnt(0)" ::: "memory");
        __syncthreads();
#pragma unroll
        for (int ks = 0; ks < 2; ks++) {
            bf16x8 af[4], bfr[4];
#pragma unroll
            for (int i = 0; i < 4; i++)
                af[i] = *(const bf16x8*)&As[wr * 64 + i * 16 + (lane & 15)][ks * 32 + (lane >> 4) * 8];
#pragma unroll
            for (int n = 0; n < 4; n++)
                bfr[n] = *(const bf16x8*)&Bs[wc * 64 + n * 16 + (lane & 15)][ks * 32 + (lane >> 4) * 8];
#pragma unroll
            for (int i = 0; i < 4; i++)
#pragma unroll
                for (int n = 0; n < 4; n++)
                    acc[i][n] = __builtin_amdgcn_mfma_f32_16x16x32_bf16(af[i], bfr[n], acc[i][n], 0, 0, 0);
        }
    }
#pragma unroll
    for (int i = 0; i < 4; i++) {
        int j = j0 + wr * 64 + i * 16 + ((lane >> 4) << 2);
        if (j < DIP) {
#pragma unroll
            for (int n = 0; n < 4; n++) {
                int m = m0 + wc * 64 + n * 16 + (lane & 15);
                *(f32x4*)(zx + (size_t)m * DIP + j) = acc[i][n];
            }
        }
    }
}

// ---------------- Kernel 2b: f32 strip GEMM for dt columns ----------------
__global__ __launch_bounds__(256) void gemm1_kernel(const float* __restrict__ x,
                                                    const float* __restrict__ mu,
                                                    const float* __restrict__ rs,
                                                    const float* __restrict__ ln_w,
                                                    const float* __restrict__ ln_b,
                                                    const float* __restrict__ Win,
                                                    float* __restrict__ zx,
                                                    int jbase) {
    __shared__ float As[16][64];
    __shared__ float Ws[64][17];
    int tid = threadIdx.x;
    int tx = tid & 15;
    int ty = tid >> 4;
    int j0 = jbase + blockIdx.x * 64;
    int m0 = blockIdx.y * 64;
    int b = m0 >> 12;
    int t0 = m0 & 4095;
    const float* Xb = x + (size_t)b * DM * TT + t0;

    int lr = tid >> 4;
    int lc = (tid & 15) * 4;
    int wr = tid >> 2;
    int wc = (tid & 3) * 4;

    float acc[4][4] = {};
    for (int k0 = 0; k0 < DM; k0 += 16) {
        float4 xv = *(const float4*)(Xb + (size_t)(k0 + lr) * TT + lc);
        float4 muv = *(const float4*)(&mu[m0 + lc]);
        float4 rsv = *(const float4*)(&rs[m0 + lc]);
        float lw = ln_w[k0 + lr], lb = ln_b[k0 + lr];
        As[lr][lc]     = (xv.x - muv.x) * rsv.x * lw + lb;
        As[lr][lc + 1] = (xv.y - muv.y) * rsv.y * lw + lb;
        As[lr][lc + 2] = (xv.z - muv.z) * rsv.z * lw + lb;
        As[lr][lc + 3] = (xv.w - muv.w) * rsv.w * lw + lb;

        int j = j0 + wr;
        float4 wv = make_float4(0.f, 0.f, 0.f, 0.f);
        if (j < DIP) wv = *(const float4*)(Win + (size_t)j * DM + k0 + wc);
        Ws[wr][wc] = wv.x; Ws[wr][wc + 1] = wv.y; Ws[wr][wc + 2] = wv.z; Ws[wr][wc + 3] = wv.w;
        __syncthreads();
#pragma unroll
        for (int kk = 0; kk < 16; kk++) {
            float4 a4 = *(const float4*)&As[kk][ty * 4];
            float a[4] = {a4.x, a4.y, a4.z, a4.w};
            float bv[4];
#pragma unroll
            for (int n = 0; n < 4; n++) bv[n] = Ws[tx * 4 + n][kk];
#pragma unroll
            for (int i = 0; i < 4; i++)
#pragma unroll
                for (int n = 0; n < 4; n++)
                    acc[i][n] = fmaf(a[i], bv[n], acc[i][n]);
        }
        __syncthreads();
    }
#pragma unroll
    for (int i = 0; i < 4; i++) {
        int m = m0 + ty * 4 + i;
        int j = j0 + tx * 4;
        if (j < DIP) {
            float4 v = make_float4(acc[i][0], acc[i][1], acc[i][2], acc[i][3]);
            *(float4*)(zx + (size_t)m * DIP + j) = v;
        }
    }
}

// ---------------- Kernel 3: causal depthwise conv(4) + SiLU ----------------
__global__ __launch_bounds__(256) void conv_kernel(const float* __restrict__ zx,
                                                   const float* __restrict__ cw,
                                                   const float* __restrict__ cb,
                                                   float* __restrict__ xBC) {
    int i = blockIdx.x * 256 + threadIdx.x;
    int c = i % CD;
    int t = (i / CD) & (TT - 1);
    int b = i / (CD * TT);
    const float* src = zx + (size_t)b * TT * DIP + DI + c;
    float acc = cb[c];
#pragma unroll
    for (int k = 0; k < 4; k++) {
        int ts = t - 3 + k;
        if (ts >= 0) acc = fmaf(cw[c * 4 + k], src[(size_t)ts * DIP], acc);
    }
    float sg = 1.f / (1.f + expf(-acc));
    xBC[(size_t)i] = acc * sg;
}

// ---------------- Kernel 4: dt softplus + dA ----------------
__global__ __launch_bounds__(256) void dt_kernel(const float* __restrict__ zx,
                                                 const float* __restrict__ dt_bias,
                                                 const float* __restrict__ A_log,
                                                 float* __restrict__ dtv,
                                                 float* __restrict__ dAb) {
    int i = blockIdx.x * 256 + threadIdx.x;
    int hh = i & (NH - 1);
    int m = i >> 5;
    float raw = zx[(size_t)m * DIP + (DI + CD) + hh] + dt_bias[hh];
    float dt = (raw > 20.f) ? raw : log1pf(expf(raw));
    float dA = expf(-expf(A_log[hh]) * dt);
    dtv[i] = dt;
    dAb[i] = dA;
}

// ---------------- Kernel 5a: chunk reduce v3 (KT-batched LDS staging) ----------------
// Block 256 thr per (chunk, head, batch). Thread owns 4p x 8n (n split: ng*4 and 64+ng*4).
// One barrier per KT=8 timesteps; double-buffered LDS; issue-early/write-late staging.
__global__ __launch_bounds__(256, 2) void scan_reduce_kernel(const float* __restrict__ xBC,
                                                             const float* __restrict__ dAb,
                                                             const float* __restrict__ dtg,
                                                             float* __restrict__ S,
                                                             float* __restrict__ P) {
    int tid = threadIdx.x;
    int wave = tid >> 6, lane = tid & 63;
    int pg = lane >> 4, ng = lane & 15;
    int c = blockIdx.x, hh = blockIdx.y, b = blockIdx.z;
    int p0 = wave * 16 + pg * 4;
    int nA = ng * 4, nB = 64 + ng * 4;
    int tbeg = c * CL;

    __shared__ alignas(16) float sB[2][KT][128];
    __shared__ alignas(16) float sx[2][KT][64];
    __shared__ float sda[2][KT];
    __shared__ float sdt[2][KT];

    float h[4][8];
#pragma unroll
    for (int pp = 0; pp < 4; pp++)
#pragma unroll
        for (int nn = 0; nn < 8; nn++) h[pp][nn] = 0.f;
    float cd = 1.f;

    const float* base = xBC + (size_t)b * TT * CD;
    const float* dab = dAb + (size_t)b * TT * NH + hh;
    const float* dtb = dtg + (size_t)b * TT * NH + hh;

    // staging roles
    int btt = tid >> 5, boff = (tid & 31) * 4;          // B: 256 float4
    int xtt = tid >> 4, xoff = (tid & 15) * 4;          // x: 128 float4 (tid<128)

    float4 rB, rx;
    float rda = 0.f, rdt = 0.f;

    // prologue: group 0
    {
        int tb = tbeg;
        rB = *(const float4*)(base + (size_t)(tb + btt) * CD + DI + boff);
        if (tid < 128) rx = *(const float4*)(base + (size_t)(tb + xtt) * CD + hh * HD + xoff);
        if (tid >= 128 && tid < 128 + KT) rda = dab[(size_t)(tb + tid - 128) * NH];
        if (tid >= 144 && tid < 144 + KT) rdt = dtb[(size_t)(tb + tid - 144) * NH];
    }
    *(float4*)&sB[0][btt][boff] = rB;
    if (tid < 128) *(float4*)&sx[0][xtt][xoff] = rx;
    if (tid >= 128 && tid < 128 + KT) sda[0][tid - 128] = rda;
    if (tid >= 144 && tid < 144 + KT) sdt[0][tid - 144] = rdt;
    __syncthreads();

    const int NG = CL / KT;
    int buf = 0;
    for (int g = 0; g < NG; g++) {
        if (g + 1 < NG) {
            int tb = tbeg + (g + 1) * KT;
            rB = *(const float4*)(base + (size_t)(tb + btt) * CD + DI + boff);
            if (tid < 128) rx = *(const float4*)(base + (size_t)(tb + xtt) * CD + hh * HD + xoff);
            if (tid >= 128 && tid < 128 + KT) rda = dab[(size_t)(tb + tid - 128) * NH];
            if (tid >= 144 && tid < 144 + KT) rdt = dtb[(size_t)(tb + tid - 144) * NH];
        }
#pragma unroll
        for (int tt = 0; tt < KT; tt++) {
            float da = sda[buf][tt];
            float dtt = sdt[buf][tt];
            float4 xq = *(float4*)&sx[buf][tt][p0];
            float4 B0 = *(float4*)&sB[buf][tt][nA];
            float4 B1 = *(float4*)&sB[buf][tt][nB];
            float xdt[4] = {xq.x * dtt, xq.y * dtt, xq.z * dtt, xq.w * dtt};
#pragma unroll
            for (int pp = 0; pp < 4; pp++) {
                h[pp][0] = fmaf(h[pp][0], da, xdt[pp] * B0.x);
                h[pp][1] = fmaf(h[pp][1], da, xdt[pp] * B0.y);
                h[pp][2] = fmaf(h[pp][2], da, xdt[pp] * B0.z);
                h[pp][3] = fmaf(h[pp][3], da, xdt[pp] * B0.w);
                h[pp][4] = fmaf(h[pp][4], da, xdt[pp] * B1.x);
                h[pp][5] = fmaf(h[pp][5], da, xdt[pp] * B1.y);
                h[pp][6] = fmaf(h[pp][6], da, xdt[pp] * B1.z);
                h[pp][7] = fmaf(h[pp][7], da, xdt[pp] * B1.w);
            }
            cd *= da;
        }
        if (g + 1 < NG) {
            *(float4*)&sB[buf ^ 1][btt][boff] = rB;
            if (tid < 128) *(float4*)&sx[buf ^ 1][xtt][xoff] = rx;
            if (tid >= 128 && tid < 128 + KT) sda[buf ^ 1][tid - 128] = rda;
            if (tid >= 144 && tid < 144 + KT) sdt[buf ^ 1][tid - 144] = rdt;
            __syncthreads();
        }
        buf ^= 1;
    }

    float* Sp = S + (size_t)c * SELEMS + ((size_t)(b * NH + hh) * HD) * DSTATE;
#pragma unroll
    for (int pp = 0; pp < 4; pp++) {
        float* q = Sp + (size_t)(p0 + pp) * DSTATE;
        *(float4*)(q + nA) = make_float4(h[pp][0], h[pp][1], h[pp][2], h[pp][3]);
        *(float4*)(q + nB) = make_float4(h[pp][4], h[pp][5], h[pp][6], h[pp][7]);
    }
    if (tid == 0) P[(c * BB + b) * NH + hh] = cd;
}

// ---------------- Kernel 5b: sequential chunk combine ----------------
__global__ __launch_bounds__(256) void scan_combine_kernel(const float* __restrict__ h0,
                                                           const float* __restrict__ P,
                                                           float* __restrict__ S,
                                                           float* __restrict__ hT) {
    size_t tid = (size_t)blockIdx.x * 256 + threadIdx.x;
    int hh = (int)((tid >> 13) & 31);
    int b = (int)(tid >> 18);
    float h = h0[tid];
#pragma unroll
    for (int c = 0; c < NC; c++) {
        float s = S[(size_t)c * SELEMS + tid];
        S[(size_t)c * SELEMS + tid] = h;
        h = fmaf(P[(c * BB + b) * NH + hh], h, s);
    }
    hT[tid] = h;
}

// ---------------- Kernel 5c: chunk emit v3 (KT-batched LDS staging) ----------------
// B||C (1KB/t, contiguous) staged for 8 t's per barrier; y -> zx cols [2048,4096).
__global__ __launch_bounds__(256, 2) void scan_emit_kernel(const float* __restrict__ xBC,
                                                           const float* __restrict__ dAb,
                                                           const float* __restrict__ dtg,
                                                           const float* __restrict__ S,
                                                           const float* __restrict__ Dp,
                                                           float* __restrict__ zx) {
    int tid = threadIdx.x;
    int wave = tid >> 6, lane = tid & 63;
    int pg = lane >> 4, ng = lane & 15;
    int c = blockIdx.x, hh = blockIdx.y, b = blockIdx.z;
    int p0 = wave * 16 + pg * 4;
    int nA = ng * 4, nB = 64 + ng * 4;
    int tbeg = c * CL;

    __shared__ alignas(16) float sBC[2][KT][256];
    __shared__ alignas(16) float sx[2][KT][64];
    __shared__ float sda[2][KT];
    __shared__ float sdt[2][KT];

    float h[4][8];
    const float* Sp = S + (size_t)c * SELEMS + ((size_t)(b * NH + hh) * HD) * DSTATE;
#pragma unroll
    for (int pp = 0; pp < 4; pp++) {
        const float* q = Sp + (size_t)(p0 + pp) * DSTATE;
        float4 v0 = *(const float4*)(q + nA);
        float4 v1 = *(const float4*)(q + nB);
        h[pp][0] = v0.x; h[pp][1] = v0.y; h[pp][2] = v0.z; h[pp][3] = v0.w;
        h[pp][4] = v1.x; h[pp][5] = v1.y; h[pp][6] = v1.z; h[pp][7] = v1.w;
    }

    float Dh = Dp[hh];
    const float* base = xBC + (size_t)b * TT * CD;
    const float* dab = dAb + (size_t)b * TT * NH + hh;
    const float* dtb = dtg + (size_t)b * TT * NH + hh;
    float* yb = zx + (size_t)b * TT * DIP + DI + hh * HD + p0;

    // staging roles: BC = 512 float4 -> 2 per thread at [tt][off] and [tt+4][off]
    int ctt = tid >> 6, coff = (tid & 63) * 4;
    int xtt = tid >> 4, xoff = (tid & 15) * 4;

    float4 rBC0, rBC1, rx;
    float rda = 0.f, rdt = 0.f;

    {
        int tb = tbeg;
        rBC0 = *(const float4*)(base + (size_t)(tb + ctt) * CD + DI + coff);
        rBC1 = *(const float4*)(base + (size_t)(tb + ctt + 4) * CD + DI + coff);
        if (tid < 128) rx = *(const float4*)(base + (size_t)(tb + xtt) * CD + hh * HD + xoff);
        if (tid >= 128 && tid < 128 + KT) rda = dab[(size_t)(tb + tid - 128) * NH];
        if (tid >= 144 && tid < 144 + KT) rdt = dtb[(size_t)(tb + tid - 144) * NH];
    }
    *(float4*)&sBC[0][ctt][coff] = rBC0;
    *(float4*)&sBC[0][ctt + 4][coff] = rBC1;
    if (tid < 128) *(float4*)&sx[0][xtt][xoff] = rx;
    if (tid >= 128 && tid < 128 + KT) sda[0][tid - 128] = rda;
    if (tid >= 144 && tid < 144 + KT) sdt[0][tid - 144] = rdt;
    __syncthreads();

    const int NG = CL / KT;
    int buf = 0;
    for (int g = 0; g < NG; g++) {
        if (g + 1 < NG) {
            int tb = tbeg + (g + 1) * KT;
            rBC0 = *(const float4*)(base + (size_t)(tb + ctt) * CD + DI + coff);
            rBC1 = *(const float4*)(base + (size_t)(tb + ctt + 4) * CD + DI + coff);
            if (tid < 128) rx = *(const float4*)(base + (size_t)(tb + xtt) * CD + hh * HD + xoff);
            if (tid >= 128 && tid < 128 + KT) rda = dab[(size_t)(tb + tid - 128) * NH];
            if (tid >= 144 && tid < 144 + KT) rdt = dtb[(size_t)(tb + tid - 144) * NH];
        }
#pragma unroll
        for (int tt = 0; tt < KT; tt++) {
            float da = sda[buf][tt];
            float dtt = sdt[buf][tt];
            float4 xq = *(float4*)&sx[buf][tt][p0];
            float4 B0 = *(float4*)&sBC[buf][tt][nA];
            float4 B1 = *(float4*)&sBC[buf][tt][nB];
            float4 C0 = *(float4*)&sBC[buf][tt][128 + nA];
            float4 C1 = *(float4*)&sBC[buf][tt][128 + nB];
            float xdt[4] = {xq.x * dtt, xq.y * dtt, xq.z * dtt, xq.w * dtt};
            float ps[4] = {0.f, 0.f, 0.f, 0.f};
#pragma unroll
            for (int pp = 0; pp < 4; pp++) {
                float hv;
                hv = fmaf(h[pp][0], da, xdt[pp] * B0.x); h[pp][0] = hv; ps[pp] = fmaf(hv, C0.x, ps[pp]);
                hv = fmaf(h[pp][1], da, xdt[pp] * B0.y); h[pp][1] = hv; ps[pp] = fmaf(hv, C0.y, ps[pp]);
                hv = fmaf(h[pp][2], da, xdt[pp] * B0.z); h[pp][2] = hv; ps[pp] = fmaf(hv, C0.z, ps[pp]);
                hv = fmaf(h[pp][3], da, xdt[pp] * B0.w); h[pp][3] = hv; ps[pp] = fmaf(hv, C0.w, ps[pp]);
                hv = fmaf(h[pp][4], da, xdt[pp] * B1.x); h[pp][4] = hv; ps[pp] = fmaf(hv, C1.x, ps[pp]);
                hv = fmaf(h[pp][5], da, xdt[pp] * B1.y); h[pp][5] = hv; ps[pp] = fmaf(hv, C1.y, ps[pp]);
                hv = fmaf(h[pp][6], da, xdt[pp] * B1.z); h[pp][6] = hv; ps[pp] = fmaf(hv, C1.z, ps[pp]);
                hv = fmaf(h[pp][7], da, xdt[pp] * B1.w); h[pp][7] = hv; ps[pp] = fmaf(hv, C1.w, ps[pp]);
            }
#pragma unroll
            for (int pp = 0; pp < 4; pp++) {
                ps[pp] += __shfl_xor(ps[pp], 1);
                ps[pp] += __shfl_xor(ps[pp], 2);
                ps[pp] += __shfl_xor(ps[pp], 4);
                ps[pp] += __shfl_xor(ps[pp], 8);
            }
            if (ng == 0) {
                float4 yo = make_float4(ps[0] + Dh * xq.x, ps[1] + Dh * xq.y,
                                        ps[2] + Dh * xq.z, ps[3] + Dh * xq.w);
                *(float4*)(yb + (size_t)(tbeg + g * KT + tt) * DIP) = yo;
            }
        }
        if (g + 1 < NG) {
            *(float4*)&sBC[buf ^ 1][ctt][coff] = rBC0;
            *(float4*)&sBC[buf ^ 1][ctt + 4][coff] = rBC1;
            if (tid < 128) *(float4*)&sx[buf ^ 1][xtt][xoff] = rx;
            if (tid >= 128 && tid < 128 + KT) sda[buf ^ 1][tid - 128] = rda;
            if (tid >= 144 && tid < 144 + KT) sdt[buf ^ 1][tid - 144] = rdt;
            __syncthreads();
        }
        buf ^= 1;
    }
}

// ---------------- Kernel 6: gating + RMSNorm -> bf16 g ----------------
__global__ __launch_bounds__(256) void gate_rms_kernel(const float* __restrict__ zx,
                                                       const float* __restrict__ rw,
                                                       __hip_bfloat16* __restrict__ gq) {
    int m = blockIdx.x;
    int tid = threadIdx.x;
    const float* yr = zx + (size_t)m * DIP + DI;
    const float* zr = zx + (size_t)m * DIP;
    int base = tid * 8;
    float gv[8];
    float ss = 0.f;
    float4 ya = *(const float4*)(yr + base);
    float4 yb4 = *(const float4*)(yr + base + 4);
    float4 za = *(const float4*)(zr + base);
    float4 zb4 = *(const float4*)(zr + base + 4);
    float yv[8] = {ya.x, ya.y, ya.z, ya.w, yb4.x, yb4.y, yb4.z, yb4.w};
    float zv[8] = {za.x, za.y, za.z, za.w, zb4.x, zb4.y, zb4.z, zb4.w};
#pragma unroll
    for (int i = 0; i < 8; i++) {
        float sg = 1.f / (1.f + expf(-zv[i]));
        float gg = yv[i] * zv[i] * sg;
        gv[i] = gg;
        ss += gg * gg;
    }
#pragma unroll
    for (int off = 1; off < 64; off <<= 1) ss += __shfl_xor(ss, off);
    __shared__ float red[4];
    int w = tid >> 6;
    if ((tid & 63) == 0) red[w] = ss;
    __syncthreads();
    float tot = red[0] + red[1] + red[2] + red[3];
    float r = rsqrtf(tot * (1.f / DI) + 1e-5f);
#pragma unroll
    for (int i = 0; i < 8; i += 2) {
        __hip_bfloat162 p;
        p.x = __float2bfloat16(gv[i] * r * rw[base + i]);
        p.y = __float2bfloat16(gv[i + 1] * r * rw[base + i + 1]);
        *(__hip_bfloat162*)(gq + (size_t)m * DI + base + i) = p;
    }
}

// ---------------- Kernel 7: GEMM2 bf16 MFMA (transposed store) ----------------
__global__ __launch_bounds__(256) void gemm2_mfma(const __hip_bfloat16* __restrict__ gq,
                                                  const __hip_bfloat16* __restrict__ Wob,
                                                  float* __restrict__ out) {
    __shared__ short As[128][64];
    __shared__ short Bs[128][64];
    int tid = threadIdx.x;
    int lane = tid & 63;
    int wave = tid >> 6;
    int wr = wave >> 1, wc = wave & 1;
    int m0 = blockIdx.x * 128;
    int j0 = blockIdx.y * 128;
    int srow = tid >> 3;
    int skc = (tid & 7) * 8;

    f32x4 acc[4][4] = {};

    for (int k0 = 0; k0 < DI; k0 += 64) {
        __syncthreads();
#pragma unroll
        for (int q = 0; q < 4; q++) {
            gload16(gq + (size_t)(m0 + q * 32 + srow) * DI + k0 + skc,
                    ((short*)As) + q * 2048 + wave * 512);
            gload16(Wob + (size_t)(j0 + q * 32 + srow) * DI + k0 + skc,
                    ((short*)Bs) + q * 2048 + wave * 512);
        }
        asm volatile("s_waitcnt vmcnt(0)" ::: "memory");
        __syncthreads();
#pragma unroll
        for (int ks = 0; ks < 2; ks++) {
            bf16x8 af[4], bfr[4];
#pragma unroll
            for (int i = 0; i < 4; i++)
                af[i] = *(const bf16x8*)&As[wr * 64 + i * 16 + (lane & 15)][ks * 32 + (lane >> 4) * 8];
#pragma unroll
            for (int n = 0; n < 4; n++)
                bfr[n] = *(const bf16x8*)&Bs[wc * 64 + n * 16 + (lane & 15)][ks * 32 + (lane >> 4) * 8];
#pragma unroll
            for (int i = 0; i < 4; i++)
#pragma unroll
                for (int n = 0; n < 4; n++)
                    acc[i][n] = __builtin_amdgcn_mfma_f32_16x16x32_bf16(af[i], bfr[n], acc[i][n], 0, 0, 0);
        }
    }
#pragma unroll
    for (int i = 0; i < 4; i++) {
        int m = m0 + wr * 64 + i * 16 + ((lane >> 4) << 2);
        int b = m >> 12;
        int t = m & 4095;
#pragma unroll
        for (int n = 0; n < 4; n++) {
            int j = j0 + wc * 64 + n * 16 + (lane & 15);
            *(f32x4*)(out + (size_t)b * DM * TT + (size_t)j * TT + t) = acc[i][n];
        }
    }
}

extern "C" void kernel_launch(void* const* d_in, const int* in_sizes, int n_in,
                              void* d_out, int out_size, void* d_ws, size_t ws_size,
                              hipStream_t stream) {
    const float* x       = (const float*)d_in[0];
    const float* ln_w    = (const float*)d_in[1];
    const float* ln_b    = (const float*)d_in[2];
    const float* W_in    = (const float*)d_in[3];
    const float* conv_w  = (const float*)d_in[4];
    const float* conv_b  = (const float*)d_in[5];
    const float* dt_bias = (const float*)d_in[6];
    const float* A_log   = (const float*)d_in[7];
    const float* Dp      = (const float*)d_in[8];
    const float* rms_w   = (const float*)d_in[9];
    const float* W_out   = (const float*)d_in[10];
    const float* h0      = (const float*)d_in[11];

    float* out = (float*)d_out;
    float* hT = out + (size_t)BB * DM * TT;

    char* ws = (char*)d_ws;
    // Total footprint: 238,094,336 bytes (identical to proven layout).
    float* mu  = (float*)(ws + 0);
    float* rs  = (float*)(ws + 32768);
    float* zx  = (float*)(ws + 65536);        // 143,654,912  (B,T,4384) f32
    float* xBC = (float*)(ws + 143720448);    //  75,497,472  (phase B)
    __hip_bfloat16* Wb  = (__hip_bfloat16*)(ws + 143720448);              // phase A
    __hip_bfloat16* gq  = (__hip_bfloat16*)(ws + 143720448);              // phase C
    __hip_bfloat16* Wob = (__hip_bfloat16*)(ws + 143720448 + 41943040);   // phase C
    float* dAb = (float*)(ws + 219217920);
    float* dtv = (float*)(ws + 220266496);
    __hip_bfloat16* xnb = (__hip_bfloat16*)(ws + 221315072);   // shares with S
    float* S   = (float*)(ws + 221315072);
    float* P   = (float*)(ws + 238092288);

    ln_stats_kernel<<<dim3(TT / 64, BB), 64, 0, stream>>>(x, mu, rs);
    xn_kernel<<<dim3(TT / 64, DM / 64, BB), 256, 0, stream>>>(x, mu, rs, ln_w, ln_b, xnb);
    cvt_pad_kernel<<<(NP1 * DM) / 1024, 256, 0, stream>>>(W_in, Wb, DIP * DM, NP1 * DM);
    gemm1_mfma<<<dim3(NP1 / 128, (BB * TT) / 128), 256, 0, stream>>>(Wb, xnb, zx);
    gemm1_kernel<<<dim3(1, (BB * TT) / 64), 256, 0, stream>>>(x, mu, rs, ln_w, ln_b, W_in, zx, 4352);
    conv_kernel<<<(BB * TT * CD) / 256, 256, 0, stream>>>(zx, conv_w, conv_b, xBC);
    dt_kernel<<<(BB * TT * NH) / 256, 256, 0, stream>>>(zx, dt_bias, A_log, dtv, dAb);
    scan_reduce_kernel<<<dim3(NC, NH, BB), 256, 0, stream>>>(xBC, dAb, dtv, S, P);
    scan_combine_kernel<<<(int)(SELEMS / 256), 256, 0, stream>>>(h0, P, S, hT);
    scan_emit_kernel<<<dim3(NC, NH, BB), 256, 0, stream>>>(xBC, dAb, dtv, S, Dp, zx);
    cvt_pad_kernel<<<(DM * DI) / 1024, 256, 0, stream>>>(W_out, Wob, DM * DI, DM * DI);
    gate_rms_kernel<<<BB * TT, 256, 0, stream>>>(zx, rms_w, gq);
    gemm2_mfma<<<dim3((BB * TT) / 128, DM / 128), 256, 0, stream>>>(gq, Wob, out);
}

// Round 9
// 667.602 us; speedup vs baseline: 3.3276x; 1.3496x over previous
//
#include <hip/hip_runtime.h>
#include <hip/hip_bf16.h>
#include <math.h>

// Problem constants
#define BB 2
#define TT 4096
#define DM 1024
#define DSTATE 128
#define DI 2048
#define HD 64
#define NH 32
#define DIP 4384   // 2*DI + 2*DSTATE + NH
#define CD 2304    // DI + 2*DSTATE

// Chunked scan parameters
#define NC 8
#define CL 512
#define KT 8
#define FL 64            // SSD fine-chunk length
#define FPC (CL / FL)    // 8
#define SELEMS ((size_t)BB * NH * HD * DSTATE)   // 524288

#define NP1 4480   // DIP padded to multiple of 128 for MFMA staging

typedef __attribute__((ext_vector_type(8))) short bf16x8;
typedef __attribute__((ext_vector_type(4))) float f32x4;

__device__ inline void gload16(const void* g, void* l) {
    __builtin_amdgcn_global_load_lds(
        (const __attribute__((address_space(1))) void*)g,
        (__attribute__((address_space(3))) void*)l, 16, 0, 0);
}

__device__ inline short f2bs(float f) {
    __hip_bfloat16 h = __float2bfloat16(f);
    union { __hip_bfloat16 h; short s; } u;
    u.h = h;
    return u.s;
}
__device__ inline float b2f(short s) {
    union { float f; unsigned u; } u;
    u.u = ((unsigned)(unsigned short)s) << 16;
    return u.f;
}

// ---------------- Kernel 1: LayerNorm statistics ----------------
__global__ __launch_bounds__(64) void ln_stats_kernel(const float* __restrict__ x,
                                                      float* __restrict__ mu,
                                                      float* __restrict__ rs) {
    int t = blockIdx.x * 64 + threadIdx.x;
    int b = blockIdx.y;
    const float* xb = x + (size_t)b * DM * TT + t;
    float s = 0.f, ss = 0.f;
#pragma unroll 8
    for (int d = 0; d < DM; d++) {
        float v = xb[(size_t)d * TT];
        s += v;
        ss += v * v;
    }
    float m = s * (1.f / DM);
    float var = ss * (1.f / DM) - m * m;
    int idx = b * TT + t;
    mu[idx] = m;
    rs[idx] = rsqrtf(var + 1e-5f);
}

// ---------------- Kernel 1b: xn = LN(x) transposed to (m, k) in bf16 ----------------
__global__ __launch_bounds__(256) void xn_kernel(const float* __restrict__ x,
                                                 const float* __restrict__ mu,
                                                 const float* __restrict__ rs,
                                                 const float* __restrict__ ln_w,
                                                 const float* __restrict__ ln_b,
                                                 __hip_bfloat16* __restrict__ xn) {
    __shared__ float tile[64][65];
    int tid = threadIdx.x;
    int t0 = blockIdx.x * 64, d0 = blockIdx.y * 64, b = blockIdx.z;
#pragma unroll
    for (int i = 0; i < 64; i += 4) {
        int dl = i + (tid >> 6);
        tile[dl][tid & 63] = x[(size_t)b * DM * TT + (size_t)(d0 + dl) * TT + t0 + (tid & 63)];
    }
    __syncthreads();
#pragma unroll
    for (int i = 0; i < 64; i += 8) {
        int tl = i + (tid >> 5);
        int kk = (tid & 31) * 2;
        int m = b * TT + t0 + tl;
        float mu_m = mu[m], rs_m = rs[m];
        float v0 = (tile[kk][tl] - mu_m) * rs_m * ln_w[d0 + kk] + ln_b[d0 + kk];
        float v1 = (tile[kk + 1][tl] - mu_m) * rs_m * ln_w[d0 + kk + 1] + ln_b[d0 + kk + 1];
        __hip_bfloat162 pk;
        pk.x = __float2bfloat16(v0);
        pk.y = __float2bfloat16(v1);
        *(__hip_bfloat162*)(xn + (size_t)m * DM + d0 + kk) = pk;
    }
}

// ---------------- convert f32 -> bf16 with zero-padding ----------------
__global__ __launch_bounds__(256) void cvt_pad_kernel(const float* __restrict__ src,
                                                      __hip_bfloat16* __restrict__ dst,
                                                      int src_n, int tot_n) {
    int i = (blockIdx.x * 256 + threadIdx.x) * 4;
    if (i >= tot_n) return;
    float4 v = (i < src_n) ? *(const float4*)(src + i) : make_float4(0.f, 0.f, 0.f, 0.f);
    __hip_bfloat162 p0, p1;
    p0.x = __float2bfloat16(v.x); p0.y = __float2bfloat16(v.y);
    p1.x = __float2bfloat16(v.z); p1.y = __float2bfloat16(v.w);
    *(__hip_bfloat162*)(dst + i) = p0;
    *(__hip_bfloat162*)(dst + i + 2) = p1;
}

// ---------------- Kernel 2: GEMM1 bf16 MFMA ----------------
__global__ __launch_bounds__(256) void gemm1_mfma(const __hip_bfloat16* __restrict__ Wb,
                                                  const __hip_bfloat16* __restrict__ xn,
                                                  float* __restrict__ zx) {
    __shared__ short As[128][64];
    __shared__ short Bs[128][64];
    int tid = threadIdx.x;
    int lane = tid & 63;
    int wave = tid >> 6;
    int wr = wave >> 1, wc = wave & 1;
    int j0 = blockIdx.x * 128;
    int m0 = blockIdx.y * 128;
    int srow = tid >> 3;
    int skc = (tid & 7) * 8;

    f32x4 acc[4][4] = {};

    for (int k0 = 0; k0 < DM; k0 += 64) {
        __syncthreads();
#pragma unroll
        for (int q = 0; q < 4; q++) {
            gload16(Wb + (size_t)(j0 + q * 32 + srow) * DM + k0 + skc,
                    ((short*)As) + q * 2048 + wave * 512);
            gload16(xn + (size_t)(m0 + q * 32 + srow) * DM + k0 + skc,
                    ((short*)Bs) + q * 2048 + wave * 512);
        }
        asm volatile("s_waitcnt vmcnt(0)" ::: "memory");
        __syncthreads();
#pragma unroll
        for (int ks = 0; ks < 2; ks++) {
            bf16x8 af[4], bfr[4];
#pragma unroll
            for (int i = 0; i < 4; i++)
                af[i] = *(const bf16x8*)&As[wr * 64 + i * 16 + (lane & 15)][ks * 32 + (lane >> 4) * 8];
#pragma unroll
            for (int n = 0; n < 4; n++)
                bfr[n] = *(const bf16x8*)&Bs[wc * 64 + n * 16 + (lane & 15)][ks * 32 + (lane >> 4) * 8];
#pragma unroll
            for (int i = 0; i < 4; i++)
#pragma unroll
                for (int n = 0; n < 4; n++)
                    acc[i][n] = __builtin_amdgcn_mfma_f32_16x16x32_bf16(af[i], bfr[n], acc[i][n], 0, 0, 0);
        }
    }
#pragma unroll
    for (int i = 0; i < 4; i++) {
        int j = j0 + wr * 64 + i * 16 + ((lane >> 4) << 2);
        if (j < DIP) {
#pragma unroll
            for (int n = 0; n < 4; n++) {
                int m = m0 + wc * 64 + n * 16 + (lane & 15);
                *(f32x4*)(zx + (size_t)m * DIP + j) = acc[i][n];
            }
        }
    }
}

// ---------------- Kernel 2b: f32 strip GEMM for dt columns ----------------
__global__ __launch_bounds__(256) void gemm1_kernel(const float* __restrict__ x,
                                                    const float* __restrict__ mu,
                                                    const float* __restrict__ rs,
                                                    const float* __restrict__ ln_w,
                                                    const float* __restrict__ ln_b,
                                                    const float* __restrict__ Win,
                                                    float* __restrict__ zx,
                                                    int jbase) {
    __shared__ float As[16][64];
    __shared__ float Ws[64][17];
    int tid = threadIdx.x;
    int tx = tid & 15;
    int ty = tid >> 4;
    int j0 = jbase + blockIdx.x * 64;
    int m0 = blockIdx.y * 64;
    int b = m0 >> 12;
    int t0 = m0 & 4095;
    const float* Xb = x + (size_t)b * DM * TT + t0;

    int lr = tid >> 4;
    int lc = (tid & 15) * 4;
    int wr = tid >> 2;
    int wc = (tid & 3) * 4;

    float acc[4][4] = {};
    for (int k0 = 0; k0 < DM; k0 += 16) {
        float4 xv = *(const float4*)(Xb + (size_t)(k0 + lr) * TT + lc);
        float4 muv = *(const float4*)(&mu[m0 + lc]);
        float4 rsv = *(const float4*)(&rs[m0 + lc]);
        float lw = ln_w[k0 + lr], lb = ln_b[k0 + lr];
        As[lr][lc]     = (xv.x - muv.x) * rsv.x * lw + lb;
        As[lr][lc + 1] = (xv.y - muv.y) * rsv.y * lw + lb;
        As[lr][lc + 2] = (xv.z - muv.z) * rsv.z * lw + lb;
        As[lr][lc + 3] = (xv.w - muv.w) * rsv.w * lw + lb;

        int j = j0 + wr;
        float4 wv = make_float4(0.f, 0.f, 0.f, 0.f);
        if (j < DIP) wv = *(const float4*)(Win + (size_t)j * DM + k0 + wc);
        Ws[wr][wc] = wv.x; Ws[wr][wc + 1] = wv.y; Ws[wr][wc + 2] = wv.z; Ws[wr][wc + 3] = wv.w;
        __syncthreads();
#pragma unroll
        for (int kk = 0; kk < 16; kk++) {
            float4 a4 = *(const float4*)&As[kk][ty * 4];
            float a[4] = {a4.x, a4.y, a4.z, a4.w};
            float bv[4];
#pragma unroll
            for (int n = 0; n < 4; n++) bv[n] = Ws[tx * 4 + n][kk];
#pragma unroll
            for (int i = 0; i < 4; i++)
#pragma unroll
                for (int n = 0; n < 4; n++)
                    acc[i][n] = fmaf(a[i], bv[n], acc[i][n]);
        }
        __syncthreads();
    }
#pragma unroll
    for (int i = 0; i < 4; i++) {
        int m = m0 + ty * 4 + i;
        int j = j0 + tx * 4;
        if (j < DIP) {
            float4 v = make_float4(acc[i][0], acc[i][1], acc[i][2], acc[i][3]);
            *(float4*)(zx + (size_t)m * DIP + j) = v;
        }
    }
}

// ---------------- Kernel 3: causal depthwise conv(4) + SiLU ----------------
__global__ __launch_bounds__(256) void conv_kernel(const float* __restrict__ zx,
                                                   const float* __restrict__ cw,
                                                   const float* __restrict__ cb,
                                                   float* __restrict__ xBC) {
    int i = blockIdx.x * 256 + threadIdx.x;
    int c = i % CD;
    int t = (i / CD) & (TT - 1);
    int b = i / (CD * TT);
    const float* src = zx + (size_t)b * TT * DIP + DI + c;
    float acc = cb[c];
#pragma unroll
    for (int k = 0; k < 4; k++) {
        int ts = t - 3 + k;
        if (ts >= 0) acc = fmaf(cw[c * 4 + k], src[(size_t)ts * DIP], acc);
    }
    float sg = 1.f / (1.f + expf(-acc));
    xBC[(size_t)i] = acc * sg;
}

// ---------------- Kernel 4: dt softplus + dA ----------------
__global__ __launch_bounds__(256) void dt_kernel(const float* __restrict__ zx,
                                                 const float* __restrict__ dt_bias,
                                                 const float* __restrict__ A_log,
                                                 float* __restrict__ dtv,
                                                 float* __restrict__ dAb) {
    int i = blockIdx.x * 256 + threadIdx.x;
    int hh = i & (NH - 1);
    int m = i >> 5;
    float raw = zx[(size_t)m * DIP + (DI + CD) + hh] + dt_bias[hh];
    float dt = (raw > 20.f) ? raw : log1pf(expf(raw));
    float dA = expf(-expf(A_log[hh]) * dt);
    dtv[i] = dt;
    dAb[i] = dA;
}

// ---------------- Kernel 5a: chunk reduce v3 (KT-batched LDS staging) ----------------
__global__ __launch_bounds__(256, 2) void scan_reduce_kernel(const float* __restrict__ xBC,
                                                             const float* __restrict__ dAb,
                                                             const float* __restrict__ dtg,
                                                             float* __restrict__ S,
                                                             float* __restrict__ P) {
    int tid = threadIdx.x;
    int wave = tid >> 6, lane = tid & 63;
    int pg = lane >> 4, ng = lane & 15;
    int c = blockIdx.x, hh = blockIdx.y, b = blockIdx.z;
    int p0 = wave * 16 + pg * 4;
    int nA = ng * 4, nB = 64 + ng * 4;
    int tbeg = c * CL;

    __shared__ alignas(16) float sB[2][KT][128];
    __shared__ alignas(16) float sx[2][KT][64];
    __shared__ float sda[2][KT];
    __shared__ float sdt[2][KT];

    float h[4][8];
#pragma unroll
    for (int pp = 0; pp < 4; pp++)
#pragma unroll
        for (int nn = 0; nn < 8; nn++) h[pp][nn] = 0.f;
    float cd = 1.f;

    const float* base = xBC + (size_t)b * TT * CD;
    const float* dab = dAb + (size_t)b * TT * NH + hh;
    const float* dtb = dtg + (size_t)b * TT * NH + hh;

    int btt = tid >> 5, boff = (tid & 31) * 4;
    int xtt = tid >> 4, xoff = (tid & 15) * 4;

    float4 rB, rx;
    float rda = 0.f, rdt = 0.f;

    {
        int tb = tbeg;
        rB = *(const float4*)(base + (size_t)(tb + btt) * CD + DI + boff);
        if (tid < 128) rx = *(const float4*)(base + (size_t)(tb + xtt) * CD + hh * HD + xoff);
        if (tid >= 128 && tid < 128 + KT) rda = dab[(size_t)(tb + tid - 128) * NH];
        if (tid >= 144 && tid < 144 + KT) rdt = dtb[(size_t)(tb + tid - 144) * NH];
    }
    *(float4*)&sB[0][btt][boff] = rB;
    if (tid < 128) *(float4*)&sx[0][xtt][xoff] = rx;
    if (tid >= 128 && tid < 128 + KT) sda[0][tid - 128] = rda;
    if (tid >= 144 && tid < 144 + KT) sdt[0][tid - 144] = rdt;
    __syncthreads();

    const int NG = CL / KT;
    int buf = 0;
    for (int g = 0; g < NG; g++) {
        if (g + 1 < NG) {
            int tb = tbeg + (g + 1) * KT;
            rB = *(const float4*)(base + (size_t)(tb + btt) * CD + DI + boff);
            if (tid < 128) rx = *(const float4*)(base + (size_t)(tb + xtt) * CD + hh * HD + xoff);
            if (tid >= 128 && tid < 128 + KT) rda = dab[(size_t)(tb + tid - 128) * NH];
            if (tid >= 144 && tid < 144 + KT) rdt = dtb[(size_t)(tb + tid - 144) * NH];
        }
#pragma unroll
        for (int tt = 0; tt < KT; tt++) {
            float da = sda[buf][tt];
            float dtt = sdt[buf][tt];
            float4 xq = *(float4*)&sx[buf][tt][p0];
            float4 B0 = *(float4*)&sB[buf][tt][nA];
            float4 B1 = *(float4*)&sB[buf][tt][nB];
            float xdt[4] = {xq.x * dtt, xq.y * dtt, xq.z * dtt, xq.w * dtt};
#pragma unroll
            for (int pp = 0; pp < 4; pp++) {
                h[pp][0] = fmaf(h[pp][0], da, xdt[pp] * B0.x);
                h[pp][1] = fmaf(h[pp][1], da, xdt[pp] * B0.y);
                h[pp][2] = fmaf(h[pp][2], da, xdt[pp] * B0.z);
                h[pp][3] = fmaf(h[pp][3], da, xdt[pp] * B0.w);
                h[pp][4] = fmaf(h[pp][4], da, xdt[pp] * B1.x);
                h[pp][5] = fmaf(h[pp][5], da, xdt[pp] * B1.y);
                h[pp][6] = fmaf(h[pp][6], da, xdt[pp] * B1.z);
                h[pp][7] = fmaf(h[pp][7], da, xdt[pp] * B1.w);
            }
            cd *= da;
        }
        if (g + 1 < NG) {
            *(float4*)&sB[buf ^ 1][btt][boff] = rB;
            if (tid < 128) *(float4*)&sx[buf ^ 1][xtt][xoff] = rx;
            if (tid >= 128 && tid < 128 + KT) sda[buf ^ 1][tid - 128] = rda;
            if (tid >= 144 && tid < 144 + KT) sdt[buf ^ 1][tid - 144] = rdt;
            __syncthreads();
        }
        buf ^= 1;
    }

    float* Sp = S + (size_t)c * SELEMS + ((size_t)(b * NH + hh) * HD) * DSTATE;
#pragma unroll
    for (int pp = 0; pp < 4; pp++) {
        float* q = Sp + (size_t)(p0 + pp) * DSTATE;
        *(float4*)(q + nA) = make_float4(h[pp][0], h[pp][1], h[pp][2], h[pp][3]);
        *(float4*)(q + nB) = make_float4(h[pp][4], h[pp][5], h[pp][6], h[pp][7]);
    }
    if (tid == 0) P[(c * BB + b) * NH + hh] = cd;
}

// ---------------- Kernel 5b: sequential chunk combine ----------------
__global__ __launch_bounds__(256) void scan_combine_kernel(const float* __restrict__ h0,
                                                           const float* __restrict__ P,
                                                           float* __restrict__ S,
                                                           float* __restrict__ hT) {
    size_t tid = (size_t)blockIdx.x * 256 + threadIdx.x;
    int hh = (int)((tid >> 13) & 31);
    int b = (int)(tid >> 18);
    float h = h0[tid];
#pragma unroll
    for (int c = 0; c < NC; c++) {
        float s = S[(size_t)c * SELEMS + tid];
        S[(size_t)c * SELEMS + tid] = h;
        h = fmaf(P[(c * BB + b) * NH + hh], h, s);
    }
    hT[tid] = h;
}

// ---------------- Kernel 5c: SSD emit — per fine chunk of 64: MFMA G/M/Y + state ----------------
// Block = (coarse chunk, head, batch), 256 thr. Sequential over FPC=8 fine chunks.
// y -> zx cols [2048,4096) (f32), h_in from S (combine output, f32).
__global__ __launch_bounds__(256, 2) void scan_emit_ssd(const float* __restrict__ xBC,
                                                        const float* __restrict__ dtg,
                                                        const float* __restrict__ A_log,
                                                        const float* __restrict__ S,
                                                        const float* __restrict__ Dp,
                                                        float* __restrict__ zx) {
    int tid = threadIdx.x;
    int wave = tid >> 6, lane = tid & 63;
    int l4 = lane >> 4, l16 = lane & 15;
    int c = blockIdx.x, hh = blockIdx.y, b = blockIdx.z;
    int cbase = c * CL;

    __shared__ __align__(16) short CtL[64][136];   // C rows t, n-contig (pad 8)
    __shared__ __align__(16) short BtL[64][136];   // B rows s, n-contig
    __shared__ __align__(16) short hL[64][132];    // h_in rows p, n-contig (pad 4)
    __shared__ __align__(16) short XdL[64][72];    // xdt rows p, s-contig (pad 8)
    __shared__ __align__(16) short ML[64][72];     // M rows t, s-contig
    __shared__ __align__(16) float sdt[64];
    __shared__ __align__(16) float sL[64];
    __shared__ __align__(16) float sW[64];
    __shared__ __align__(16) float sRdt[64];

    // state accumulator in MFMA D-layout: D[n][p], wave owns n in [wave*32,+32)
    // n = wave*32 + i*16 + l4*4 + reg ; p = pq*16 + l16
    f32x4 acc_h[2][4];
    {
        const float* Sp = S + (size_t)c * SELEMS + ((size_t)(b * NH + hh) * HD) * DSTATE;
#pragma unroll
        for (int i = 0; i < 2; i++)
#pragma unroll
            for (int pq = 0; pq < 4; pq++) {
                int nb = wave * 32 + i * 16 + (l4 << 2);
                int p = pq * 16 + l16;
                acc_h[i][pq] = *(const f32x4*)(Sp + (size_t)p * DSTATE + nb);
            }
    }

    float expA = expf(A_log[hh]);
    float Dh = Dp[hh];
    const float* dtb = dtg + (size_t)b * TT * NH + hh;
    const float* xb = xBC + (size_t)b * TT * CD;
    float* yb = zx + (size_t)b * TT * DIP + DI + hh * HD;

    int tg = wave >> 1;   // t-half for G/Y
    int sg = wave & 1;    // s-half for G, p-half for Y

#pragma unroll 1
    for (int f = 0; f < FPC; f++) {
        int t0 = cbase + f * FL;

        // ---- P0: stage sdt, Ct, Bt, hL ----
        if (tid < 64) sdt[tid] = dtb[(size_t)(t0 + tid) * NH];
        {
            int r = tid >> 2, q = tid & 3;
            const float* cs = xb + (size_t)(t0 + r) * CD + DI + DSTATE + q * 32;
            const float* bs = xb + (size_t)(t0 + r) * CD + DI + q * 32;
#pragma unroll
            for (int j = 0; j < 4; j++) {
                float4 a0 = *(const float4*)(cs + j * 8);
                float4 a1 = *(const float4*)(cs + j * 8 + 4);
                short pk[8] = {f2bs(a0.x), f2bs(a0.y), f2bs(a0.z), f2bs(a0.w),
                               f2bs(a1.x), f2bs(a1.y), f2bs(a1.z), f2bs(a1.w)};
                *(bf16x8*)&CtL[r][q * 32 + j * 8] = *(bf16x8*)pk;
                float4 b0 = *(const float4*)(bs + j * 8);
                float4 b1 = *(const float4*)(bs + j * 8 + 4);
                short pb[8] = {f2bs(b0.x), f2bs(b0.y), f2bs(b0.z), f2bs(b0.w),
                               f2bs(b1.x), f2bs(b1.y), f2bs(b1.z), f2bs(b1.w)};
                *(bf16x8*)&BtL[r][q * 32 + j * 8] = *(bf16x8*)pb;
            }
        }
#pragma unroll
        for (int i = 0; i < 2; i++)
#pragma unroll
            for (int pq = 0; pq < 4; pq++) {
                int nb = wave * 32 + i * 16 + (l4 << 2);
                int p = pq * 16 + l16;
                *(short2*)&hL[p][nb] = make_short2(f2bs(acc_h[i][pq][0]), f2bs(acc_h[i][pq][1]));
                *(short2*)&hL[p][nb + 2] = make_short2(f2bs(acc_h[i][pq][2]), f2bs(acc_h[i][pq][3]));
            }
        __syncthreads();

        // ---- P1: within-chunk decay prefix scan (wave 0) ----
        if (tid < 64) {
            float v = -expA * sdt[tid];
#pragma unroll
            for (int off = 1; off < 64; off <<= 1) {
                float u = __shfl_up(v, off);
                if (lane >= off) v += u;
            }
            sL[tid] = v;
            float lt = __shfl(v, 63);
            sW[tid] = expf(lt - v);
            sRdt[tid] = 1.f / sdt[tid];
        }
        __syncthreads();

        // ---- P2: stage XdL (transposed xdt, bf16) ----
        {
            int s = tid & 63, pg = tid >> 6;
            const float* xs = xb + (size_t)(t0 + s) * CD + hh * HD + pg * 16;
            float dts = sdt[s];
#pragma unroll
            for (int j = 0; j < 4; j++) {
                float4 v = *(const float4*)(xs + j * 4);
                XdL[pg * 16 + j * 4 + 0][s] = f2bs(v.x * dts);
                XdL[pg * 16 + j * 4 + 1][s] = f2bs(v.y * dts);
                XdL[pg * 16 + j * 4 + 2][s] = f2bs(v.z * dts);
                XdL[pg * 16 + j * 4 + 3][s] = f2bs(v.w * dts);
            }
        }
        __syncthreads();

        // ---- P3: G = C@B^T, mask+decay -> ML ----
        {
            f32x4 g[2][2] = {};
#pragma unroll
            for (int ks = 0; ks < 4; ks++) {
                bf16x8 af[2], bfm[2];
#pragma unroll
                for (int i = 0; i < 2; i++)
                    af[i] = *(const bf16x8*)&CtL[tg * 32 + i * 16 + l16][ks * 32 + l4 * 8];
#pragma unroll
                for (int n = 0; n < 2; n++)
                    bfm[n] = *(const bf16x8*)&BtL[sg * 32 + n * 16 + l16][ks * 32 + l4 * 8];
#pragma unroll
                for (int i = 0; i < 2; i++)
#pragma unroll
                    for (int n = 0; n < 2; n++)
                        g[i][n] = __builtin_amdgcn_mfma_f32_16x16x32_bf16(af[i], bfm[n], g[i][n], 0, 0, 0);
            }
#pragma unroll
            for (int i = 0; i < 2; i++) {
                int tb2 = tg * 32 + i * 16 + (l4 << 2);
                float4 Lt = *(const float4*)&sL[tb2];
                float Ltr[4] = {Lt.x, Lt.y, Lt.z, Lt.w};
#pragma unroll
                for (int n = 0; n < 2; n++) {
                    int sE = sg * 32 + n * 16 + l16;
                    float Ls = sL[sE];
#pragma unroll
                    for (int r2 = 0; r2 < 4; r2++) {
                        float m = (sE <= tb2 + r2) ? g[i][n][r2] * expf(Ltr[r2] - Ls) : 0.f;
                        ML[tb2 + r2][sE] = f2bs(m);
                    }
                }
            }
        }
        __syncthreads();

        // ---- P4: Y = M@Xdt + exp(L[t])*(C@h_in) + Dh*x ; state update ----
        {
            f32x4 ay[2][2] = {};
            f32x4 ai[2][2] = {};
#pragma unroll
            for (int ks = 0; ks < 2; ks++) {
                bf16x8 af[2], bfp[2];
#pragma unroll
                for (int i = 0; i < 2; i++)
                    af[i] = *(const bf16x8*)&ML[tg * 32 + i * 16 + l16][ks * 32 + l4 * 8];
#pragma unroll
                for (int n = 0; n < 2; n++)
                    bfp[n] = *(const bf16x8*)&XdL[sg * 32 + n * 16 + l16][ks * 32 + l4 * 8];
#pragma unroll
                for (int i = 0; i < 2; i++)
#pragma unroll
                    for (int n = 0; n < 2; n++)
                        ay[i][n] = __builtin_amdgcn_mfma_f32_16x16x32_bf16(af[i], bfp[n], ay[i][n], 0, 0, 0);
            }
#pragma unroll
            for (int ks = 0; ks < 4; ks++) {
                bf16x8 af[2], bfh[2];
#pragma unroll
                for (int i = 0; i < 2; i++)
                    af[i] = *(const bf16x8*)&CtL[tg * 32 + i * 16 + l16][ks * 32 + l4 * 8];
#pragma unroll
                for (int n = 0; n < 2; n++) {
                    int prow = sg * 32 + n * 16 + l16;
                    int kb = ks * 32 + l4 * 8;
                    union { bf16x8 v; uint2 u2[2]; } hu;
                    hu.u2[0] = *(const uint2*)&hL[prow][kb];
                    hu.u2[1] = *(const uint2*)&hL[prow][kb + 4];
                    bfh[n] = hu.v;
                }
#pragma unroll
                for (int i = 0; i < 2; i++)
#pragma unroll
                    for (int n = 0; n < 2; n++)
                        ai[i][n] = __builtin_amdgcn_mfma_f32_16x16x32_bf16(af[i], bfh[n], ai[i][n], 0, 0, 0);
            }
            float Lft = sL[63];
#pragma unroll
            for (int i = 0; i < 2; i++) {
                int tb2 = tg * 32 + i * 16 + (l4 << 2);
                float4 Lt = *(const float4*)&sL[tb2];
                float4 Rt = *(const float4*)&sRdt[tb2];
                float Ltr[4] = {Lt.x, Lt.y, Lt.z, Lt.w};
                float Rtr[4] = {Rt.x, Rt.y, Rt.z, Rt.w};
#pragma unroll
                for (int n = 0; n < 2; n++) {
                    int p = sg * 32 + n * 16 + l16;
#pragma unroll
                    for (int r2 = 0; r2 < 4; r2++) {
                        float xv = b2f(XdL[p][tb2 + r2]) * Rtr[r2];
                        float yv = ay[i][n][r2] + expf(Ltr[r2]) * ai[i][n][r2] + Dh * xv;
                        yb[(size_t)(t0 + tb2 + r2) * DIP + p] = yv;
                    }
                }
            }
            // state update: acc_h = exp(Lftot)*acc_h + (B*W)^T @ Xdt
            float Pf = expf(Lft);
#pragma unroll
            for (int i = 0; i < 2; i++)
#pragma unroll
                for (int pq = 0; pq < 4; pq++)
                    acc_h[i][pq] *= Pf;
#pragma unroll
            for (int ks = 0; ks < 2; ks++) {
                bf16x8 af2[2], bfw[4];
#pragma unroll
                for (int i = 0; i < 2; i++) {
                    int nrow = wave * 32 + i * 16 + l16;
                    short e[8];
#pragma unroll
                    for (int j = 0; j < 8; j++) {
                        int s = ks * 32 + l4 * 8 + j;
                        e[j] = f2bs(b2f(BtL[s][nrow]) * sW[s]);
                    }
                    af2[i] = *(bf16x8*)e;
                }
#pragma unroll
                for (int pq = 0; pq < 4; pq++)
                    bfw[pq] = *(const bf16x8*)&XdL[pq * 16 + l16][ks * 32 + l4 * 8];
#pragma unroll
                for (int i = 0; i < 2; i++)
#pragma unroll
                    for (int pq = 0; pq < 4; pq++)
                        acc_h[i][pq] = __builtin_amdgcn_mfma_f32_16x16x32_bf16(af2[i], bfw[pq], acc_h[i][pq], 0, 0, 0);
            }
        }
        __syncthreads();
    }
}

// ---------------- Kernel 6: gating + RMSNorm -> bf16 g ----------------
__global__ __launch_bounds__(256) void gate_rms_kernel(const float* __restrict__ zx,
                                                       const float* __restrict__ rw,
                                                       __hip_bfloat16* __restrict__ gq) {
    int m = blockIdx.x;
    int tid = threadIdx.x;
    const float* yr = zx + (size_t)m * DIP + DI;
    const float* zr = zx + (size_t)m * DIP;
    int base = tid * 8;
    float gv[8];
    float ss = 0.f;
    float4 ya = *(const float4*)(yr + base);
    float4 yb4 = *(const float4*)(yr + base + 4);
    float4 za = *(const float4*)(zr + base);
    float4 zb4 = *(const float4*)(zr + base + 4);
    float yv[8] = {ya.x, ya.y, ya.z, ya.w, yb4.x, yb4.y, yb4.z, yb4.w};
    float zv[8] = {za.x, za.y, za.z, za.w, zb4.x, zb4.y, zb4.z, zb4.w};
#pragma unroll
    for (int i = 0; i < 8; i++) {
        float sg = 1.f / (1.f + expf(-zv[i]));
        float gg = yv[i] * zv[i] * sg;
        gv[i] = gg;
        ss += gg * gg;
    }
#pragma unroll
    for (int off = 1; off < 64; off <<= 1) ss += __shfl_xor(ss, off);
    __shared__ float red[4];
    int w = tid >> 6;
    if ((tid & 63) == 0) red[w] = ss;
    __syncthreads();
    float tot = red[0] + red[1] + red[2] + red[3];
    float r = rsqrtf(tot * (1.f / DI) + 1e-5f);
#pragma unroll
    for (int i = 0; i < 8; i += 2) {
        __hip_bfloat162 p;
        p.x = __float2bfloat16(gv[i] * r * rw[base + i]);
        p.y = __float2bfloat16(gv[i + 1] * r * rw[base + i + 1]);
        *(__hip_bfloat162*)(gq + (size_t)m * DI + base + i) = p;
    }
}

// ---------------- Kernel 7: GEMM2 bf16 MFMA (transposed store) ----------------
__global__ __launch_bounds__(256) void gemm2_mfma(const __hip_bfloat16* __restrict__ gq,
                                                  const __hip_bfloat16* __restrict__ Wob,
                                                  float* __restrict__ out) {
    __shared__ short As[128][64];
    __shared__ short Bs[128][64];
    int tid = threadIdx.x;
    int lane = tid & 63;
    int wave = tid >> 6;
    int wr = wave >> 1, wc = wave & 1;
    int m0 = blockIdx.x * 128;
    int j0 = blockIdx.y * 128;
    int srow = tid >> 3;
    int skc = (tid & 7) * 8;

    f32x4 acc[4][4] = {};

    for (int k0 = 0; k0 < DI; k0 += 64) {
        __syncthreads();
#pragma unroll
        for (int q = 0; q < 4; q++) {
            gload16(gq + (size_t)(m0 + q * 32 + srow) * DI + k0 + skc,
                    ((short*)As) + q * 2048 + wave * 512);
            gload16(Wob + (size_t)(j0 + q * 32 + srow) * DI + k0 + skc,
                    ((short*)Bs) + q * 2048 + wave * 512);
        }
        asm volatile("s_waitcnt vmcnt(0)" ::: "memory");
        __syncthreads();
#pragma unroll
        for (int ks = 0; ks < 2; ks++) {
            bf16x8 af[4], bfr[4];
#pragma unroll
            for (int i = 0; i < 4; i++)
                af[i] = *(const bf16x8*)&As[wr * 64 + i * 16 + (lane & 15)][ks * 32 + (lane >> 4) * 8];
#pragma unroll
            for (int n = 0; n < 4; n++)
                bfr[n] = *(const bf16x8*)&Bs[wc * 64 + n * 16 + (lane & 15)][ks * 32 + (lane >> 4) * 8];
#pragma unroll
            for (int i = 0; i < 4; i++)
#pragma unroll
                for (int n = 0; n < 4; n++)
                    acc[i][n] = __builtin_amdgcn_mfma_f32_16x16x32_bf16(af[i], bfr[n], acc[i][n], 0, 0, 0);
        }
    }
#pragma unroll
    for (int i = 0; i < 4; i++) {
        int m = m0 + wr * 64 + i * 16 + ((lane >> 4) << 2);
        int b = m >> 12;
        int t = m & 4095;
#pragma unroll
        for (int n = 0; n < 4; n++) {
            int j = j0 + wc * 64 + n * 16 + (lane & 15);
            *(f32x4*)(out + (size_t)b * DM * TT + (size_t)j * TT + t) = acc[i][n];
        }
    }
}

extern "C" void kernel_launch(void* const* d_in, const int* in_sizes, int n_in,
                              void* d_out, int out_size, void* d_ws, size_t ws_size,
                              hipStream_t stream) {
    const float* x       = (const float*)d_in[0];
    const float* ln_w    = (const float*)d_in[1];
    const float* ln_b    = (const float*)d_in[2];
    const float* W_in    = (const float*)d_in[3];
    const float* conv_w  = (const float*)d_in[4];
    const float* conv_b  = (const float*)d_in[5];
    const float* dt_bias = (const float*)d_in[6];
    const float* A_log   = (const float*)d_in[7];
    const float* Dp      = (const float*)d_in[8];
    const float* rms_w   = (const float*)d_in[9];
    const float* W_out   = (const float*)d_in[10];
    const float* h0      = (const float*)d_in[11];

    float* out = (float*)d_out;
    float* hT = out + (size_t)BB * DM * TT;

    char* ws = (char*)d_ws;
    // Total footprint: 238,094,336 bytes (identical to proven layout).
    float* mu  = (float*)(ws + 0);
    float* rs  = (float*)(ws + 32768);
    float* zx  = (float*)(ws + 65536);        // 143,654,912  (B,T,4384) f32
    float* xBC = (float*)(ws + 143720448);    //  75,497,472  (phase B)
    __hip_bfloat16* Wb  = (__hip_bfloat16*)(ws + 143720448);              // phase A
    __hip_bfloat16* gq  = (__hip_bfloat16*)(ws + 143720448);              // phase C
    __hip_bfloat16* Wob = (__hip_bfloat16*)(ws + 143720448 + 41943040);   // phase C
    float* dAb = (float*)(ws + 219217920);
    float* dtv = (float*)(ws + 220266496);
    __hip_bfloat16* xnb = (__hip_bfloat16*)(ws + 221315072);   // shares with S
    float* S   = (float*)(ws + 221315072);
    float* P   = (float*)(ws + 238092288);

    ln_stats_kernel<<<dim3(TT / 64, BB), 64, 0, stream>>>(x, mu, rs);
    xn_kernel<<<dim3(TT / 64, DM / 64, BB), 256, 0, stream>>>(x, mu, rs, ln_w, ln_b, xnb);
    cvt_pad_kernel<<<(NP1 * DM) / 1024, 256, 0, stream>>>(W_in, Wb, DIP * DM, NP1 * DM);
    gemm1_mfma<<<dim3(NP1 / 128, (BB * TT) / 128), 256, 0, stream>>>(Wb, xnb, zx);
    gemm1_kernel<<<dim3(1, (BB * TT) / 64), 256, 0, stream>>>(x, mu, rs, ln_w, ln_b, W_in, zx, 4352);
    conv_kernel<<<(BB * TT * CD) / 256, 256, 0, stream>>>(zx, conv_w, conv_b, xBC);
    dt_kernel<<<(BB * TT * NH) / 256, 256, 0, stream>>>(zx, dt_bias, A_log, dtv, dAb);
    scan_reduce_kernel<<<dim3(NC, NH, BB), 256, 0, stream>>>(xBC, dAb, dtv, S, P);
    scan_combine_kernel<<<(int)(SELEMS / 256), 256, 0, stream>>>(h0, P, S, hT);
    scan_emit_ssd<<<dim3(NC, NH, BB), 256, 0, stream>>>(xBC, dtv, A_log, S, Dp, zx);
    cvt_pad_kernel<<<(DM * DI) / 1024, 256, 0, stream>>>(W_out, Wob, DM * DI, DM * DI);
    gate_rms_kernel<<<BB * TT, 256, 0, stream>>>(zx, rms_w, gq);
    gemm2_mfma<<<dim3((BB * TT) / 128, DM / 128), 256, 0, stream>>>(gq, Wob, out);
}

// Round 10
// 581.368 us; speedup vs baseline: 3.8212x; 1.1483x over previous
//
#include <hip/hip_runtime.h>
#include <hip/hip_bf16.h>
#include <math.h>

// Problem constants
#define BB 2
#define TT 4096
#define DM 1024
#define DSTATE 128
#define DI 2048
#define HD 64
#define NH 32
#define DIP 4384   // 2*DI + 2*DSTATE + NH
#define CD 2304    // DI + 2*DSTATE

// Chunked scan parameters
#define NC 8
#define CL 512
#define FL 64            // SSD fine-chunk length
#define FPC (CL / FL)    // 8
#define SELEMS ((size_t)BB * NH * HD * DSTATE)   // 524288

#define NP1 4480   // DIP padded to multiple of 128 for MFMA staging

typedef __attribute__((ext_vector_type(8))) short bf16x8;
typedef __attribute__((ext_vector_type(4))) float f32x4;

__device__ inline void gload16(const void* g, void* l) {
    __builtin_amdgcn_global_load_lds(
        (const __attribute__((address_space(1))) void*)g,
        (__attribute__((address_space(3))) void*)l, 16, 0, 0);
}

__device__ inline short f2bs(float f) {
    __hip_bfloat16 h = __float2bfloat16(f);
    union { __hip_bfloat16 h; short s; } u;
    u.h = h;
    return u.s;
}
__device__ inline float b2f(short s) {
    union { float f; unsigned u; } u;
    u.u = ((unsigned)(unsigned short)s) << 16;
    return u.f;
}

// ---------------- Kernel 1: LayerNorm statistics ----------------
__global__ __launch_bounds__(64) void ln_stats_kernel(const float* __restrict__ x,
                                                      float* __restrict__ mu,
                                                      float* __restrict__ rs) {
    int t = blockIdx.x * 64 + threadIdx.x;
    int b = blockIdx.y;
    const float* xb = x + (size_t)b * DM * TT + t;
    float s = 0.f, ss = 0.f;
#pragma unroll 8
    for (int d = 0; d < DM; d++) {
        float v = xb[(size_t)d * TT];
        s += v;
        ss += v * v;
    }
    float m = s * (1.f / DM);
    float var = ss * (1.f / DM) - m * m;
    int idx = b * TT + t;
    mu[idx] = m;
    rs[idx] = rsqrtf(var + 1e-5f);
}

// ---------------- Kernel 1b: xn = LN(x) transposed to (m, k) in bf16 ----------------
__global__ __launch_bounds__(256) void xn_kernel(const float* __restrict__ x,
                                                 const float* __restrict__ mu,
                                                 const float* __restrict__ rs,
                                                 const float* __restrict__ ln_w,
                                                 const float* __restrict__ ln_b,
                                                 __hip_bfloat16* __restrict__ xn) {
    __shared__ float tile[64][65];
    int tid = threadIdx.x;
    int t0 = blockIdx.x * 64, d0 = blockIdx.y * 64, b = blockIdx.z;
#pragma unroll
    for (int i = 0; i < 64; i += 4) {
        int dl = i + (tid >> 6);
        tile[dl][tid & 63] = x[(size_t)b * DM * TT + (size_t)(d0 + dl) * TT + t0 + (tid & 63)];
    }
    __syncthreads();
#pragma unroll
    for (int i = 0; i < 64; i += 8) {
        int tl = i + (tid >> 5);
        int kk = (tid & 31) * 2;
        int m = b * TT + t0 + tl;
        float mu_m = mu[m], rs_m = rs[m];
        float v0 = (tile[kk][tl] - mu_m) * rs_m * ln_w[d0 + kk] + ln_b[d0 + kk];
        float v1 = (tile[kk + 1][tl] - mu_m) * rs_m * ln_w[d0 + kk + 1] + ln_b[d0 + kk + 1];
        __hip_bfloat162 pk;
        pk.x = __float2bfloat16(v0);
        pk.y = __float2bfloat16(v1);
        *(__hip_bfloat162*)(xn + (size_t)m * DM + d0 + kk) = pk;
    }
}

// ---------------- convert f32 -> bf16 with zero-padding ----------------
__global__ __launch_bounds__(256) void cvt_pad_kernel(const float* __restrict__ src,
                                                      __hip_bfloat16* __restrict__ dst,
                                                      int src_n, int tot_n) {
    int i = (blockIdx.x * 256 + threadIdx.x) * 4;
    if (i >= tot_n) return;
    float4 v = (i < src_n) ? *(const float4*)(src + i) : make_float4(0.f, 0.f, 0.f, 0.f);
    __hip_bfloat162 p0, p1;
    p0.x = __float2bfloat16(v.x); p0.y = __float2bfloat16(v.y);
    p1.x = __float2bfloat16(v.z); p1.y = __float2bfloat16(v.w);
    *(__hip_bfloat162*)(dst + i) = p0;
    *(__hip_bfloat162*)(dst + i + 2) = p1;
}

// ---------------- Kernel 2: GEMM1 bf16 MFMA (T2 XOR-swizzled LDS) ----------------
// Swizzle: LDS[r][ch] = G[r][ch ^ (r&7)] (16B chunks). gload_lds dest stays linear;
// the global SOURCE chunk is pre-swizzled; reads apply the same XOR (rule #21).
__global__ __launch_bounds__(256) void gemm1_mfma(const __hip_bfloat16* __restrict__ Wb,
                                                  const __hip_bfloat16* __restrict__ xn,
                                                  float* __restrict__ zx) {
    __shared__ short As[128][64];
    __shared__ short Bs[128][64];
    int tid = threadIdx.x;
    int lane = tid & 63;
    int wave = tid >> 6;
    int wr = wave >> 1, wc = wave & 1;
    int j0 = blockIdx.x * 128;
    int m0 = blockIdx.y * 128;
    int srow = tid >> 3;
    int skc = (((tid & 7) ^ ((tid >> 3) & 7)) * 8);   // pre-swizzled source k-chunk

    f32x4 acc[4][4] = {};

    for (int k0 = 0; k0 < DM; k0 += 64) {
        __syncthreads();
#pragma unroll
        for (int q = 0; q < 4; q++) {
            gload16(Wb + (size_t)(j0 + q * 32 + srow) * DM + k0 + skc,
                    ((short*)As) + q * 2048 + wave * 512);
            gload16(xn + (size_t)(m0 + q * 32 + srow) * DM + k0 + skc,
                    ((short*)Bs) + q * 2048 + wave * 512);
        }
        asm volatile("s_waitcnt vmcnt(0)" ::: "memory");
        __syncthreads();
#pragma unroll
        for (int ks = 0; ks < 2; ks++) {
            int pch = (((ks * 4) + (lane >> 4)) ^ (lane & 7)) * 8;   // row&7 == lane&7
            bf16x8 af[4], bfr[4];
#pragma unroll
            for (int i = 0; i < 4; i++)
                af[i] = *(const bf16x8*)&As[wr * 64 + i * 16 + (lane & 15)][pch];
#pragma unroll
            for (int n = 0; n < 4; n++)
                bfr[n] = *(const bf16x8*)&Bs[wc * 64 + n * 16 + (lane & 15)][pch];
#pragma unroll
            for (int i = 0; i < 4; i++)
#pragma unroll
                for (int n = 0; n < 4; n++)
                    acc[i][n] = __builtin_amdgcn_mfma_f32_16x16x32_bf16(af[i], bfr[n], acc[i][n], 0, 0, 0);
        }
    }
#pragma unroll
    for (int i = 0; i < 4; i++) {
        int j = j0 + wr * 64 + i * 16 + ((lane >> 4) << 2);
        if (j < DIP) {
#pragma unroll
            for (int n = 0; n < 4; n++) {
                int m = m0 + wc * 64 + n * 16 + (lane & 15);
                *(f32x4*)(zx + (size_t)m * DIP + j) = acc[i][n];
            }
        }
    }
}

// ---------------- Kernel 2b: f32 strip GEMM for dt columns ----------------
__global__ __launch_bounds__(256) void gemm1_kernel(const float* __restrict__ x,
                                                    const float* __restrict__ mu,
                                                    const float* __restrict__ rs,
                                                    const float* __restrict__ ln_w,
                                                    const float* __restrict__ ln_b,
                                                    const float* __restrict__ Win,
                                                    float* __restrict__ zx,
                                                    int jbase) {
    __shared__ float As[16][64];
    __shared__ float Ws[64][17];
    int tid = threadIdx.x;
    int tx = tid & 15;
    int ty = tid >> 4;
    int j0 = jbase + blockIdx.x * 64;
    int m0 = blockIdx.y * 64;
    int b = m0 >> 12;
    int t0 = m0 & 4095;
    const float* Xb = x + (size_t)b * DM * TT + t0;

    int lr = tid >> 4;
    int lc = (tid & 15) * 4;
    int wr = tid >> 2;
    int wc = (tid & 3) * 4;

    float acc[4][4] = {};
    for (int k0 = 0; k0 < DM; k0 += 16) {
        float4 xv = *(const float4*)(Xb + (size_t)(k0 + lr) * TT + lc);
        float4 muv = *(const float4*)(&mu[m0 + lc]);
        float4 rsv = *(const float4*)(&rs[m0 + lc]);
        float lw = ln_w[k0 + lr], lb = ln_b[k0 + lr];
        As[lr][lc]     = (xv.x - muv.x) * rsv.x * lw + lb;
        As[lr][lc + 1] = (xv.y - muv.y) * rsv.y * lw + lb;
        As[lr][lc + 2] = (xv.z - muv.z) * rsv.z * lw + lb;
        As[lr][lc + 3] = (xv.w - muv.w) * rsv.w * lw + lb;

        int j = j0 + wr;
        float4 wv = make_float4(0.f, 0.f, 0.f, 0.f);
        if (j < DIP) wv = *(const float4*)(Win + (size_t)j * DM + k0 + wc);
        Ws[wr][wc] = wv.x; Ws[wr][wc + 1] = wv.y; Ws[wr][wc + 2] = wv.z; Ws[wr][wc + 3] = wv.w;
        __syncthreads();
#pragma unroll
        for (int kk = 0; kk < 16; kk++) {
            float4 a4 = *(const float4*)&As[kk][ty * 4];
            float a[4] = {a4.x, a4.y, a4.z, a4.w};
            float bv[4];
#pragma unroll
            for (int n = 0; n < 4; n++) bv[n] = Ws[tx * 4 + n][kk];
#pragma unroll
            for (int i = 0; i < 4; i++)
#pragma unroll
                for (int n = 0; n < 4; n++)
                    acc[i][n] = fmaf(a[i], bv[n], acc[i][n]);
        }
        __syncthreads();
    }
#pragma unroll
    for (int i = 0; i < 4; i++) {
        int m = m0 + ty * 4 + i;
        int j = j0 + tx * 4;
        if (j < DIP) {
            float4 v = make_float4(acc[i][0], acc[i][1], acc[i][2], acc[i][3]);
            *(float4*)(zx + (size_t)m * DIP + j) = v;
        }
    }
}

// ---------------- Kernel 3: causal depthwise conv(4) + SiLU ----------------
__global__ __launch_bounds__(256) void conv_kernel(const float* __restrict__ zx,
                                                   const float* __restrict__ cw,
                                                   const float* __restrict__ cb,
                                                   float* __restrict__ xBC) {
    int i = blockIdx.x * 256 + threadIdx.x;
    int c = i % CD;
    int t = (i / CD) & (TT - 1);
    int b = i / (CD * TT);
    const float* src = zx + (size_t)b * TT * DIP + DI + c;
    float acc = cb[c];
#pragma unroll
    for (int k = 0; k < 4; k++) {
        int ts = t - 3 + k;
        if (ts >= 0) acc = fmaf(cw[c * 4 + k], src[(size_t)ts * DIP], acc);
    }
    float sg = 1.f / (1.f + expf(-acc));
    xBC[(size_t)i] = acc * sg;
}

// ---------------- Kernel 4: dt softplus + dA ----------------
__global__ __launch_bounds__(256) void dt_kernel(const float* __restrict__ zx,
                                                 const float* __restrict__ dt_bias,
                                                 const float* __restrict__ A_log,
                                                 float* __restrict__ dtv,
                                                 float* __restrict__ dAb) {
    int i = blockIdx.x * 256 + threadIdx.x;
    int hh = i & (NH - 1);
    int m = i >> 5;
    float raw = zx[(size_t)m * DIP + (DI + CD) + hh] + dt_bias[hh];
    float dt = (raw > 20.f) ? raw : log1pf(expf(raw));
    float dA = expf(-expf(A_log[hh]) * dt);
    dtv[i] = dt;
    dAb[i] = dA;
}

// ---------------- Kernel 5a: SSD chunk reduce — MFMA state-only pass ----------------
// Block = (coarse chunk, head, batch). Per fine chunk of 64:
//   acc_h = exp(Lf)*acc_h + (B*W)^T @ Xdt   (same verified machinery as emit P4)
// Stores S[c] (chunk-final state from zero, f32 [p][n]) and P[c] = exp(sum L).
__global__ __launch_bounds__(256, 2) void scan_reduce_ssd(const float* __restrict__ xBC,
                                                          const float* __restrict__ dtg,
                                                          const float* __restrict__ A_log,
                                                          float* __restrict__ S,
                                                          float* __restrict__ P) {
    int tid = threadIdx.x;
    int wave = tid >> 6, lane = tid & 63;
    int l4 = lane >> 4, l16 = lane & 15;
    int c = blockIdx.x, hh = blockIdx.y, b = blockIdx.z;
    int cbase = c * CL;

    __shared__ __align__(16) short BtL[64][136];
    __shared__ __align__(16) short XdL[64][72];
    __shared__ __align__(16) float sdt[64];
    __shared__ __align__(16) float sL[64];
    __shared__ __align__(16) float sW[64];

    f32x4 acc_h[2][4];
#pragma unroll
    for (int i = 0; i < 2; i++)
#pragma unroll
        for (int pq = 0; pq < 4; pq++) acc_h[i][pq] = (f32x4){0.f, 0.f, 0.f, 0.f};
    float Lsum = 0.f;

    float expA = expf(A_log[hh]);
    const float* dtb = dtg + (size_t)b * TT * NH + hh;
    const float* xb = xBC + (size_t)b * TT * CD;

#pragma unroll 1
    for (int f = 0; f < FPC; f++) {
        int t0 = cbase + f * FL;
        if (tid < 64) sdt[tid] = dtb[(size_t)(t0 + tid) * NH];
        {
            int r = tid >> 2, q = tid & 3;
            const float* bs = xb + (size_t)(t0 + r) * CD + DI + q * 32;
#pragma unroll
            for (int j = 0; j < 4; j++) {
                float4 b0 = *(const float4*)(bs + j * 8);
                float4 b1 = *(const float4*)(bs + j * 8 + 4);
                short pb[8] = {f2bs(b0.x), f2bs(b0.y), f2bs(b0.z), f2bs(b0.w),
                               f2bs(b1.x), f2bs(b1.y), f2bs(b1.z), f2bs(b1.w)};
                *(bf16x8*)&BtL[r][q * 32 + j * 8] = *(bf16x8*)pb;
            }
        }
        __syncthreads();
        if (tid < 64) {
            float v = -expA * sdt[tid];
#pragma unroll
            for (int off = 1; off < 64; off <<= 1) {
                float u = __shfl_up(v, off);
                if (lane >= off) v += u;
            }
            sL[tid] = v;
            float lt = __shfl(v, 63);
            sW[tid] = expf(lt - v);
        }
        __syncthreads();
        {
            int s = tid & 63, pg2 = tid >> 6;
            const float* xs = xb + (size_t)(t0 + s) * CD + hh * HD + pg2 * 16;
            float dts = sdt[s];
#pragma unroll
            for (int j = 0; j < 4; j++) {
                float4 v = *(const float4*)(xs + j * 4);
                XdL[pg2 * 16 + j * 4 + 0][s] = f2bs(v.x * dts);
                XdL[pg2 * 16 + j * 4 + 1][s] = f2bs(v.y * dts);
                XdL[pg2 * 16 + j * 4 + 2][s] = f2bs(v.z * dts);
                XdL[pg2 * 16 + j * 4 + 3][s] = f2bs(v.w * dts);
            }
        }
        __syncthreads();
        float Lft = sL[63];
        float Pf = expf(Lft);
        Lsum += Lft;
#pragma unroll
        for (int i = 0; i < 2; i++)
#pragma unroll
            for (int pq = 0; pq < 4; pq++) acc_h[i][pq] *= Pf;
#pragma unroll
        for (int ks = 0; ks < 2; ks++) {
            bf16x8 af2[2], bfw[4];
#pragma unroll
            for (int i = 0; i < 2; i++) {
                int nrow = wave * 32 + i * 16 + l16;
                short e[8];
#pragma unroll
                for (int j = 0; j < 8; j++) {
                    int s = ks * 32 + l4 * 8 + j;
                    e[j] = f2bs(b2f(BtL[s][nrow]) * sW[s]);
                }
                af2[i] = *(bf16x8*)e;
            }
#pragma unroll
            for (int pq = 0; pq < 4; pq++)
                bfw[pq] = *(const bf16x8*)&XdL[pq * 16 + l16][ks * 32 + l4 * 8];
#pragma unroll
            for (int i = 0; i < 2; i++)
#pragma unroll
                for (int pq = 0; pq < 4; pq++)
                    acc_h[i][pq] = __builtin_amdgcn_mfma_f32_16x16x32_bf16(af2[i], bfw[pq], acc_h[i][pq], 0, 0, 0);
        }
        __syncthreads();
    }

    float* Sp = S + (size_t)c * SELEMS + ((size_t)(b * NH + hh) * HD) * DSTATE;
#pragma unroll
    for (int i = 0; i < 2; i++)
#pragma unroll
        for (int pq = 0; pq < 4; pq++) {
            int nb = wave * 32 + i * 16 + (l4 << 2);
            int p = pq * 16 + l16;
            *(f32x4*)(Sp + (size_t)p * DSTATE + nb) = acc_h[i][pq];
        }
    if (tid == 0) P[(c * BB + b) * NH + hh] = expf(Lsum);
}

// ---------------- Kernel 5b: sequential chunk combine ----------------
__global__ __launch_bounds__(256) void scan_combine_kernel(const float* __restrict__ h0,
                                                           const float* __restrict__ P,
                                                           float* __restrict__ S,
                                                           float* __restrict__ hT) {
    size_t tid = (size_t)blockIdx.x * 256 + threadIdx.x;
    int hh = (int)((tid >> 13) & 31);
    int b = (int)(tid >> 18);
    float h = h0[tid];
#pragma unroll
    for (int c = 0; c < NC; c++) {
        float s = S[(size_t)c * SELEMS + tid];
        S[(size_t)c * SELEMS + tid] = h;
        h = fmaf(P[(c * BB + b) * NH + hh], h, s);
    }
    hT[tid] = h;
}

// ---------------- Kernel 5c: SSD emit — per fine chunk of 64: MFMA G/M/Y + state ----------------
__global__ __launch_bounds__(256, 2) void scan_emit_ssd(const float* __restrict__ xBC,
                                                        const float* __restrict__ dtg,
                                                        const float* __restrict__ A_log,
                                                        const float* __restrict__ S,
                                                        const float* __restrict__ Dp,
                                                        float* __restrict__ zx) {
    int tid = threadIdx.x;
    int wave = tid >> 6, lane = tid & 63;
    int l4 = lane >> 4, l16 = lane & 15;
    int c = blockIdx.x, hh = blockIdx.y, b = blockIdx.z;
    int cbase = c * CL;

    __shared__ __align__(16) short CtL[64][136];
    __shared__ __align__(16) short BtL[64][136];
    __shared__ __align__(16) short hL[64][132];
    __shared__ __align__(16) short XdL[64][72];
    __shared__ __align__(16) short ML[64][72];
    __shared__ __align__(16) float sdt[64];
    __shared__ __align__(16) float sL[64];
    __shared__ __align__(16) float sW[64];
    __shared__ __align__(16) float sRdt[64];

    f32x4 acc_h[2][4];
    {
        const float* Sp = S + (size_t)c * SELEMS + ((size_t)(b * NH + hh) * HD) * DSTATE;
#pragma unroll
        for (int i = 0; i < 2; i++)
#pragma unroll
            for (int pq = 0; pq < 4; pq++) {
                int nb = wave * 32 + i * 16 + (l4 << 2);
                int p = pq * 16 + l16;
                acc_h[i][pq] = *(const f32x4*)(Sp + (size_t)p * DSTATE + nb);
            }
    }

    float expA = expf(A_log[hh]);
    float Dh = Dp[hh];
    const float* dtb = dtg + (size_t)b * TT * NH + hh;
    const float* xb = xBC + (size_t)b * TT * CD;
    float* yb = zx + (size_t)b * TT * DIP + DI + hh * HD;

    int tg = wave >> 1;
    int sg = wave & 1;

#pragma unroll 1
    for (int f = 0; f < FPC; f++) {
        int t0 = cbase + f * FL;

        if (tid < 64) sdt[tid] = dtb[(size_t)(t0 + tid) * NH];
        {
            int r = tid >> 2, q = tid & 3;
            const float* cs = xb + (size_t)(t0 + r) * CD + DI + DSTATE + q * 32;
            const float* bs = xb + (size_t)(t0 + r) * CD + DI + q * 32;
#pragma unroll
            for (int j = 0; j < 4; j++) {
                float4 a0 = *(const float4*)(cs + j * 8);
                float4 a1 = *(const float4*)(cs + j * 8 + 4);
                short pk[8] = {f2bs(a0.x), f2bs(a0.y), f2bs(a0.z), f2bs(a0.w),
                               f2bs(a1.x), f2bs(a1.y), f2bs(a1.z), f2bs(a1.w)};
                *(bf16x8*)&CtL[r][q * 32 + j * 8] = *(bf16x8*)pk;
                float4 b0 = *(const float4*)(bs + j * 8);
                float4 b1 = *(const float4*)(bs + j * 8 + 4);
                short pb[8] = {f2bs(b0.x), f2bs(b0.y), f2bs(b0.z), f2bs(b0.w),
                               f2bs(b1.x), f2bs(b1.y), f2bs(b1.z), f2bs(b1.w)};
                *(bf16x8*)&BtL[r][q * 32 + j * 8] = *(bf16x8*)pb;
            }
        }
#pragma unroll
        for (int i = 0; i < 2; i++)
#pragma unroll
            for (int pq = 0; pq < 4; pq++) {
                int nb = wave * 32 + i * 16 + (l4 << 2);
                int p = pq * 16 + l16;
                *(short2*)&hL[p][nb] = make_short2(f2bs(acc_h[i][pq][0]), f2bs(acc_h[i][pq][1]));
                *(short2*)&hL[p][nb + 2] = make_short2(f2bs(acc_h[i][pq][2]), f2bs(acc_h[i][pq][3]));
            }
        __syncthreads();

        if (tid < 64) {
            float v = -expA * sdt[tid];
#pragma unroll
            for (int off = 1; off < 64; off <<= 1) {
                float u = __shfl_up(v, off);
                if (lane >= off) v += u;
            }
            sL[tid] = v;
            float lt = __shfl(v, 63);
            sW[tid] = expf(lt - v);
            sRdt[tid] = 1.f / sdt[tid];
        }
        __syncthreads();

        {
            int s = tid & 63, pg = tid >> 6;
            const float* xs = xb + (size_t)(t0 + s) * CD + hh * HD + pg * 16;
            float dts = sdt[s];
#pragma unroll
            for (int j = 0; j < 4; j++) {
                float4 v = *(const float4*)(xs + j * 4);
                XdL[pg * 16 + j * 4 + 0][s] = f2bs(v.x * dts);
                XdL[pg * 16 + j * 4 + 1][s] = f2bs(v.y * dts);
                XdL[pg * 16 + j * 4 + 2][s] = f2bs(v.z * dts);
                XdL[pg * 16 + j * 4 + 3][s] = f2bs(v.w * dts);
            }
        }
        __syncthreads();

        {
            f32x4 g[2][2] = {};
#pragma unroll
            for (int ks = 0; ks < 4; ks++) {
                bf16x8 af[2], bfm[2];
#pragma unroll
                for (int i = 0; i < 2; i++)
                    af[i] = *(const bf16x8*)&CtL[tg * 32 + i * 16 + l16][ks * 32 + l4 * 8];
#pragma unroll
                for (int n = 0; n < 2; n++)
                    bfm[n] = *(const bf16x8*)&BtL[sg * 32 + n * 16 + l16][ks * 32 + l4 * 8];
#pragma unroll
                for (int i = 0; i < 2; i++)
#pragma unroll
                    for (int n = 0; n < 2; n++)
                        g[i][n] = __builtin_amdgcn_mfma_f32_16x16x32_bf16(af[i], bfm[n], g[i][n], 0, 0, 0);
            }
#pragma unroll
            for (int i = 0; i < 2; i++) {
                int tb2 = tg * 32 + i * 16 + (l4 << 2);
                float4 Lt = *(const float4*)&sL[tb2];
                float Ltr[4] = {Lt.x, Lt.y, Lt.z, Lt.w};
#pragma unroll
                for (int n = 0; n < 2; n++) {
                    int sE = sg * 32 + n * 16 + l16;
                    float Ls = sL[sE];
#pragma unroll
                    for (int r2 = 0; r2 < 4; r2++) {
                        float m = (sE <= tb2 + r2) ? g[i][n][r2] * expf(Ltr[r2] - Ls) : 0.f;
                        ML[tb2 + r2][sE] = f2bs(m);
                    }
                }
            }
        }
        __syncthreads();

        {
            f32x4 ay[2][2] = {};
            f32x4 ai[2][2] = {};
#pragma unroll
            for (int ks = 0; ks < 2; ks++) {
                bf16x8 af[2], bfp[2];
#pragma unroll
                for (int i = 0; i < 2; i++)
                    af[i] = *(const bf16x8*)&ML[tg * 32 + i * 16 + l16][ks * 32 + l4 * 8];
#pragma unroll
                for (int n = 0; n < 2; n++)
                    bfp[n] = *(const bf16x8*)&XdL[sg * 32 + n * 16 + l16][ks * 32 + l4 * 8];
#pragma unroll
                for (int i = 0; i < 2; i++)
#pragma unroll
                    for (int n = 0; n < 2; n++)
                        ay[i][n] = __builtin_amdgcn_mfma_f32_16x16x32_bf16(af[i], bfp[n], ay[i][n], 0, 0, 0);
            }
#pragma unroll
            for (int ks = 0; ks < 4; ks++) {
                bf16x8 af[2], bfh[2];
#pragma unroll
                for (int i = 0; i < 2; i++)
                    af[i] = *(const bf16x8*)&CtL[tg * 32 + i * 16 + l16][ks * 32 + l4 * 8];
#pragma unroll
                for (int n = 0; n < 2; n++) {
                    int prow = sg * 32 + n * 16 + l16;
                    int kb = ks * 32 + l4 * 8;
                    union { bf16x8 v; uint2 u2[2]; } hu;
                    hu.u2[0] = *(const uint2*)&hL[prow][kb];
                    hu.u2[1] = *(const uint2*)&hL[prow][kb + 4];
                    bfh[n] = hu.v;
                }
#pragma unroll
                for (int i = 0; i < 2; i++)
#pragma unroll
                    for (int n = 0; n < 2; n++)
                        ai[i][n] = __builtin_amdgcn_mfma_f32_16x16x32_bf16(af[i], bfh[n], ai[i][n], 0, 0, 0);
            }
            float Lft = sL[63];
#pragma unroll
            for (int i = 0; i < 2; i++) {
                int tb2 = tg * 32 + i * 16 + (l4 << 2);
                float4 Lt = *(const float4*)&sL[tb2];
                float4 Rt = *(const float4*)&sRdt[tb2];
                float Ltr[4] = {Lt.x, Lt.y, Lt.z, Lt.w};
                float Rtr[4] = {Rt.x, Rt.y, Rt.z, Rt.w};
#pragma unroll
                for (int n = 0; n < 2; n++) {
                    int p = sg * 32 + n * 16 + l16;
#pragma unroll
                    for (int r2 = 0; r2 < 4; r2++) {
                        float xv = b2f(XdL[p][tb2 + r2]) * Rtr[r2];
                        float yv = ay[i][n][r2] + expf(Ltr[r2]) * ai[i][n][r2] + Dh * xv;
                        yb[(size_t)(t0 + tb2 + r2) * DIP + p] = yv;
                    }
                }
            }
            float Pf = expf(Lft);
#pragma unroll
            for (int i = 0; i < 2; i++)
#pragma unroll
                for (int pq = 0; pq < 4; pq++)
                    acc_h[i][pq] *= Pf;
#pragma unroll
            for (int ks = 0; ks < 2; ks++) {
                bf16x8 af2[2], bfw[4];
#pragma unroll
                for (int i = 0; i < 2; i++) {
                    int nrow = wave * 32 + i * 16 + l16;
                    short e[8];
#pragma unroll
                    for (int j = 0; j < 8; j++) {
                        int s = ks * 32 + l4 * 8 + j;
                        e[j] = f2bs(b2f(BtL[s][nrow]) * sW[s]);
                    }
                    af2[i] = *(bf16x8*)e;
                }
#pragma unroll
                for (int pq = 0; pq < 4; pq++)
                    bfw[pq] = *(const bf16x8*)&XdL[pq * 16 + l16][ks * 32 + l4 * 8];
#pragma unroll
                for (int i = 0; i < 2; i++)
#pragma unroll
                    for (int pq = 0; pq < 4; pq++)
                        acc_h[i][pq] = __builtin_amdgcn_mfma_f32_16x16x32_bf16(af2[i], bfw[pq], acc_h[i][pq], 0, 0, 0);
            }
        }
        __syncthreads();
    }
}

// ---------------- Kernel 6: gating + RMSNorm -> bf16 g ----------------
__global__ __launch_bounds__(256) void gate_rms_kernel(const float* __restrict__ zx,
                                                       const float* __restrict__ rw,
                                                       __hip_bfloat16* __restrict__ gq) {
    int m = blockIdx.x;
    int tid = threadIdx.x;
    const float* yr = zx + (size_t)m * DIP + DI;
    const float* zr = zx + (size_t)m * DIP;
    int base = tid * 8;
    float gv[8];
    float ss = 0.f;
    float4 ya = *(const float4*)(yr + base);
    float4 yb4 = *(const float4*)(yr + base + 4);
    float4 za = *(const float4*)(zr + base);
    float4 zb4 = *(const float4*)(zr + base + 4);
    float yv[8] = {ya.x, ya.y, ya.z, ya.w, yb4.x, yb4.y, yb4.z, yb4.w};
    float zv[8] = {za.x, za.y, za.z, za.w, zb4.x, zb4.y, zb4.z, zb4.w};
#pragma unroll
    for (int i = 0; i < 8; i++) {
        float sg = 1.f / (1.f + expf(-zv[i]));
        float gg = yv[i] * zv[i] * sg;
        gv[i] = gg;
        ss += gg * gg;
    }
#pragma unroll
    for (int off = 1; off < 64; off <<= 1) ss += __shfl_xor(ss, off);
    __shared__ float red[4];
    int w = tid >> 6;
    if ((tid & 63) == 0) red[w] = ss;
    __syncthreads();
    float tot = red[0] + red[1] + red[2] + red[3];
    float r = rsqrtf(tot * (1.f / DI) + 1e-5f);
#pragma unroll
    for (int i = 0; i < 8; i += 2) {
        __hip_bfloat162 p;
        p.x = __float2bfloat16(gv[i] * r * rw[base + i]);
        p.y = __float2bfloat16(gv[i + 1] * r * rw[base + i + 1]);
        *(__hip_bfloat162*)(gq + (size_t)m * DI + base + i) = p;
    }
}

// ---------------- Kernel 7: GEMM2 bf16 MFMA (T2 swizzle, transposed store) ----------------
__global__ __launch_bounds__(256) void gemm2_mfma(const __hip_bfloat16* __restrict__ gq,
                                                  const __hip_bfloat16* __restrict__ Wob,
                                                  float* __restrict__ out) {
    __shared__ short As[128][64];
    __shared__ short Bs[128][64];
    int tid = threadIdx.x;
    int lane = tid & 63;
    int wave = tid >> 6;
    int wr = wave >> 1, wc = wave & 1;
    int m0 = blockIdx.x * 128;
    int j0 = blockIdx.y * 128;
    int srow = tid >> 3;
    int skc = (((tid & 7) ^ ((tid >> 3) & 7)) * 8);

    f32x4 acc[4][4] = {};

    for (int k0 = 0; k0 < DI; k0 += 64) {
        __syncthreads();
#pragma unroll
        for (int q = 0; q < 4; q++) {
            gload16(gq + (size_t)(m0 + q * 32 + srow) * DI + k0 + skc,
                    ((short*)As) + q * 2048 + wave * 512);
            gload16(Wob + (size_t)(j0 + q * 32 + srow) * DI + k0 + skc,
                    ((short*)Bs) + q * 2048 + wave * 512);
        }
        asm volatile("s_waitcnt vmcnt(0)" ::: "memory");
        __syncthreads();
#pragma unroll
        for (int ks = 0; ks < 2; ks++) {
            int pch = (((ks * 4) + (lane >> 4)) ^ (lane & 7)) * 8;
            bf16x8 af[4], bfr[4];
#pragma unroll
            for (int i = 0; i < 4; i++)
                af[i] = *(const bf16x8*)&As[wr * 64 + i * 16 + (lane & 15)][pch];
#pragma unroll
            for (int n = 0; n < 4; n++)
                bfr[n] = *(const bf16x8*)&Bs[wc * 64 + n * 16 + (lane & 15)][pch];
#pragma unroll
            for (int i = 0; i < 4; i++)
#pragma unroll
                for (int n = 0; n < 4; n++)
                    acc[i][n] = __builtin_amdgcn_mfma_f32_16x16x32_bf16(af[i], bfr[n], acc[i][n], 0, 0, 0);
        }
    }
#pragma unroll
    for (int i = 0; i < 4; i++) {
        int m = m0 + wr * 64 + i * 16 + ((lane >> 4) << 2);
        int b = m >> 12;
        int t = m & 4095;
#pragma unroll
        for (int n = 0; n < 4; n++) {
            int j = j0 + wc * 64 + n * 16 + (lane & 15);
            *(f32x4*)(out + (size_t)b * DM * TT + (size_t)j * TT + t) = acc[i][n];
        }
    }
}

extern "C" void kernel_launch(void* const* d_in, const int* in_sizes, int n_in,
                              void* d_out, int out_size, void* d_ws, size_t ws_size,
                              hipStream_t stream) {
    const float* x       = (const float*)d_in[0];
    const float* ln_w    = (const float*)d_in[1];
    const float* ln_b    = (const float*)d_in[2];
    const float* W_in    = (const float*)d_in[3];
    const float* conv_w  = (const float*)d_in[4];
    const float* conv_b  = (const float*)d_in[5];
    const float* dt_bias = (const float*)d_in[6];
    const float* A_log   = (const float*)d_in[7];
    const float* Dp      = (const float*)d_in[8];
    const float* rms_w   = (const float*)d_in[9];
    const float* W_out   = (const float*)d_in[10];
    const float* h0      = (const float*)d_in[11];

    float* out = (float*)d_out;
    float* hT = out + (size_t)BB * DM * TT;

    char* ws = (char*)d_ws;
    // Total footprint: 238,094,336 bytes (identical to proven layout).
    float* mu  = (float*)(ws + 0);
    float* rs  = (float*)(ws + 32768);
    float* zx  = (float*)(ws + 65536);        // 143,654,912  (B,T,4384) f32
    float* xBC = (float*)(ws + 143720448);    //  75,497,472  (phase B)
    __hip_bfloat16* Wb  = (__hip_bfloat16*)(ws + 143720448);              // phase A
    __hip_bfloat16* gq  = (__hip_bfloat16*)(ws + 143720448);              // phase C
    __hip_bfloat16* Wob = (__hip_bfloat16*)(ws + 143720448 + 41943040);   // phase C
    float* dAb = (float*)(ws + 219217920);
    float* dtv = (float*)(ws + 220266496);
    __hip_bfloat16* xnb = (__hip_bfloat16*)(ws + 221315072);   // shares with S
    float* S   = (float*)(ws + 221315072);
    float* P   = (float*)(ws + 238092288);

    ln_stats_kernel<<<dim3(TT / 64, BB), 64, 0, stream>>>(x, mu, rs);
    xn_kernel<<<dim3(TT / 64, DM / 64, BB), 256, 0, stream>>>(x, mu, rs, ln_w, ln_b, xnb);
    cvt_pad_kernel<<<(NP1 * DM) / 1024, 256, 0, stream>>>(W_in, Wb, DIP * DM, NP1 * DM);
    gemm1_mfma<<<dim3(NP1 / 128, (BB * TT) / 128), 256, 0, stream>>>(Wb, xnb, zx);
    gemm1_kernel<<<dim3(1, (BB * TT) / 64), 256, 0, stream>>>(x, mu, rs, ln_w, ln_b, W_in, zx, 4352);
    conv_kernel<<<(BB * TT * CD) / 256, 256, 0, stream>>>(zx, conv_w, conv_b, xBC);
    dt_kernel<<<(BB * TT * NH) / 256, 256, 0, stream>>>(zx, dt_bias, A_log, dtv, dAb);
    scan_reduce_ssd<<<dim3(NC, NH, BB), 256, 0, stream>>>(xBC, dtv, A_log, S, P);
    scan_combine_kernel<<<(int)(SELEMS / 256), 256, 0, stream>>>(h0, P, S, hT);
    scan_emit_ssd<<<dim3(NC, NH, BB), 256, 0, stream>>>(xBC, dtv, A_log, S, Dp, zx);
    cvt_pad_kernel<<<(DM * DI) / 1024, 256, 0, stream>>>(W_out, Wob, DM * DI, DM * DI);
    gate_rms_kernel<<<BB * TT, 256, 0, stream>>>(zx, rms_w, gq);
    gemm2_mfma<<<dim3((BB * TT) / 128, DM / 128), 256, 0, stream>>>(gq, Wob, out);
}

// Round 11
// 488.314 us; speedup vs baseline: 4.5493x; 1.1906x over previous
//
#include <hip/hip_runtime.h>
#include <hip/hip_bf16.h>
#include <math.h>

// Problem constants
#define BB 2
#define TT 4096
#define DM 1024
#define DSTATE 128
#define DI 2048
#define HD 64
#define NH 32
#define DIP 4384   // 2*DI + 2*DSTATE + NH
#define CD 2304    // DI + 2*DSTATE

// Chunked scan parameters
#define NC 8
#define CL 512
#define FL 64            // SSD fine-chunk length
#define FPC (CL / FL)    // 8
#define SELEMS ((size_t)BB * NH * HD * DSTATE)   // 524288

#define NP1 4480   // DIP padded to multiple of 128 for MFMA staging

typedef __attribute__((ext_vector_type(8))) short bf16x8;
typedef __attribute__((ext_vector_type(4))) float f32x4;

__device__ inline void gload16(const void* g, void* l) {
    __builtin_amdgcn_global_load_lds(
        (const __attribute__((address_space(1))) void*)g,
        (__attribute__((address_space(3))) void*)l, 16, 0, 0);
}

__device__ inline short f2bs(float f) {
    __hip_bfloat16 h = __float2bfloat16(f);
    union { __hip_bfloat16 h; short s; } u;
    u.h = h;
    return u.s;
}
__device__ inline float b2f(short s) {
    union { float f; unsigned u; } u;
    u.u = ((unsigned)(unsigned short)s) << 16;
    return u.f;
}

// ---------------- Kernel 1: LayerNorm statistics ----------------
__global__ __launch_bounds__(64) void ln_stats_kernel(const float* __restrict__ x,
                                                      float* __restrict__ mu,
                                                      float* __restrict__ rs) {
    int t = blockIdx.x * 64 + threadIdx.x;
    int b = blockIdx.y;
    const float* xb = x + (size_t)b * DM * TT + t;
    float s = 0.f, ss = 0.f;
#pragma unroll 8
    for (int d = 0; d < DM; d++) {
        float v = xb[(size_t)d * TT];
        s += v;
        ss += v * v;
    }
    float m = s * (1.f / DM);
    float var = ss * (1.f / DM) - m * m;
    int idx = b * TT + t;
    mu[idx] = m;
    rs[idx] = rsqrtf(var + 1e-5f);
}

// ---------------- Kernel 1b: xn = LN(x) transposed to (m, k) in bf16 ----------------
__global__ __launch_bounds__(256) void xn_kernel(const float* __restrict__ x,
                                                 const float* __restrict__ mu,
                                                 const float* __restrict__ rs,
                                                 const float* __restrict__ ln_w,
                                                 const float* __restrict__ ln_b,
                                                 __hip_bfloat16* __restrict__ xn) {
    __shared__ float tile[64][65];
    int tid = threadIdx.x;
    int t0 = blockIdx.x * 64, d0 = blockIdx.y * 64, b = blockIdx.z;
#pragma unroll
    for (int i = 0; i < 64; i += 4) {
        int dl = i + (tid >> 6);
        tile[dl][tid & 63] = x[(size_t)b * DM * TT + (size_t)(d0 + dl) * TT + t0 + (tid & 63)];
    }
    __syncthreads();
#pragma unroll
    for (int i = 0; i < 64; i += 8) {
        int tl = i + (tid >> 5);
        int kk = (tid & 31) * 2;
        int m = b * TT + t0 + tl;
        float mu_m = mu[m], rs_m = rs[m];
        float v0 = (tile[kk][tl] - mu_m) * rs_m * ln_w[d0 + kk] + ln_b[d0 + kk];
        float v1 = (tile[kk + 1][tl] - mu_m) * rs_m * ln_w[d0 + kk + 1] + ln_b[d0 + kk + 1];
        __hip_bfloat162 pk;
        pk.x = __float2bfloat16(v0);
        pk.y = __float2bfloat16(v1);
        *(__hip_bfloat162*)(xn + (size_t)m * DM + d0 + kk) = pk;
    }
}

// ---------------- convert f32 -> bf16 with zero-padding ----------------
__global__ __launch_bounds__(256) void cvt_pad_kernel(const float* __restrict__ src,
                                                      __hip_bfloat16* __restrict__ dst,
                                                      int src_n, int tot_n) {
    int i = (blockIdx.x * 256 + threadIdx.x) * 4;
    if (i >= tot_n) return;
    float4 v = (i < src_n) ? *(const float4*)(src + i) : make_float4(0.f, 0.f, 0.f, 0.f);
    __hip_bfloat162 p0, p1;
    p0.x = __float2bfloat16(v.x); p0.y = __float2bfloat16(v.y);
    p1.x = __float2bfloat16(v.z); p1.y = __float2bfloat16(v.w);
    *(__hip_bfloat162*)(dst + i) = p0;
    *(__hip_bfloat162*)(dst + i + 2) = p1;
}

// ---------------- Kernel 2: GEMM1 bf16 MFMA (T2 swizzle, bf16 output) ----------------
__global__ __launch_bounds__(256) void gemm1_mfma(const __hip_bfloat16* __restrict__ Wb,
                                                  const __hip_bfloat16* __restrict__ xn,
                                                  short* __restrict__ zx) {
    __shared__ short As[128][64];
    __shared__ short Bs[128][64];
    int tid = threadIdx.x;
    int lane = tid & 63;
    int wave = tid >> 6;
    int wr = wave >> 1, wc = wave & 1;
    int j0 = blockIdx.x * 128;
    int m0 = blockIdx.y * 128;
    int srow = tid >> 3;
    int skc = (((tid & 7) ^ ((tid >> 3) & 7)) * 8);   // pre-swizzled source k-chunk

    f32x4 acc[4][4] = {};

    for (int k0 = 0; k0 < DM; k0 += 64) {
        __syncthreads();
#pragma unroll
        for (int q = 0; q < 4; q++) {
            gload16(Wb + (size_t)(j0 + q * 32 + srow) * DM + k0 + skc,
                    ((short*)As) + q * 2048 + wave * 512);
            gload16(xn + (size_t)(m0 + q * 32 + srow) * DM + k0 + skc,
                    ((short*)Bs) + q * 2048 + wave * 512);
        }
        asm volatile("s_waitcnt vmcnt(0)" ::: "memory");
        __syncthreads();
#pragma unroll
        for (int ks = 0; ks < 2; ks++) {
            int pch = (((ks * 4) + (lane >> 4)) ^ (lane & 7)) * 8;
            bf16x8 af[4], bfr[4];
#pragma unroll
            for (int i = 0; i < 4; i++)
                af[i] = *(const bf16x8*)&As[wr * 64 + i * 16 + (lane & 15)][pch];
#pragma unroll
            for (int n = 0; n < 4; n++)
                bfr[n] = *(const bf16x8*)&Bs[wc * 64 + n * 16 + (lane & 15)][pch];
#pragma unroll
            for (int i = 0; i < 4; i++)
#pragma unroll
                for (int n = 0; n < 4; n++)
                    acc[i][n] = __builtin_amdgcn_mfma_f32_16x16x32_bf16(af[i], bfr[n], acc[i][n], 0, 0, 0);
        }
    }
#pragma unroll
    for (int i = 0; i < 4; i++) {
        int j = j0 + wr * 64 + i * 16 + ((lane >> 4) << 2);
        if (j < DIP) {
#pragma unroll
            for (int n = 0; n < 4; n++) {
                int m = m0 + wc * 64 + n * 16 + (lane & 15);
                short4 s4;
                s4.x = f2bs(acc[i][n][0]); s4.y = f2bs(acc[i][n][1]);
                s4.z = f2bs(acc[i][n][2]); s4.w = f2bs(acc[i][n][3]);
                *(short4*)(zx + (size_t)m * DIP + j) = s4;
            }
        }
    }
}

// ---------------- Kernel 2b: f32 strip GEMM, dt cols, fused bias+softplus -> dtv ----------------
__global__ __launch_bounds__(256) void gemm1_strip(const float* __restrict__ x,
                                                   const float* __restrict__ mu,
                                                   const float* __restrict__ rs,
                                                   const float* __restrict__ ln_w,
                                                   const float* __restrict__ ln_b,
                                                   const float* __restrict__ Win,
                                                   const float* __restrict__ dt_bias,
                                                   float* __restrict__ dtv) {
    __shared__ float As[16][64];
    __shared__ float Ws[64][17];
    int tid = threadIdx.x;
    int tx = tid & 15;
    int ty = tid >> 4;
    int j0 = 4352;
    int m0 = blockIdx.y * 64;
    int b = m0 >> 12;
    int t0 = m0 & 4095;
    const float* Xb = x + (size_t)b * DM * TT + t0;

    int lr = tid >> 4;
    int lc = (tid & 15) * 4;
    int wr = tid >> 2;
    int wc = (tid & 3) * 4;

    float acc[4][4] = {};
    for (int k0 = 0; k0 < DM; k0 += 16) {
        float4 xv = *(const float4*)(Xb + (size_t)(k0 + lr) * TT + lc);
        float4 muv = *(const float4*)(&mu[m0 + lc]);
        float4 rsv = *(const float4*)(&rs[m0 + lc]);
        float lw = ln_w[k0 + lr], lb = ln_b[k0 + lr];
        As[lr][lc]     = (xv.x - muv.x) * rsv.x * lw + lb;
        As[lr][lc + 1] = (xv.y - muv.y) * rsv.y * lw + lb;
        As[lr][lc + 2] = (xv.z - muv.z) * rsv.z * lw + lb;
        As[lr][lc + 3] = (xv.w - muv.w) * rsv.w * lw + lb;

        int j = j0 + wr;
        float4 wv = make_float4(0.f, 0.f, 0.f, 0.f);
        if (j < DIP) wv = *(const float4*)(Win + (size_t)j * DM + k0 + wc);
        Ws[wr][wc] = wv.x; Ws[wr][wc + 1] = wv.y; Ws[wr][wc + 2] = wv.z; Ws[wr][wc + 3] = wv.w;
        __syncthreads();
#pragma unroll
        for (int kk = 0; kk < 16; kk++) {
            float4 a4 = *(const float4*)&As[kk][ty * 4];
            float a[4] = {a4.x, a4.y, a4.z, a4.w};
            float bv[4];
#pragma unroll
            for (int n = 0; n < 4; n++) bv[n] = Ws[tx * 4 + n][kk];
#pragma unroll
            for (int i = 0; i < 4; i++)
#pragma unroll
                for (int n = 0; n < 4; n++)
                    acc[i][n] = fmaf(a[i], bv[n], acc[i][n]);
        }
        __syncthreads();
    }
#pragma unroll
    for (int i = 0; i < 4; i++) {
        int m = m0 + ty * 4 + i;
        int j = j0 + tx * 4;
        if (j + 3 < DIP) {
            int hh = j - 4352;
            float4 v;
            float r0 = acc[i][0] + dt_bias[hh];
            float r1 = acc[i][1] + dt_bias[hh + 1];
            float r2 = acc[i][2] + dt_bias[hh + 2];
            float r3 = acc[i][3] + dt_bias[hh + 3];
            v.x = (r0 > 20.f) ? r0 : log1pf(expf(r0));
            v.y = (r1 > 20.f) ? r1 : log1pf(expf(r1));
            v.z = (r2 > 20.f) ? r2 : log1pf(expf(r2));
            v.w = (r3 > 20.f) ? r3 : log1pf(expf(r3));
            *(float4*)(dtv + (size_t)m * NH + hh) = v;
        }
    }
}

// ---------------- Kernel 3: causal depthwise conv(4) + SiLU (bf16 in/out) ----------------
__global__ __launch_bounds__(256) void conv_kernel(const short* __restrict__ zx,
                                                   const float* __restrict__ cw,
                                                   const float* __restrict__ cb,
                                                   short* __restrict__ xBC) {
    size_t i = ((size_t)blockIdx.x * 256 + threadIdx.x) * 8;
    int c = (int)(i % CD);
    int t = (int)((i / CD) & (TT - 1));
    int b = (int)(i / ((size_t)CD * TT));
    const short* src = zx + (size_t)b * TT * DIP + DI + c;
    float acc[8];
#pragma unroll
    for (int e = 0; e < 8; e++) acc[e] = cb[c + e];
    float wv[8][4];
#pragma unroll
    for (int e = 0; e < 8; e++) {
        float4 w4 = *(const float4*)(cw + (c + e) * 4);
        wv[e][0] = w4.x; wv[e][1] = w4.y; wv[e][2] = w4.z; wv[e][3] = w4.w;
    }
#pragma unroll
    for (int k = 0; k < 4; k++) {
        int ts = t - 3 + k;
        if (ts >= 0) {
            bf16x8 v = *(const bf16x8*)(src + (size_t)ts * DIP);
#pragma unroll
            for (int e = 0; e < 8; e++)
                acc[e] = fmaf(wv[e][k], b2f(v[e]), acc[e]);
        }
    }
    short o[8];
#pragma unroll
    for (int e = 0; e < 8; e++) {
        float sg = 1.f / (1.f + expf(-acc[e]));
        o[e] = f2bs(acc[e] * sg);
    }
    *(bf16x8*)(xBC + i) = *(bf16x8*)o;
}

// ---------------- Kernel 5a: SSD chunk reduce — MFMA state-only pass (bf16 input) ----------------
__global__ __launch_bounds__(256, 2) void scan_reduce_ssd(const short* __restrict__ xBC,
                                                          const float* __restrict__ dtg,
                                                          const float* __restrict__ A_log,
                                                          float* __restrict__ S,
                                                          float* __restrict__ P) {
    int tid = threadIdx.x;
    int wave = tid >> 6, lane = tid & 63;
    int l4 = lane >> 4, l16 = lane & 15;
    int c = blockIdx.x, hh = blockIdx.y, b = blockIdx.z;
    int cbase = c * CL;

    __shared__ __align__(16) short BtL[64][136];
    __shared__ __align__(16) short XdL[64][72];
    __shared__ __align__(16) float sdt[64];
    __shared__ __align__(16) float sL[64];
    __shared__ __align__(16) float sW[64];

    f32x4 acc_h[2][4];
#pragma unroll
    for (int i = 0; i < 2; i++)
#pragma unroll
        for (int pq = 0; pq < 4; pq++) acc_h[i][pq] = (f32x4){0.f, 0.f, 0.f, 0.f};
    float Lsum = 0.f;

    float expA = expf(A_log[hh]);
    const float* dtb = dtg + (size_t)b * TT * NH + hh;
    const short* xb = xBC + (size_t)b * TT * CD;

#pragma unroll 1
    for (int f = 0; f < FPC; f++) {
        int t0 = cbase + f * FL;
        if (tid < 64) sdt[tid] = dtb[(size_t)(t0 + tid) * NH];
        {
            int r = tid >> 2, q = tid & 3;
            const short* bs = xb + (size_t)(t0 + r) * CD + DI + q * 32;
#pragma unroll
            for (int j = 0; j < 4; j++)
                *(bf16x8*)&BtL[r][q * 32 + j * 8] = *(const bf16x8*)(bs + j * 8);
        }
        __syncthreads();
        if (tid < 64) {
            float v = -expA * sdt[tid];
#pragma unroll
            for (int off = 1; off < 64; off <<= 1) {
                float u = __shfl_up(v, off);
                if (lane >= off) v += u;
            }
            sL[tid] = v;
            float lt = __shfl(v, 63);
            sW[tid] = expf(lt - v);
        }
        __syncthreads();
        {
            int s = tid & 63, pg2 = tid >> 6;
            const short* xs = xb + (size_t)(t0 + s) * CD + hh * HD + pg2 * 16;
            float dts = sdt[s];
            bf16x8 v0 = *(const bf16x8*)xs;
            bf16x8 v1 = *(const bf16x8*)(xs + 8);
#pragma unroll
            for (int j = 0; j < 8; j++) XdL[pg2 * 16 + j][s] = f2bs(b2f(v0[j]) * dts);
#pragma unroll
            for (int j = 0; j < 8; j++) XdL[pg2 * 16 + 8 + j][s] = f2bs(b2f(v1[j]) * dts);
        }
        __syncthreads();
        float Lft = sL[63];
        float Pf = expf(Lft);
        Lsum += Lft;
#pragma unroll
        for (int i = 0; i < 2; i++)
#pragma unroll
            for (int pq = 0; pq < 4; pq++) acc_h[i][pq] *= Pf;
#pragma unroll
        for (int ks = 0; ks < 2; ks++) {
            bf16x8 af2[2], bfw[4];
#pragma unroll
            for (int i = 0; i < 2; i++) {
                int nrow = wave * 32 + i * 16 + l16;
                short e[8];
#pragma unroll
                for (int j = 0; j < 8; j++) {
                    int s = ks * 32 + l4 * 8 + j;
                    e[j] = f2bs(b2f(BtL[s][nrow]) * sW[s]);
                }
                af2[i] = *(bf16x8*)e;
            }
#pragma unroll
            for (int pq = 0; pq < 4; pq++)
                bfw[pq] = *(const bf16x8*)&XdL[pq * 16 + l16][ks * 32 + l4 * 8];
#pragma unroll
            for (int i = 0; i < 2; i++)
#pragma unroll
                for (int pq = 0; pq < 4; pq++)
                    acc_h[i][pq] = __builtin_amdgcn_mfma_f32_16x16x32_bf16(af2[i], bfw[pq], acc_h[i][pq], 0, 0, 0);
        }
        __syncthreads();
    }

    float* Sp = S + (size_t)c * SELEMS + ((size_t)(b * NH + hh) * HD) * DSTATE;
#pragma unroll
    for (int i = 0; i < 2; i++)
#pragma unroll
        for (int pq = 0; pq < 4; pq++) {
            int nb = wave * 32 + i * 16 + (l4 << 2);
            int p = pq * 16 + l16;
            *(f32x4*)(Sp + (size_t)p * DSTATE + nb) = acc_h[i][pq];
        }
    if (tid == 0) P[(c * BB + b) * NH + hh] = expf(Lsum);
}

// ---------------- Kernel 5b: sequential chunk combine ----------------
__global__ __launch_bounds__(256) void scan_combine_kernel(const float* __restrict__ h0,
                                                           const float* __restrict__ P,
                                                           float* __restrict__ S,
                                                           float* __restrict__ hT) {
    size_t tid = (size_t)blockIdx.x * 256 + threadIdx.x;
    int hh = (int)((tid >> 13) & 31);
    int b = (int)(tid >> 18);
    float h = h0[tid];
#pragma unroll
    for (int c = 0; c < NC; c++) {
        float s = S[(size_t)c * SELEMS + tid];
        S[(size_t)c * SELEMS + tid] = h;
        h = fmaf(P[(c * BB + b) * NH + hh], h, s);
    }
    hT[tid] = h;
}

// ---------------- Kernel 5c: SSD emit (bf16 input, f32 y to ybuf) ----------------
__global__ __launch_bounds__(256, 2) void scan_emit_ssd(const short* __restrict__ xBC,
                                                        const float* __restrict__ dtg,
                                                        const float* __restrict__ A_log,
                                                        const float* __restrict__ S,
                                                        const float* __restrict__ Dp,
                                                        float* __restrict__ ybuf) {
    int tid = threadIdx.x;
    int wave = tid >> 6, lane = tid & 63;
    int l4 = lane >> 4, l16 = lane & 15;
    int c = blockIdx.x, hh = blockIdx.y, b = blockIdx.z;
    int cbase = c * CL;

    __shared__ __align__(16) short CtL[64][136];
    __shared__ __align__(16) short BtL[64][136];
    __shared__ __align__(16) short hL[64][132];
    __shared__ __align__(16) short XdL[64][72];
    __shared__ __align__(16) short ML[64][72];
    __shared__ __align__(16) float sdt[64];
    __shared__ __align__(16) float sL[64];
    __shared__ __align__(16) float sW[64];
    __shared__ __align__(16) float sRdt[64];

    f32x4 acc_h[2][4];
    {
        const float* Sp = S + (size_t)c * SELEMS + ((size_t)(b * NH + hh) * HD) * DSTATE;
#pragma unroll
        for (int i = 0; i < 2; i++)
#pragma unroll
            for (int pq = 0; pq < 4; pq++) {
                int nb = wave * 32 + i * 16 + (l4 << 2);
                int p = pq * 16 + l16;
                acc_h[i][pq] = *(const f32x4*)(Sp + (size_t)p * DSTATE + nb);
            }
    }

    float expA = expf(A_log[hh]);
    float Dh = Dp[hh];
    const float* dtb = dtg + (size_t)b * TT * NH + hh;
    const short* xb = xBC + (size_t)b * TT * CD;
    float* yb = ybuf + (size_t)b * TT * DI + hh * HD;

    int tg = wave >> 1;
    int sg = wave & 1;

#pragma unroll 1
    for (int f = 0; f < FPC; f++) {
        int t0 = cbase + f * FL;

        if (tid < 64) sdt[tid] = dtb[(size_t)(t0 + tid) * NH];
        {
            int r = tid >> 2, q = tid & 3;
            const short* cs = xb + (size_t)(t0 + r) * CD + DI + DSTATE + q * 32;
            const short* bs = xb + (size_t)(t0 + r) * CD + DI + q * 32;
#pragma unroll
            for (int j = 0; j < 4; j++) {
                *(bf16x8*)&CtL[r][q * 32 + j * 8] = *(const bf16x8*)(cs + j * 8);
                *(bf16x8*)&BtL[r][q * 32 + j * 8] = *(const bf16x8*)(bs + j * 8);
            }
        }
#pragma unroll
        for (int i = 0; i < 2; i++)
#pragma unroll
            for (int pq = 0; pq < 4; pq++) {
                int nb = wave * 32 + i * 16 + (l4 << 2);
                int p = pq * 16 + l16;
                *(short2*)&hL[p][nb] = make_short2(f2bs(acc_h[i][pq][0]), f2bs(acc_h[i][pq][1]));
                *(short2*)&hL[p][nb + 2] = make_short2(f2bs(acc_h[i][pq][2]), f2bs(acc_h[i][pq][3]));
            }
        __syncthreads();

        if (tid < 64) {
            float v = -expA * sdt[tid];
#pragma unroll
            for (int off = 1; off < 64; off <<= 1) {
                float u = __shfl_up(v, off);
                if (lane >= off) v += u;
            }
            sL[tid] = v;
            float lt = __shfl(v, 63);
            sW[tid] = expf(lt - v);
            sRdt[tid] = 1.f / sdt[tid];
        }
        __syncthreads();

        {
            int s = tid & 63, pg = tid >> 6;
            const short* xs = xb + (size_t)(t0 + s) * CD + hh * HD + pg * 16;
            float dts = sdt[s];
            bf16x8 v0 = *(const bf16x8*)xs;
            bf16x8 v1 = *(const bf16x8*)(xs + 8);
#pragma unroll
            for (int j = 0; j < 8; j++) XdL[pg * 16 + j][s] = f2bs(b2f(v0[j]) * dts);
#pragma unroll
            for (int j = 0; j < 8; j++) XdL[pg * 16 + 8 + j][s] = f2bs(b2f(v1[j]) * dts);
        }
        __syncthreads();

        {
            f32x4 g[2][2] = {};
#pragma unroll
            for (int ks = 0; ks < 4; ks++) {
                bf16x8 af[2], bfm[2];
#pragma unroll
                for (int i = 0; i < 2; i++)
                    af[i] = *(const bf16x8*)&CtL[tg * 32 + i * 16 + l16][ks * 32 + l4 * 8];
#pragma unroll
                for (int n = 0; n < 2; n++)
                    bfm[n] = *(const bf16x8*)&BtL[sg * 32 + n * 16 + l16][ks * 32 + l4 * 8];
#pragma unroll
                for (int i = 0; i < 2; i++)
#pragma unroll
                    for (int n = 0; n < 2; n++)
                        g[i][n] = __builtin_amdgcn_mfma_f32_16x16x32_bf16(af[i], bfm[n], g[i][n], 0, 0, 0);
            }
#pragma unroll
            for (int i = 0; i < 2; i++) {
                int tb2 = tg * 32 + i * 16 + (l4 << 2);
                float4 Lt = *(const float4*)&sL[tb2];
                float Ltr[4] = {Lt.x, Lt.y, Lt.z, Lt.w};
#pragma unroll
                for (int n = 0; n < 2; n++) {
                    int sE = sg * 32 + n * 16 + l16;
                    float Ls = sL[sE];
#pragma unroll
                    for (int r2 = 0; r2 < 4; r2++) {
                        float m = (sE <= tb2 + r2) ? g[i][n][r2] * expf(Ltr[r2] - Ls) : 0.f;
                        ML[tb2 + r2][sE] = f2bs(m);
                    }
                }
            }
        }
        __syncthreads();

        {
            f32x4 ay[2][2] = {};
            f32x4 ai[2][2] = {};
#pragma unroll
            for (int ks = 0; ks < 2; ks++) {
                bf16x8 af[2], bfp[2];
#pragma unroll
                for (int i = 0; i < 2; i++)
                    af[i] = *(const bf16x8*)&ML[tg * 32 + i * 16 + l16][ks * 32 + l4 * 8];
#pragma unroll
                for (int n = 0; n < 2; n++)
                    bfp[n] = *(const bf16x8*)&XdL[sg * 32 + n * 16 + l16][ks * 32 + l4 * 8];
#pragma unroll
                for (int i = 0; i < 2; i++)
#pragma unroll
                    for (int n = 0; n < 2; n++)
                        ay[i][n] = __builtin_amdgcn_mfma_f32_16x16x32_bf16(af[i], bfp[n], ay[i][n], 0, 0, 0);
            }
#pragma unroll
            for (int ks = 0; ks < 4; ks++) {
                bf16x8 af[2], bfh[2];
#pragma unroll
                for (int i = 0; i < 2; i++)
                    af[i] = *(const bf16x8*)&CtL[tg * 32 + i * 16 + l16][ks * 32 + l4 * 8];
#pragma unroll
                for (int n = 0; n < 2; n++) {
                    int prow = sg * 32 + n * 16 + l16;
                    int kb = ks * 32 + l4 * 8;
                    union { bf16x8 v; uint2 u2[2]; } hu;
                    hu.u2[0] = *(const uint2*)&hL[prow][kb];
                    hu.u2[1] = *(const uint2*)&hL[prow][kb + 4];
                    bfh[n] = hu.v;
                }
#pragma unroll
                for (int i = 0; i < 2; i++)
#pragma unroll
                    for (int n = 0; n < 2; n++)
                        ai[i][n] = __builtin_amdgcn_mfma_f32_16x16x32_bf16(af[i], bfh[n], ai[i][n], 0, 0, 0);
            }
            float Lft = sL[63];
#pragma unroll
            for (int i = 0; i < 2; i++) {
                int tb2 = tg * 32 + i * 16 + (l4 << 2);
                float4 Lt = *(const float4*)&sL[tb2];
                float4 Rt = *(const float4*)&sRdt[tb2];
                float Ltr[4] = {Lt.x, Lt.y, Lt.z, Lt.w};
                float Rtr[4] = {Rt.x, Rt.y, Rt.z, Rt.w};
#pragma unroll
                for (int n = 0; n < 2; n++) {
                    int p = sg * 32 + n * 16 + l16;
#pragma unroll
                    for (int r2 = 0; r2 < 4; r2++) {
                        float xv = b2f(XdL[p][tb2 + r2]) * Rtr[r2];
                        float yv = ay[i][n][r2] + expf(Ltr[r2]) * ai[i][n][r2] + Dh * xv;
                        yb[(size_t)(t0 + tb2 + r2) * DI + p] = yv;
                    }
                }
            }
            float Pf = expf(Lft);
#pragma unroll
            for (int i = 0; i < 2; i++)
#pragma unroll
                for (int pq = 0; pq < 4; pq++)
                    acc_h[i][pq] *= Pf;
#pragma unroll
            for (int ks = 0; ks < 2; ks++) {
                bf16x8 af2[2], bfw[4];
#pragma unroll
                for (int i = 0; i < 2; i++) {
                    int nrow = wave * 32 + i * 16 + l16;
                    short e[8];
#pragma unroll
                    for (int j = 0; j < 8; j++) {
                        int s = ks * 32 + l4 * 8 + j;
                        e[j] = f2bs(b2f(BtL[s][nrow]) * sW[s]);
                    }
                    af2[i] = *(bf16x8*)e;
                }
#pragma unroll
                for (int pq = 0; pq < 4; pq++)
                    bfw[pq] = *(const bf16x8*)&XdL[pq * 16 + l16][ks * 32 + l4 * 8];
#pragma unroll
                for (int i = 0; i < 2; i++)
#pragma unroll
                    for (int pq = 0; pq < 4; pq++)
                        acc_h[i][pq] = __builtin_amdgcn_mfma_f32_16x16x32_bf16(af2[i], bfw[pq], acc_h[i][pq], 0, 0, 0);
            }
        }
        __syncthreads();
    }
}

// ---------------- Kernel 6: gating + RMSNorm (f32 y, bf16 z) -> bf16 g ----------------
__global__ __launch_bounds__(256) void gate_rms_kernel(const float* __restrict__ ybuf,
                                                       const short* __restrict__ zx,
                                                       const float* __restrict__ rw,
                                                       __hip_bfloat16* __restrict__ gq) {
    int m = blockIdx.x;
    int tid = threadIdx.x;
    const float* yr = ybuf + (size_t)m * DI;
    const short* zr = zx + (size_t)m * DIP;
    int base = tid * 8;
    float gv[8];
    float ss = 0.f;
    float4 ya = *(const float4*)(yr + base);
    float4 yb4 = *(const float4*)(yr + base + 4);
    bf16x8 zv8 = *(const bf16x8*)(zr + base);
    float yv[8] = {ya.x, ya.y, ya.z, ya.w, yb4.x, yb4.y, yb4.z, yb4.w};
#pragma unroll
    for (int i = 0; i < 8; i++) {
        float z = b2f(zv8[i]);
        float sg = 1.f / (1.f + expf(-z));
        float gg = yv[i] * z * sg;
        gv[i] = gg;
        ss += gg * gg;
    }
#pragma unroll
    for (int off = 1; off < 64; off <<= 1) ss += __shfl_xor(ss, off);
    __shared__ float red[4];
    int w = tid >> 6;
    if ((tid & 63) == 0) red[w] = ss;
    __syncthreads();
    float tot = red[0] + red[1] + red[2] + red[3];
    float r = rsqrtf(tot * (1.f / DI) + 1e-5f);
#pragma unroll
    for (int i = 0; i < 8; i += 2) {
        __hip_bfloat162 p;
        p.x = __float2bfloat16(gv[i] * r * rw[base + i]);
        p.y = __float2bfloat16(gv[i + 1] * r * rw[base + i + 1]);
        *(__hip_bfloat162*)(gq + (size_t)m * DI + base + i) = p;
    }
}

// ---------------- Kernel 7: GEMM2 bf16 MFMA (T2 swizzle, transposed store) ----------------
__global__ __launch_bounds__(256) void gemm2_mfma(const __hip_bfloat16* __restrict__ gq,
                                                  const __hip_bfloat16* __restrict__ Wob,
                                                  float* __restrict__ out) {
    __shared__ short As[128][64];
    __shared__ short Bs[128][64];
    int tid = threadIdx.x;
    int lane = tid & 63;
    int wave = tid >> 6;
    int wr = wave >> 1, wc = wave & 1;
    int m0 = blockIdx.x * 128;
    int j0 = blockIdx.y * 128;
    int srow = tid >> 3;
    int skc = (((tid & 7) ^ ((tid >> 3) & 7)) * 8);

    f32x4 acc[4][4] = {};

    for (int k0 = 0; k0 < DI; k0 += 64) {
        __syncthreads();
#pragma unroll
        for (int q = 0; q < 4; q++) {
            gload16(gq + (size_t)(m0 + q * 32 + srow) * DI + k0 + skc,
                    ((short*)As) + q * 2048 + wave * 512);
            gload16(Wob + (size_t)(j0 + q * 32 + srow) * DI + k0 + skc,
                    ((short*)Bs) + q * 2048 + wave * 512);
        }
        asm volatile("s_waitcnt vmcnt(0)" ::: "memory");
        __syncthreads();
#pragma unroll
        for (int ks = 0; ks < 2; ks++) {
            int pch = (((ks * 4) + (lane >> 4)) ^ (lane & 7)) * 8;
            bf16x8 af[4], bfr[4];
#pragma unroll
            for (int i = 0; i < 4; i++)
                af[i] = *(const bf16x8*)&As[wr * 64 + i * 16 + (lane & 15)][pch];
#pragma unroll
            for (int n = 0; n < 4; n++)
                bfr[n] = *(const bf16x8*)&Bs[wc * 64 + n * 16 + (lane & 15)][pch];
#pragma unroll
            for (int i = 0; i < 4; i++)
#pragma unroll
                for (int n = 0; n < 4; n++)
                    acc[i][n] = __builtin_amdgcn_mfma_f32_16x16x32_bf16(af[i], bfr[n], acc[i][n], 0, 0, 0);
        }
    }
#pragma unroll
    for (int i = 0; i < 4; i++) {
        int m = m0 + wr * 64 + i * 16 + ((lane >> 4) << 2);
        int b = m >> 12;
        int t = m & 4095;
#pragma unroll
        for (int n = 0; n < 4; n++) {
            int j = j0 + wc * 64 + n * 16 + (lane & 15);
            *(f32x4*)(out + (size_t)b * DM * TT + (size_t)j * TT + t) = acc[i][n];
        }
    }
}

extern "C" void kernel_launch(void* const* d_in, const int* in_sizes, int n_in,
                              void* d_out, int out_size, void* d_ws, size_t ws_size,
                              hipStream_t stream) {
    const float* x       = (const float*)d_in[0];
    const float* ln_w    = (const float*)d_in[1];
    const float* ln_b    = (const float*)d_in[2];
    const float* W_in    = (const float*)d_in[3];
    const float* conv_w  = (const float*)d_in[4];
    const float* conv_b  = (const float*)d_in[5];
    const float* dt_bias = (const float*)d_in[6];
    const float* A_log   = (const float*)d_in[7];
    const float* Dp      = (const float*)d_in[8];
    const float* rms_w   = (const float*)d_in[9];
    const float* W_out   = (const float*)d_in[10];
    const float* h0      = (const float*)d_in[11];

    float* out = (float*)d_out;
    float* hT = out + (size_t)BB * DM * TT;

    char* ws = (char*)d_ws;
    // Workspace layout — total 194,578,432 bytes (under proven 238 MB):
    float* mu   = (float*)(ws + 0);                       //      32,768
    float* rs   = (float*)(ws + 32768);                   //      32,768
    short* zxq  = (short*)(ws + 65536);                   //  71,827,456  (B,T,4384) bf16
    short* xBCq = (short*)(ws + 71892992);                //  37,748,736  (B,T,2304) bf16
    __hip_bfloat16* gq  = (__hip_bfloat16*)(ws + 71892992);        // overlays xBC (post-emit)
    __hip_bfloat16* Wob = (__hip_bfloat16*)(ws + 105447424);       // overlays xBC tail (post-emit)
    float* ybuf = (float*)(ws + 109641728);               //  67,108,864  (B,T,2048) f32
    __hip_bfloat16* Wb  = (__hip_bfloat16*)(ws + 109641728);       // overlays ybuf (pre-scan)
    float* dtv  = (float*)(ws + 176750592);               //   1,048,576
    __hip_bfloat16* xnb = (__hip_bfloat16*)(ws + 177799168);       //  16,777,216 (shares S)
    float* S    = (float*)(ws + 177799168);
    float* P    = (float*)(ws + 194576384);               //       2,048

    ln_stats_kernel<<<dim3(TT / 64, BB), 64, 0, stream>>>(x, mu, rs);
    xn_kernel<<<dim3(TT / 64, DM / 64, BB), 256, 0, stream>>>(x, mu, rs, ln_w, ln_b, xnb);
    cvt_pad_kernel<<<(NP1 * DM) / 1024, 256, 0, stream>>>(W_in, Wb, DIP * DM, NP1 * DM);
    gemm1_mfma<<<dim3(NP1 / 128, (BB * TT) / 128), 256, 0, stream>>>(Wb, xnb, zxq);
    gemm1_strip<<<dim3(1, (BB * TT) / 64), 256, 0, stream>>>(x, mu, rs, ln_w, ln_b, W_in, dt_bias, dtv);
    conv_kernel<<<(int)(((size_t)BB * TT * CD) / 2048), 256, 0, stream>>>(zxq, conv_w, conv_b, xBCq);
    scan_reduce_ssd<<<dim3(NC, NH, BB), 256, 0, stream>>>(xBCq, dtv, A_log, S, P);
    scan_combine_kernel<<<(int)(SELEMS / 256), 256, 0, stream>>>(h0, P, S, hT);
    scan_emit_ssd<<<dim3(NC, NH, BB), 256, 0, stream>>>(xBCq, dtv, A_log, S, Dp, ybuf);
    cvt_pad_kernel<<<(DM * DI) / 1024, 256, 0, stream>>>(W_out, Wob, DM * DI, DM * DI);
    gate_rms_kernel<<<BB * TT, 256, 0, stream>>>(ybuf, zxq, rms_w, gq);
    gemm2_mfma<<<dim3((BB * TT) / 128, DM / 128), 256, 0, stream>>>(gq, Wob, out);
}

// Round 12
// 483.357 us; speedup vs baseline: 4.5960x; 1.0103x over previous
//
#include <hip/hip_runtime.h>
#include <hip/hip_bf16.h>
#include <math.h>

// Problem constants
#define BB 2
#define TT 4096
#define DM 1024
#define DSTATE 128
#define DI 2048
#define HD 64
#define NH 32
#define DIP 4384   // 2*DI + 2*DSTATE + NH
#define CD 2304    // DI + 2*DSTATE

// Chunked scan parameters
#define NC 8
#define CL 512
#define FL 64            // SSD fine-chunk length
#define FPC (CL / FL)    // 8
#define SELEMS ((size_t)BB * NH * HD * DSTATE)   // 524288

#define NP1 4480   // DIP padded to multiple of 128 for MFMA staging

typedef __attribute__((ext_vector_type(8))) short bf16x8;
typedef __attribute__((ext_vector_type(4))) float f32x4;

__device__ inline void gload16(const void* g, void* l) {
    __builtin_amdgcn_global_load_lds(
        (const __attribute__((address_space(1))) void*)g,
        (__attribute__((address_space(3))) void*)l, 16, 0, 0);
}

__device__ inline short f2bs(float f) {
    __hip_bfloat16 h = __float2bfloat16(f);
    union { __hip_bfloat16 h; short s; } u;
    u.h = h;
    return u.s;
}
__device__ inline float b2f(short s) {
    union { float f; unsigned u; } u;
    u.u = ((unsigned)(unsigned short)s) << 16;
    return u.f;
}

// ---------------- Kernel 1: LayerNorm statistics ----------------
__global__ __launch_bounds__(64) void ln_stats_kernel(const float* __restrict__ x,
                                                      float* __restrict__ mu,
                                                      float* __restrict__ rs) {
    int t = blockIdx.x * 64 + threadIdx.x;
    int b = blockIdx.y;
    const float* xb = x + (size_t)b * DM * TT + t;
    float s = 0.f, ss = 0.f;
#pragma unroll 8
    for (int d = 0; d < DM; d++) {
        float v = xb[(size_t)d * TT];
        s += v;
        ss += v * v;
    }
    float m = s * (1.f / DM);
    float var = ss * (1.f / DM) - m * m;
    int idx = b * TT + t;
    mu[idx] = m;
    rs[idx] = rsqrtf(var + 1e-5f);
}

// ---------------- Kernel 1b: xn = LN(x) transposed to (m, k) in bf16 ----------------
__global__ __launch_bounds__(256) void xn_kernel(const float* __restrict__ x,
                                                 const float* __restrict__ mu,
                                                 const float* __restrict__ rs,
                                                 const float* __restrict__ ln_w,
                                                 const float* __restrict__ ln_b,
                                                 __hip_bfloat16* __restrict__ xn) {
    __shared__ float tile[64][65];
    int tid = threadIdx.x;
    int t0 = blockIdx.x * 64, d0 = blockIdx.y * 64, b = blockIdx.z;
#pragma unroll
    for (int i = 0; i < 64; i += 4) {
        int dl = i + (tid >> 6);
        tile[dl][tid & 63] = x[(size_t)b * DM * TT + (size_t)(d0 + dl) * TT + t0 + (tid & 63)];
    }
    __syncthreads();
#pragma unroll
    for (int i = 0; i < 64; i += 8) {
        int tl = i + (tid >> 5);
        int kk = (tid & 31) * 2;
        int m = b * TT + t0 + tl;
        float mu_m = mu[m], rs_m = rs[m];
        float v0 = (tile[kk][tl] - mu_m) * rs_m * ln_w[d0 + kk] + ln_b[d0 + kk];
        float v1 = (tile[kk + 1][tl] - mu_m) * rs_m * ln_w[d0 + kk + 1] + ln_b[d0 + kk + 1];
        __hip_bfloat162 pk;
        pk.x = __float2bfloat16(v0);
        pk.y = __float2bfloat16(v1);
        *(__hip_bfloat162*)(xn + (size_t)m * DM + d0 + kk) = pk;
    }
}

// ---------------- convert f32 -> bf16 with zero-padding ----------------
__global__ __launch_bounds__(256) void cvt_pad_kernel(const float* __restrict__ src,
                                                      __hip_bfloat16* __restrict__ dst,
                                                      int src_n, int tot_n) {
    int i = (blockIdx.x * 256 + threadIdx.x) * 4;
    if (i >= tot_n) return;
    float4 v = (i < src_n) ? *(const float4*)(src + i) : make_float4(0.f, 0.f, 0.f, 0.f);
    __hip_bfloat162 p0, p1;
    p0.x = __float2bfloat16(v.x); p0.y = __float2bfloat16(v.y);
    p1.x = __float2bfloat16(v.z); p1.y = __float2bfloat16(v.w);
    *(__hip_bfloat162*)(dst + i) = p0;
    *(__hip_bfloat162*)(dst + i + 2) = p1;
}

// ---------------- Kernel 2: GEMM1 bf16 MFMA (T2 swizzle + T1 XCD panel remap) ----------------
// 1-D grid of 2240 wgs. xcd = id%8 owns m-strip [xcd*8, xcd*8+8) x all 35 j-tiles
// -> per-XCD L2 fetch = full W (9.2 MB) + xn strip (2.1 MB) instead of 8x xn duplication.
__global__ __launch_bounds__(256) void gemm1_mfma(const __hip_bfloat16* __restrict__ Wb,
                                                  const __hip_bfloat16* __restrict__ xn,
                                                  short* __restrict__ zx) {
    __shared__ short As[128][64];
    __shared__ short Bs[128][64];
    int tid = threadIdx.x;
    int lane = tid & 63;
    int wave = tid >> 6;
    int wr = wave >> 1, wc = wave & 1;
    int id = blockIdx.x;
    int xcd = id & 7;
    int pos = id >> 3;               // [0, 280)
    int j0 = (pos % 35) * 128;
    int m0 = (xcd * 8 + pos / 35) * 128;
    int srow = tid >> 3;
    int skc = (((tid & 7) ^ ((tid >> 3) & 7)) * 8);   // pre-swizzled source k-chunk

    f32x4 acc[4][4] = {};

    for (int k0 = 0; k0 < DM; k0 += 64) {
        __syncthreads();
#pragma unroll
        for (int q = 0; q < 4; q++) {
            gload16(Wb + (size_t)(j0 + q * 32 + srow) * DM + k0 + skc,
                    ((short*)As) + q * 2048 + wave * 512);
            gload16(xn + (size_t)(m0 + q * 32 + srow) * DM + k0 + skc,
                    ((short*)Bs) + q * 2048 + wave * 512);
        }
        asm volatile("s_waitcnt vmcnt(0)" ::: "memory");
        __syncthreads();
#pragma unroll
        for (int ks = 0; ks < 2; ks++) {
            int pch = (((ks * 4) + (lane >> 4)) ^ (lane & 7)) * 8;
            bf16x8 af[4], bfr[4];
#pragma unroll
            for (int i = 0; i < 4; i++)
                af[i] = *(const bf16x8*)&As[wr * 64 + i * 16 + (lane & 15)][pch];
#pragma unroll
            for (int n = 0; n < 4; n++)
                bfr[n] = *(const bf16x8*)&Bs[wc * 64 + n * 16 + (lane & 15)][pch];
#pragma unroll
            for (int i = 0; i < 4; i++)
#pragma unroll
                for (int n = 0; n < 4; n++)
                    acc[i][n] = __builtin_amdgcn_mfma_f32_16x16x32_bf16(af[i], bfr[n], acc[i][n], 0, 0, 0);
        }
    }
#pragma unroll
    for (int i = 0; i < 4; i++) {
        int j = j0 + wr * 64 + i * 16 + ((lane >> 4) << 2);
        if (j < DIP) {
#pragma unroll
            for (int n = 0; n < 4; n++) {
                int m = m0 + wc * 64 + n * 16 + (lane & 15);
                short4 s4;
                s4.x = f2bs(acc[i][n][0]); s4.y = f2bs(acc[i][n][1]);
                s4.z = f2bs(acc[i][n][2]); s4.w = f2bs(acc[i][n][3]);
                *(short4*)(zx + (size_t)m * DIP + j) = s4;
            }
        }
    }
}

// ---------------- Kernel 2b: f32 strip GEMM, dt cols, fused bias+softplus -> dtv ----------------
__global__ __launch_bounds__(256) void gemm1_strip(const float* __restrict__ x,
                                                   const float* __restrict__ mu,
                                                   const float* __restrict__ rs,
                                                   const float* __restrict__ ln_w,
                                                   const float* __restrict__ ln_b,
                                                   const float* __restrict__ Win,
                                                   const float* __restrict__ dt_bias,
                                                   float* __restrict__ dtv) {
    __shared__ float As[16][64];
    __shared__ float Ws[64][17];
    int tid = threadIdx.x;
    int tx = tid & 15;
    int ty = tid >> 4;
    int j0 = 4352;
    int m0 = blockIdx.y * 64;
    int b = m0 >> 12;
    int t0 = m0 & 4095;
    const float* Xb = x + (size_t)b * DM * TT + t0;

    int lr = tid >> 4;
    int lc = (tid & 15) * 4;
    int wr = tid >> 2;
    int wc = (tid & 3) * 4;

    float acc[4][4] = {};
    for (int k0 = 0; k0 < DM; k0 += 16) {
        float4 xv = *(const float4*)(Xb + (size_t)(k0 + lr) * TT + lc);
        float4 muv = *(const float4*)(&mu[m0 + lc]);
        float4 rsv = *(const float4*)(&rs[m0 + lc]);
        float lw = ln_w[k0 + lr], lb = ln_b[k0 + lr];
        As[lr][lc]     = (xv.x - muv.x) * rsv.x * lw + lb;
        As[lr][lc + 1] = (xv.y - muv.y) * rsv.y * lw + lb;
        As[lr][lc + 2] = (xv.z - muv.z) * rsv.z * lw + lb;
        As[lr][lc + 3] = (xv.w - muv.w) * rsv.w * lw + lb;

        int j = j0 + wr;
        float4 wv = make_float4(0.f, 0.f, 0.f, 0.f);
        if (j < DIP) wv = *(const float4*)(Win + (size_t)j * DM + k0 + wc);
        Ws[wr][wc] = wv.x; Ws[wr][wc + 1] = wv.y; Ws[wr][wc + 2] = wv.z; Ws[wr][wc + 3] = wv.w;
        __syncthreads();
#pragma unroll
        for (int kk = 0; kk < 16; kk++) {
            float4 a4 = *(const float4*)&As[kk][ty * 4];
            float a[4] = {a4.x, a4.y, a4.z, a4.w};
            float bv[4];
#pragma unroll
            for (int n = 0; n < 4; n++) bv[n] = Ws[tx * 4 + n][kk];
#pragma unroll
            for (int i = 0; i < 4; i++)
#pragma unroll
                for (int n = 0; n < 4; n++)
                    acc[i][n] = fmaf(a[i], bv[n], acc[i][n]);
        }
        __syncthreads();
    }
#pragma unroll
    for (int i = 0; i < 4; i++) {
        int m = m0 + ty * 4 + i;
        int j = j0 + tx * 4;
        if (j + 3 < DIP) {
            int hh = j - 4352;
            float4 v;
            float r0 = acc[i][0] + dt_bias[hh];
            float r1 = acc[i][1] + dt_bias[hh + 1];
            float r2 = acc[i][2] + dt_bias[hh + 2];
            float r3 = acc[i][3] + dt_bias[hh + 3];
            v.x = (r0 > 20.f) ? r0 : log1pf(expf(r0));
            v.y = (r1 > 20.f) ? r1 : log1pf(expf(r1));
            v.z = (r2 > 20.f) ? r2 : log1pf(expf(r2));
            v.w = (r3 > 20.f) ? r3 : log1pf(expf(r3));
            *(float4*)(dtv + (size_t)m * NH + hh) = v;
        }
    }
}

// ---------------- Kernel 3: causal depthwise conv(4) + SiLU (bf16 in/out) ----------------
__global__ __launch_bounds__(256) void conv_kernel(const short* __restrict__ zx,
                                                   const float* __restrict__ cw,
                                                   const float* __restrict__ cb,
                                                   short* __restrict__ xBC) {
    size_t i = ((size_t)blockIdx.x * 256 + threadIdx.x) * 8;
    int c = (int)(i % CD);
    int t = (int)((i / CD) & (TT - 1));
    int b = (int)(i / ((size_t)CD * TT));
    const short* src = zx + (size_t)b * TT * DIP + DI + c;
    float acc[8];
#pragma unroll
    for (int e = 0; e < 8; e++) acc[e] = cb[c + e];
    float wv[8][4];
#pragma unroll
    for (int e = 0; e < 8; e++) {
        float4 w4 = *(const float4*)(cw + (c + e) * 4);
        wv[e][0] = w4.x; wv[e][1] = w4.y; wv[e][2] = w4.z; wv[e][3] = w4.w;
    }
#pragma unroll
    for (int k = 0; k < 4; k++) {
        int ts = t - 3 + k;
        if (ts >= 0) {
            bf16x8 v = *(const bf16x8*)(src + (size_t)ts * DIP);
#pragma unroll
            for (int e = 0; e < 8; e++)
                acc[e] = fmaf(wv[e][k], b2f(v[e]), acc[e]);
        }
    }
    short o[8];
#pragma unroll
    for (int e = 0; e < 8; e++) {
        float sg = 1.f / (1.f + expf(-acc[e]));
        o[e] = f2bs(acc[e] * sg);
    }
    *(bf16x8*)(xBC + i) = *(bf16x8*)o;
}

// ---------------- Kernel 5a: SSD chunk reduce — MFMA state-only pass (bf16 input) ----------------
__global__ __launch_bounds__(256, 2) void scan_reduce_ssd(const short* __restrict__ xBC,
                                                          const float* __restrict__ dtg,
                                                          const float* __restrict__ A_log,
                                                          float* __restrict__ S,
                                                          float* __restrict__ P) {
    int tid = threadIdx.x;
    int wave = tid >> 6, lane = tid & 63;
    int l4 = lane >> 4, l16 = lane & 15;
    int c = blockIdx.x, hh = blockIdx.y, b = blockIdx.z;
    int cbase = c * CL;

    __shared__ __align__(16) short BtL[64][136];
    __shared__ __align__(16) short XdL[64][72];
    __shared__ __align__(16) float sdt[64];
    __shared__ __align__(16) float sL[64];
    __shared__ __align__(16) float sW[64];

    f32x4 acc_h[2][4];
#pragma unroll
    for (int i = 0; i < 2; i++)
#pragma unroll
        for (int pq = 0; pq < 4; pq++) acc_h[i][pq] = (f32x4){0.f, 0.f, 0.f, 0.f};
    float Lsum = 0.f;

    float expA = expf(A_log[hh]);
    const float* dtb = dtg + (size_t)b * TT * NH + hh;
    const short* xb = xBC + (size_t)b * TT * CD;

#pragma unroll 1
    for (int f = 0; f < FPC; f++) {
        int t0 = cbase + f * FL;
        if (tid < 64) sdt[tid] = dtb[(size_t)(t0 + tid) * NH];
        {
            int r = tid >> 2, q = tid & 3;
            const short* bs = xb + (size_t)(t0 + r) * CD + DI + q * 32;
#pragma unroll
            for (int j = 0; j < 4; j++)
                *(bf16x8*)&BtL[r][q * 32 + j * 8] = *(const bf16x8*)(bs + j * 8);
        }
        __syncthreads();
        if (tid < 64) {
            float v = -expA * sdt[tid];
#pragma unroll
            for (int off = 1; off < 64; off <<= 1) {
                float u = __shfl_up(v, off);
                if (lane >= off) v += u;
            }
            sL[tid] = v;
            float lt = __shfl(v, 63);
            sW[tid] = expf(lt - v);
        }
        __syncthreads();
        {
            int s = tid & 63, pg2 = tid >> 6;
            const short* xs = xb + (size_t)(t0 + s) * CD + hh * HD + pg2 * 16;
            float dts = sdt[s];
            bf16x8 v0 = *(const bf16x8*)xs;
            bf16x8 v1 = *(const bf16x8*)(xs + 8);
#pragma unroll
            for (int j = 0; j < 8; j++) XdL[pg2 * 16 + j][s] = f2bs(b2f(v0[j]) * dts);
#pragma unroll
            for (int j = 0; j < 8; j++) XdL[pg2 * 16 + 8 + j][s] = f2bs(b2f(v1[j]) * dts);
        }
        __syncthreads();
        float Lft = sL[63];
        float Pf = expf(Lft);
        Lsum += Lft;
#pragma unroll
        for (int i = 0; i < 2; i++)
#pragma unroll
            for (int pq = 0; pq < 4; pq++) acc_h[i][pq] *= Pf;
#pragma unroll
        for (int ks = 0; ks < 2; ks++) {
            bf16x8 af2[2], bfw[4];
#pragma unroll
            for (int i = 0; i < 2; i++) {
                int nrow = wave * 32 + i * 16 + l16;
                short e[8];
#pragma unroll
                for (int j = 0; j < 8; j++) {
                    int s = ks * 32 + l4 * 8 + j;
                    e[j] = f2bs(b2f(BtL[s][nrow]) * sW[s]);
                }
                af2[i] = *(bf16x8*)e;
            }
#pragma unroll
            for (int pq = 0; pq < 4; pq++)
                bfw[pq] = *(const bf16x8*)&XdL[pq * 16 + l16][ks * 32 + l4 * 8];
#pragma unroll
            for (int i = 0; i < 2; i++)
#pragma unroll
                for (int pq = 0; pq < 4; pq++)
                    acc_h[i][pq] = __builtin_amdgcn_mfma_f32_16x16x32_bf16(af2[i], bfw[pq], acc_h[i][pq], 0, 0, 0);
        }
        __syncthreads();
    }

    float* Sp = S + (size_t)c * SELEMS + ((size_t)(b * NH + hh) * HD) * DSTATE;
#pragma unroll
    for (int i = 0; i < 2; i++)
#pragma unroll
        for (int pq = 0; pq < 4; pq++) {
            int nb = wave * 32 + i * 16 + (l4 << 2);
            int p = pq * 16 + l16;
            *(f32x4*)(Sp + (size_t)p * DSTATE + nb) = acc_h[i][pq];
        }
    if (tid == 0) P[(c * BB + b) * NH + hh] = expf(Lsum);
}

// ---------------- Kernel 5b: sequential chunk combine ----------------
__global__ __launch_bounds__(256) void scan_combine_kernel(const float* __restrict__ h0,
                                                           const float* __restrict__ P,
                                                           float* __restrict__ S,
                                                           float* __restrict__ hT) {
    size_t tid = (size_t)blockIdx.x * 256 + threadIdx.x;
    int hh = (int)((tid >> 13) & 31);
    int b = (int)(tid >> 18);
    float h = h0[tid];
#pragma unroll
    for (int c = 0; c < NC; c++) {
        float s = S[(size_t)c * SELEMS + tid];
        S[(size_t)c * SELEMS + tid] = h;
        h = fmaf(P[(c * BB + b) * NH + hh], h, s);
    }
    hT[tid] = h;
}

// ---------------- Kernel 5c: SSD emit (bf16 input, f32 y to ybuf) ----------------
__global__ __launch_bounds__(256, 2) void scan_emit_ssd(const short* __restrict__ xBC,
                                                        const float* __restrict__ dtg,
                                                        const float* __restrict__ A_log,
                                                        const float* __restrict__ S,
                                                        const float* __restrict__ Dp,
                                                        float* __restrict__ ybuf) {
    int tid = threadIdx.x;
    int wave = tid >> 6, lane = tid & 63;
    int l4 = lane >> 4, l16 = lane & 15;
    int c = blockIdx.x, hh = blockIdx.y, b = blockIdx.z;
    int cbase = c * CL;

    __shared__ __align__(16) short CtL[64][136];
    __shared__ __align__(16) short BtL[64][136];
    __shared__ __align__(16) short hL[64][132];
    __shared__ __align__(16) short XdL[64][72];
    __shared__ __align__(16) short ML[64][72];
    __shared__ __align__(16) float sdt[64];
    __shared__ __align__(16) float sL[64];
    __shared__ __align__(16) float sW[64];
    __shared__ __align__(16) float sRdt[64];

    f32x4 acc_h[2][4];
    {
        const float* Sp = S + (size_t)c * SELEMS + ((size_t)(b * NH + hh) * HD) * DSTATE;
#pragma unroll
        for (int i = 0; i < 2; i++)
#pragma unroll
            for (int pq = 0; pq < 4; pq++) {
                int nb = wave * 32 + i * 16 + (l4 << 2);
                int p = pq * 16 + l16;
                acc_h[i][pq] = *(const f32x4*)(Sp + (size_t)p * DSTATE + nb);
            }
    }

    float expA = expf(A_log[hh]);
    float Dh = Dp[hh];
    const float* dtb = dtg + (size_t)b * TT * NH + hh;
    const short* xb = xBC + (size_t)b * TT * CD;
    float* yb = ybuf + (size_t)b * TT * DI + hh * HD;

    int tg = wave >> 1;
    int sg = wave & 1;

#pragma unroll 1
    for (int f = 0; f < FPC; f++) {
        int t0 = cbase + f * FL;

        if (tid < 64) sdt[tid] = dtb[(size_t)(t0 + tid) * NH];
        {
            int r = tid >> 2, q = tid & 3;
            const short* cs = xb + (size_t)(t0 + r) * CD + DI + DSTATE + q * 32;
            const short* bs = xb + (size_t)(t0 + r) * CD + DI + q * 32;
#pragma unroll
            for (int j = 0; j < 4; j++) {
                *(bf16x8*)&CtL[r][q * 32 + j * 8] = *(const bf16x8*)(cs + j * 8);
                *(bf16x8*)&BtL[r][q * 32 + j * 8] = *(const bf16x8*)(bs + j * 8);
            }
        }
#pragma unroll
        for (int i = 0; i < 2; i++)
#pragma unroll
            for (int pq = 0; pq < 4; pq++) {
                int nb = wave * 32 + i * 16 + (l4 << 2);
                int p = pq * 16 + l16;
                *(short2*)&hL[p][nb] = make_short2(f2bs(acc_h[i][pq][0]), f2bs(acc_h[i][pq][1]));
                *(short2*)&hL[p][nb + 2] = make_short2(f2bs(acc_h[i][pq][2]), f2bs(acc_h[i][pq][3]));
            }
        __syncthreads();

        if (tid < 64) {
            float v = -expA * sdt[tid];
#pragma unroll
            for (int off = 1; off < 64; off <<= 1) {
                float u = __shfl_up(v, off);
                if (lane >= off) v += u;
            }
            sL[tid] = v;
            float lt = __shfl(v, 63);
            sW[tid] = expf(lt - v);
            sRdt[tid] = 1.f / sdt[tid];
        }
        __syncthreads();

        {
            int s = tid & 63, pg = tid >> 6;
            const short* xs = xb + (size_t)(t0 + s) * CD + hh * HD + pg * 16;
            float dts = sdt[s];
            bf16x8 v0 = *(const bf16x8*)xs;
            bf16x8 v1 = *(const bf16x8*)(xs + 8);
#pragma unroll
            for (int j = 0; j < 8; j++) XdL[pg * 16 + j][s] = f2bs(b2f(v0[j]) * dts);
#pragma unroll
            for (int j = 0; j < 8; j++) XdL[pg * 16 + 8 + j][s] = f2bs(b2f(v1[j]) * dts);
        }
        __syncthreads();

        {
            f32x4 g[2][2] = {};
#pragma unroll
            for (int ks = 0; ks < 4; ks++) {
                bf16x8 af[2], bfm[2];
#pragma unroll
                for (int i = 0; i < 2; i++)
                    af[i] = *(const bf16x8*)&CtL[tg * 32 + i * 16 + l16][ks * 32 + l4 * 8];
#pragma unroll
                for (int n = 0; n < 2; n++)
                    bfm[n] = *(const bf16x8*)&BtL[sg * 32 + n * 16 + l16][ks * 32 + l4 * 8];
#pragma unroll
                for (int i = 0; i < 2; i++)
#pragma unroll
                    for (int n = 0; n < 2; n++)
                        g[i][n] = __builtin_amdgcn_mfma_f32_16x16x32_bf16(af[i], bfm[n], g[i][n], 0, 0, 0);
            }
#pragma unroll
            for (int i = 0; i < 2; i++) {
                int tb2 = tg * 32 + i * 16 + (l4 << 2);
                float4 Lt = *(const float4*)&sL[tb2];
                float Ltr[4] = {Lt.x, Lt.y, Lt.z, Lt.w};
#pragma unroll
                for (int n = 0; n < 2; n++) {
                    int sE = sg * 32 + n * 16 + l16;
                    float Ls = sL[sE];
#pragma unroll
                    for (int r2 = 0; r2 < 4; r2++) {
                        float m = (sE <= tb2 + r2) ? g[i][n][r2] * expf(Ltr[r2] - Ls) : 0.f;
                        ML[tb2 + r2][sE] = f2bs(m);
                    }
                }
            }
        }
        __syncthreads();

        {
            f32x4 ay[2][2] = {};
            f32x4 ai[2][2] = {};
#pragma unroll
            for (int ks = 0; ks < 2; ks++) {
                bf16x8 af[2], bfp[2];
#pragma unroll
                for (int i = 0; i < 2; i++)
                    af[i] = *(const bf16x8*)&ML[tg * 32 + i * 16 + l16][ks * 32 + l4 * 8];
#pragma unroll
                for (int n = 0; n < 2; n++)
                    bfp[n] = *(const bf16x8*)&XdL[sg * 32 + n * 16 + l16][ks * 32 + l4 * 8];
#pragma unroll
                for (int i = 0; i < 2; i++)
#pragma unroll
                    for (int n = 0; n < 2; n++)
                        ay[i][n] = __builtin_amdgcn_mfma_f32_16x16x32_bf16(af[i], bfp[n], ay[i][n], 0, 0, 0);
            }
#pragma unroll
            for (int ks = 0; ks < 4; ks++) {
                bf16x8 af[2], bfh[2];
#pragma unroll
                for (int i = 0; i < 2; i++)
                    af[i] = *(const bf16x8*)&CtL[tg * 32 + i * 16 + l16][ks * 32 + l4 * 8];
#pragma unroll
                for (int n = 0; n < 2; n++) {
                    int prow = sg * 32 + n * 16 + l16;
                    int kb = ks * 32 + l4 * 8;
                    union { bf16x8 v; uint2 u2[2]; } hu;
                    hu.u2[0] = *(const uint2*)&hL[prow][kb];
                    hu.u2[1] = *(const uint2*)&hL[prow][kb + 4];
                    bfh[n] = hu.v;
                }
#pragma unroll
                for (int i = 0; i < 2; i++)
#pragma unroll
                    for (int n = 0; n < 2; n++)
                        ai[i][n] = __builtin_amdgcn_mfma_f32_16x16x32_bf16(af[i], bfh[n], ai[i][n], 0, 0, 0);
            }
            float Lft = sL[63];
#pragma unroll
            for (int i = 0; i < 2; i++) {
                int tb2 = tg * 32 + i * 16 + (l4 << 2);
                float4 Lt = *(const float4*)&sL[tb2];
                float4 Rt = *(const float4*)&sRdt[tb2];
                float Ltr[4] = {Lt.x, Lt.y, Lt.z, Lt.w};
                float Rtr[4] = {Rt.x, Rt.y, Rt.z, Rt.w};
#pragma unroll
                for (int n = 0; n < 2; n++) {
                    int p = sg * 32 + n * 16 + l16;
#pragma unroll
                    for (int r2 = 0; r2 < 4; r2++) {
                        float xv = b2f(XdL[p][tb2 + r2]) * Rtr[r2];
                        float yv = ay[i][n][r2] + expf(Ltr[r2]) * ai[i][n][r2] + Dh * xv;
                        yb[(size_t)(t0 + tb2 + r2) * DI + p] = yv;
                    }
                }
            }
            float Pf = expf(Lft);
#pragma unroll
            for (int i = 0; i < 2; i++)
#pragma unroll
                for (int pq = 0; pq < 4; pq++)
                    acc_h[i][pq] *= Pf;
#pragma unroll
            for (int ks = 0; ks < 2; ks++) {
                bf16x8 af2[2], bfw[4];
#pragma unroll
                for (int i = 0; i < 2; i++) {
                    int nrow = wave * 32 + i * 16 + l16;
                    short e[8];
#pragma unroll
                    for (int j = 0; j < 8; j++) {
                        int s = ks * 32 + l4 * 8 + j;
                        e[j] = f2bs(b2f(BtL[s][nrow]) * sW[s]);
                    }
                    af2[i] = *(bf16x8*)e;
                }
#pragma unroll
                for (int pq = 0; pq < 4; pq++)
                    bfw[pq] = *(const bf16x8*)&XdL[pq * 16 + l16][ks * 32 + l4 * 8];
#pragma unroll
                for (int i = 0; i < 2; i++)
#pragma unroll
                    for (int pq = 0; pq < 4; pq++)
                        acc_h[i][pq] = __builtin_amdgcn_mfma_f32_16x16x32_bf16(af2[i], bfw[pq], acc_h[i][pq], 0, 0, 0);
            }
        }
        __syncthreads();
    }
}

// ---------------- Kernel 6: gating + RMSNorm (f32 y, bf16 z) -> bf16 g ----------------
__global__ __launch_bounds__(256) void gate_rms_kernel(const float* __restrict__ ybuf,
                                                       const short* __restrict__ zx,
                                                       const float* __restrict__ rw,
                                                       __hip_bfloat16* __restrict__ gq) {
    int m = blockIdx.x;
    int tid = threadIdx.x;
    const float* yr = ybuf + (size_t)m * DI;
    const short* zr = zx + (size_t)m * DIP;
    int base = tid * 8;
    float gv[8];
    float ss = 0.f;
    float4 ya = *(const float4*)(yr + base);
    float4 yb4 = *(const float4*)(yr + base + 4);
    bf16x8 zv8 = *(const bf16x8*)(zr + base);
    float yv[8] = {ya.x, ya.y, ya.z, ya.w, yb4.x, yb4.y, yb4.z, yb4.w};
#pragma unroll
    for (int i = 0; i < 8; i++) {
        float z = b2f(zv8[i]);
        float sg = 1.f / (1.f + expf(-z));
        float gg = yv[i] * z * sg;
        gv[i] = gg;
        ss += gg * gg;
    }
#pragma unroll
    for (int off = 1; off < 64; off <<= 1) ss += __shfl_xor(ss, off);
    __shared__ float red[4];
    int w = tid >> 6;
    if ((tid & 63) == 0) red[w] = ss;
    __syncthreads();
    float tot = red[0] + red[1] + red[2] + red[3];
    float r = rsqrtf(tot * (1.f / DI) + 1e-5f);
#pragma unroll
    for (int i = 0; i < 8; i += 2) {
        __hip_bfloat162 p;
        p.x = __float2bfloat16(gv[i] * r * rw[base + i]);
        p.y = __float2bfloat16(gv[i + 1] * r * rw[base + i + 1]);
        *(__hip_bfloat162*)(gq + (size_t)m * DI + base + i) = p;
    }
}

// ---------------- Kernel 7: GEMM2 bf16 MFMA (T2 swizzle + T1 remap, transposed store) ----------------
// 1-D grid of 512 wgs. xcd = id%8 owns m-strip [xcd*8, xcd*8+8) x all 8 j-tiles.
__global__ __launch_bounds__(256) void gemm2_mfma(const __hip_bfloat16* __restrict__ gq,
                                                  const __hip_bfloat16* __restrict__ Wob,
                                                  float* __restrict__ out) {
    __shared__ short As[128][64];
    __shared__ short Bs[128][64];
    int tid = threadIdx.x;
    int lane = tid & 63;
    int wave = tid >> 6;
    int wr = wave >> 1, wc = wave & 1;
    int id = blockIdx.x;
    int xcd = id & 7;
    int pos = id >> 3;               // [0, 64)
    int j0 = (pos & 7) * 128;
    int m0 = (xcd * 8 + (pos >> 3)) * 128;
    int srow = tid >> 3;
    int skc = (((tid & 7) ^ ((tid >> 3) & 7)) * 8);

    f32x4 acc[4][4] = {};

    for (int k0 = 0; k0 < DI; k0 += 64) {
        __syncthreads();
#pragma unroll
        for (int q = 0; q < 4; q++) {
            gload16(gq + (size_t)(m0 + q * 32 + srow) * DI + k0 + skc,
                    ((short*)As) + q * 2048 + wave * 512);
            gload16(Wob + (size_t)(j0 + q * 32 + srow) * DI + k0 + skc,
                    ((short*)Bs) + q * 2048 + wave * 512);
        }
        asm volatile("s_waitcnt vmcnt(0)" ::: "memory");
        __syncthreads();
#pragma unroll
        for (int ks = 0; ks < 2; ks++) {
            int pch = (((ks * 4) + (lane >> 4)) ^ (lane & 7)) * 8;
            bf16x8 af[4], bfr[4];
#pragma unroll
            for (int i = 0; i < 4; i++)
                af[i] = *(const bf16x8*)&As[wr * 64 + i * 16 + (lane & 15)][pch];
#pragma unroll
            for (int n = 0; n < 4; n++)
                bfr[n] = *(const bf16x8*)&Bs[wc * 64 + n * 16 + (lane & 15)][pch];
#pragma unroll
            for (int i = 0; i < 4; i++)
#pragma unroll
                for (int n = 0; n < 4; n++)
                    acc[i][n] = __builtin_amdgcn_mfma_f32_16x16x32_bf16(af[i], bfr[n], acc[i][n], 0, 0, 0);
        }
    }
#pragma unroll
    for (int i = 0; i < 4; i++) {
        int m = m0 + wr * 64 + i * 16 + ((lane >> 4) << 2);
        int b = m >> 12;
        int t = m & 4095;
#pragma unroll
        for (int n = 0; n < 4; n++) {
            int j = j0 + wc * 64 + n * 16 + (lane & 15);
            *(f32x4*)(out + (size_t)b * DM * TT + (size_t)j * TT + t) = acc[i][n];
        }
    }
}

extern "C" void kernel_launch(void* const* d_in, const int* in_sizes, int n_in,
                              void* d_out, int out_size, void* d_ws, size_t ws_size,
                              hipStream_t stream) {
    const float* x       = (const float*)d_in[0];
    const float* ln_w    = (const float*)d_in[1];
    const float* ln_b    = (const float*)d_in[2];
    const float* W_in    = (const float*)d_in[3];
    const float* conv_w  = (const float*)d_in[4];
    const float* conv_b  = (const float*)d_in[5];
    const float* dt_bias = (const float*)d_in[6];
    const float* A_log   = (const float*)d_in[7];
    const float* Dp      = (const float*)d_in[8];
    const float* rms_w   = (const float*)d_in[9];
    const float* W_out   = (const float*)d_in[10];
    const float* h0      = (const float*)d_in[11];

    float* out = (float*)d_out;
    float* hT = out + (size_t)BB * DM * TT;

    char* ws = (char*)d_ws;
    // Workspace layout — total 194,578,432 bytes:
    float* mu   = (float*)(ws + 0);                       //      32,768
    float* rs   = (float*)(ws + 32768);                   //      32,768
    short* zxq  = (short*)(ws + 65536);                   //  71,827,456  (B,T,4384) bf16
    short* xBCq = (short*)(ws + 71892992);                //  37,748,736  (B,T,2304) bf16
    __hip_bfloat16* gq  = (__hip_bfloat16*)(ws + 71892992);        // overlays xBC (post-emit)
    __hip_bfloat16* Wob = (__hip_bfloat16*)(ws + 105447424);       // overlays xBC tail (post-emit)
    float* ybuf = (float*)(ws + 109641728);               //  67,108,864  (B,T,2048) f32
    __hip_bfloat16* Wb  = (__hip_bfloat16*)(ws + 109641728);       // overlays ybuf (pre-scan)
    float* dtv  = (float*)(ws + 176750592);               //   1,048,576
    __hip_bfloat16* xnb = (__hip_bfloat16*)(ws + 177799168);       //  16,777,216 (shares S)
    float* S    = (float*)(ws + 177799168);
    float* P    = (float*)(ws + 194576384);               //       2,048

    ln_stats_kernel<<<dim3(TT / 64, BB), 64, 0, stream>>>(x, mu, rs);
    xn_kernel<<<dim3(TT / 64, DM / 64, BB), 256, 0, stream>>>(x, mu, rs, ln_w, ln_b, xnb);
    cvt_pad_kernel<<<(NP1 * DM) / 1024, 256, 0, stream>>>(W_in, Wb, DIP * DM, NP1 * DM);
    gemm1_mfma<<<(NP1 / 128) * ((BB * TT) / 128), 256, 0, stream>>>(Wb, xnb, zxq);
    gemm1_strip<<<dim3(1, (BB * TT) / 64), 256, 0, stream>>>(x, mu, rs, ln_w, ln_b, W_in, dt_bias, dtv);
    conv_kernel<<<(int)(((size_t)BB * TT * CD) / 2048), 256, 0, stream>>>(zxq, conv_w, conv_b, xBCq);
    scan_reduce_ssd<<<dim3(NC, NH, BB), 256, 0, stream>>>(xBCq, dtv, A_log, S, P);
    scan_combine_kernel<<<(int)(SELEMS / 256), 256, 0, stream>>>(h0, P, S, hT);
    scan_emit_ssd<<<dim3(NC, NH, BB), 256, 0, stream>>>(xBCq, dtv, A_log, S, Dp, ybuf);
    cvt_pad_kernel<<<(DM * DI) / 1024, 256, 0, stream>>>(W_out, Wob, DM * DI, DM * DI);
    gate_rms_kernel<<<BB * TT, 256, 0, stream>>>(ybuf, zxq, rms_w, gq);
    gemm2_mfma<<<((BB * TT) / 128) * (DM / 128), 256, 0, stream>>>(gq, Wob, out);
}

// Round 13
// 458.331 us; speedup vs baseline: 4.8470x; 1.0546x over previous
//
#include <hip/hip_runtime.h>
#include <hip/hip_bf16.h>
#include <math.h>

// Problem constants
#define BB 2
#define TT 4096
#define DM 1024
#define DSTATE 128
#define DI 2048
#define HD 64
#define NH 32
#define DIP 4384   // 2*DI + 2*DSTATE + NH
#define CD 2304    // DI + 2*DSTATE

// Chunked scan parameters
#define NC 8
#define CL 512
#define FL 64            // SSD fine-chunk length
#define FPC (CL / FL)    // 8
#define SELEMS ((size_t)BB * NH * HD * DSTATE)   // 524288

#define NP1 4480   // DIP padded to multiple of 128 for MFMA staging

typedef __attribute__((ext_vector_type(8))) short bf16x8;
typedef __attribute__((ext_vector_type(4))) float f32x4;

__device__ inline void gload16(const void* g, void* l) {
    __builtin_amdgcn_global_load_lds(
        (const __attribute__((address_space(1))) void*)g,
        (__attribute__((address_space(3))) void*)l, 16, 0, 0);
}

__device__ inline short f2bs(float f) {
    __hip_bfloat16 h = __float2bfloat16(f);
    union { __hip_bfloat16 h; short s; } u;
    u.h = h;
    return u.s;
}
__device__ inline float b2f(short s) {
    union { float f; unsigned u; } u;
    u.u = ((unsigned)(unsigned short)s) << 16;
    return u.f;
}

// ---------------- Kernel 1: LayerNorm statistics ----------------
__global__ __launch_bounds__(64) void ln_stats_kernel(const float* __restrict__ x,
                                                      float* __restrict__ mu,
                                                      float* __restrict__ rs) {
    int t = blockIdx.x * 64 + threadIdx.x;
    int b = blockIdx.y;
    const float* xb = x + (size_t)b * DM * TT + t;
    float s = 0.f, ss = 0.f;
#pragma unroll 8
    for (int d = 0; d < DM; d++) {
        float v = xb[(size_t)d * TT];
        s += v;
        ss += v * v;
    }
    float m = s * (1.f / DM);
    float var = ss * (1.f / DM) - m * m;
    int idx = b * TT + t;
    mu[idx] = m;
    rs[idx] = rsqrtf(var + 1e-5f);
}

// ---------------- Kernel 1b: xn = LN(x) transposed to (m, k) in bf16 ----------------
__global__ __launch_bounds__(256) void xn_kernel(const float* __restrict__ x,
                                                 const float* __restrict__ mu,
                                                 const float* __restrict__ rs,
                                                 const float* __restrict__ ln_w,
                                                 const float* __restrict__ ln_b,
                                                 __hip_bfloat16* __restrict__ xn) {
    __shared__ float tile[64][65];
    int tid = threadIdx.x;
    int t0 = blockIdx.x * 64, d0 = blockIdx.y * 64, b = blockIdx.z;
#pragma unroll
    for (int i = 0; i < 64; i += 4) {
        int dl = i + (tid >> 6);
        tile[dl][tid & 63] = x[(size_t)b * DM * TT + (size_t)(d0 + dl) * TT + t0 + (tid & 63)];
    }
    __syncthreads();
#pragma unroll
    for (int i = 0; i < 64; i += 8) {
        int tl = i + (tid >> 5);
        int kk = (tid & 31) * 2;
        int m = b * TT + t0 + tl;
        float mu_m = mu[m], rs_m = rs[m];
        float v0 = (tile[kk][tl] - mu_m) * rs_m * ln_w[d0 + kk] + ln_b[d0 + kk];
        float v1 = (tile[kk + 1][tl] - mu_m) * rs_m * ln_w[d0 + kk + 1] + ln_b[d0 + kk + 1];
        __hip_bfloat162 pk;
        pk.x = __float2bfloat16(v0);
        pk.y = __float2bfloat16(v1);
        *(__hip_bfloat162*)(xn + (size_t)m * DM + d0 + kk) = pk;
    }
}

// ---------------- convert f32 -> bf16 with zero-padding ----------------
__global__ __launch_bounds__(256) void cvt_pad_kernel(const float* __restrict__ src,
                                                      __hip_bfloat16* __restrict__ dst,
                                                      int src_n, int tot_n) {
    int i = (blockIdx.x * 256 + threadIdx.x) * 4;
    if (i >= tot_n) return;
    float4 v = (i < src_n) ? *(const float4*)(src + i) : make_float4(0.f, 0.f, 0.f, 0.f);
    __hip_bfloat162 p0, p1;
    p0.x = __float2bfloat16(v.x); p0.y = __float2bfloat16(v.y);
    p1.x = __float2bfloat16(v.z); p1.y = __float2bfloat16(v.w);
    *(__hip_bfloat162*)(dst + i) = p0;
    *(__hip_bfloat162*)(dst + i + 2) = p1;
}

// ---------------- Kernel 2: GEMM1 bf16 MFMA (T2 swizzle + T1 remap, m-inner) ----------------
// 1-D grid of 2240 wgs. xcd = id%8 owns m-strip [xcd*8, xcd*8+8).
// Within XCD: m FASTEST (8 m-tiles = 2.1 MB xn strip stays L2-resident),
// j outer (each 262 KB W panel streamed once per XCD).
__global__ __launch_bounds__(256) void gemm1_mfma(const __hip_bfloat16* __restrict__ Wb,
                                                  const __hip_bfloat16* __restrict__ xn,
                                                  short* __restrict__ zx) {
    __shared__ short As[128][64];
    __shared__ short Bs[128][64];
    int tid = threadIdx.x;
    int lane = tid & 63;
    int wave = tid >> 6;
    int wr = wave >> 1, wc = wave & 1;
    int id = blockIdx.x;
    int xcd = id & 7;
    int pos = id >> 3;               // [0, 280)
    int j0 = (pos >> 3) * 128;       // j outer: 35 panels
    int m0 = (xcd * 8 + (pos & 7)) * 128;   // m inner: strip resident in L2
    int srow = tid >> 3;
    int skc = (((tid & 7) ^ ((tid >> 3) & 7)) * 8);   // pre-swizzled source k-chunk

    f32x4 acc[4][4] = {};

    for (int k0 = 0; k0 < DM; k0 += 64) {
        __syncthreads();
#pragma unroll
        for (int q = 0; q < 4; q++) {
            gload16(Wb + (size_t)(j0 + q * 32 + srow) * DM + k0 + skc,
                    ((short*)As) + q * 2048 + wave * 512);
            gload16(xn + (size_t)(m0 + q * 32 + srow) * DM + k0 + skc,
                    ((short*)Bs) + q * 2048 + wave * 512);
        }
        asm volatile("s_waitcnt vmcnt(0)" ::: "memory");
        __syncthreads();
#pragma unroll
        for (int ks = 0; ks < 2; ks++) {
            int pch = (((ks * 4) + (lane >> 4)) ^ (lane & 7)) * 8;
            bf16x8 af[4], bfr[4];
#pragma unroll
            for (int i = 0; i < 4; i++)
                af[i] = *(const bf16x8*)&As[wr * 64 + i * 16 + (lane & 15)][pch];
#pragma unroll
            for (int n = 0; n < 4; n++)
                bfr[n] = *(const bf16x8*)&Bs[wc * 64 + n * 16 + (lane & 15)][pch];
#pragma unroll
            for (int i = 0; i < 4; i++)
#pragma unroll
                for (int n = 0; n < 4; n++)
                    acc[i][n] = __builtin_amdgcn_mfma_f32_16x16x32_bf16(af[i], bfr[n], acc[i][n], 0, 0, 0);
        }
    }
#pragma unroll
    for (int i = 0; i < 4; i++) {
        int j = j0 + wr * 64 + i * 16 + ((lane >> 4) << 2);
        if (j < DIP) {
#pragma unroll
            for (int n = 0; n < 4; n++) {
                int m = m0 + wc * 64 + n * 16 + (lane & 15);
                short4 s4;
                s4.x = f2bs(acc[i][n][0]); s4.y = f2bs(acc[i][n][1]);
                s4.z = f2bs(acc[i][n][2]); s4.w = f2bs(acc[i][n][3]);
                *(short4*)(zx + (size_t)m * DIP + j) = s4;
            }
        }
    }
}

// ---------------- Kernel 2b: f32 strip GEMM, dt cols, fused bias+softplus -> dtv ----------------
__global__ __launch_bounds__(256) void gemm1_strip(const float* __restrict__ x,
                                                   const float* __restrict__ mu,
                                                   const float* __restrict__ rs,
                                                   const float* __restrict__ ln_w,
                                                   const float* __restrict__ ln_b,
                                                   const float* __restrict__ Win,
                                                   const float* __restrict__ dt_bias,
                                                   float* __restrict__ dtv) {
    __shared__ float As[16][64];
    __shared__ float Ws[64][17];
    int tid = threadIdx.x;
    int tx = tid & 15;
    int ty = tid >> 4;
    int j0 = 4352;
    int m0 = blockIdx.y * 64;
    int b = m0 >> 12;
    int t0 = m0 & 4095;
    const float* Xb = x + (size_t)b * DM * TT + t0;

    int lr = tid >> 4;
    int lc = (tid & 15) * 4;
    int wr = tid >> 2;
    int wc = (tid & 3) * 4;

    float acc[4][4] = {};
    for (int k0 = 0; k0 < DM; k0 += 16) {
        float4 xv = *(const float4*)(Xb + (size_t)(k0 + lr) * TT + lc);
        float4 muv = *(const float4*)(&mu[m0 + lc]);
        float4 rsv = *(const float4*)(&rs[m0 + lc]);
        float lw = ln_w[k0 + lr], lb = ln_b[k0 + lr];
        As[lr][lc]     = (xv.x - muv.x) * rsv.x * lw + lb;
        As[lr][lc + 1] = (xv.y - muv.y) * rsv.y * lw + lb;
        As[lr][lc + 2] = (xv.z - muv.z) * rsv.z * lw + lb;
        As[lr][lc + 3] = (xv.w - muv.w) * rsv.w * lw + lb;

        int j = j0 + wr;
        float4 wv = make_float4(0.f, 0.f, 0.f, 0.f);
        if (j < DIP) wv = *(const float4*)(Win + (size_t)j * DM + k0 + wc);
        Ws[wr][wc] = wv.x; Ws[wr][wc + 1] = wv.y; Ws[wr][wc + 2] = wv.z; Ws[wr][wc + 3] = wv.w;
        __syncthreads();
#pragma unroll
        for (int kk = 0; kk < 16; kk++) {
            float4 a4 = *(const float4*)&As[kk][ty * 4];
            float a[4] = {a4.x, a4.y, a4.z, a4.w};
            float bv[4];
#pragma unroll
            for (int n = 0; n < 4; n++) bv[n] = Ws[tx * 4 + n][kk];
#pragma unroll
            for (int i = 0; i < 4; i++)
#pragma unroll
                for (int n = 0; n < 4; n++)
                    acc[i][n] = fmaf(a[i], bv[n], acc[i][n]);
        }
        __syncthreads();
    }
#pragma unroll
    for (int i = 0; i < 4; i++) {
        int m = m0 + ty * 4 + i;
        int j = j0 + tx * 4;
        if (j + 3 < DIP) {
            int hh = j - 4352;
            float4 v;
            float r0 = acc[i][0] + dt_bias[hh];
            float r1 = acc[i][1] + dt_bias[hh + 1];
            float r2 = acc[i][2] + dt_bias[hh + 2];
            float r3 = acc[i][3] + dt_bias[hh + 3];
            v.x = (r0 > 20.f) ? r0 : log1pf(expf(r0));
            v.y = (r1 > 20.f) ? r1 : log1pf(expf(r1));
            v.z = (r2 > 20.f) ? r2 : log1pf(expf(r2));
            v.w = (r3 > 20.f) ? r3 : log1pf(expf(r3));
            *(float4*)(dtv + (size_t)m * NH + hh) = v;
        }
    }
}

// ---------------- Kernel 3: causal depthwise conv(4) + SiLU (bf16 in/out) ----------------
__global__ __launch_bounds__(256) void conv_kernel(const short* __restrict__ zx,
                                                   const float* __restrict__ cw,
                                                   const float* __restrict__ cb,
                                                   short* __restrict__ xBC) {
    size_t i = ((size_t)blockIdx.x * 256 + threadIdx.x) * 8;
    int c = (int)(i % CD);
    int t = (int)((i / CD) & (TT - 1));
    int b = (int)(i / ((size_t)CD * TT));
    const short* src = zx + (size_t)b * TT * DIP + DI + c;
    float acc[8];
#pragma unroll
    for (int e = 0; e < 8; e++) acc[e] = cb[c + e];
    float wv[8][4];
#pragma unroll
    for (int e = 0; e < 8; e++) {
        float4 w4 = *(const float4*)(cw + (c + e) * 4);
        wv[e][0] = w4.x; wv[e][1] = w4.y; wv[e][2] = w4.z; wv[e][3] = w4.w;
    }
#pragma unroll
    for (int k = 0; k < 4; k++) {
        int ts = t - 3 + k;
        if (ts >= 0) {
            bf16x8 v = *(const bf16x8*)(src + (size_t)ts * DIP);
#pragma unroll
            for (int e = 0; e < 8; e++)
                acc[e] = fmaf(wv[e][k], b2f(v[e]), acc[e]);
        }
    }
    short o[8];
#pragma unroll
    for (int e = 0; e < 8; e++) {
        float sg = 1.f / (1.f + expf(-acc[e]));
        o[e] = f2bs(acc[e] * sg);
    }
    *(bf16x8*)(xBC + i) = *(bf16x8*)o;
}

// ---------------- Kernel 5a: SSD chunk reduce — MFMA state-only pass (bf16 input) ----------------
__global__ __launch_bounds__(256, 2) void scan_reduce_ssd(const short* __restrict__ xBC,
                                                          const float* __restrict__ dtg,
                                                          const float* __restrict__ A_log,
                                                          float* __restrict__ S,
                                                          float* __restrict__ P) {
    int tid = threadIdx.x;
    int wave = tid >> 6, lane = tid & 63;
    int l4 = lane >> 4, l16 = lane & 15;
    int c = blockIdx.x, hh = blockIdx.y, b = blockIdx.z;
    int cbase = c * CL;

    __shared__ __align__(16) short BtL[64][136];
    __shared__ __align__(16) short XdL[64][72];
    __shared__ __align__(16) float sdt[64];
    __shared__ __align__(16) float sL[64];
    __shared__ __align__(16) float sW[64];

    f32x4 acc_h[2][4];
#pragma unroll
    for (int i = 0; i < 2; i++)
#pragma unroll
        for (int pq = 0; pq < 4; pq++) acc_h[i][pq] = (f32x4){0.f, 0.f, 0.f, 0.f};
    float Lsum = 0.f;

    float expA = expf(A_log[hh]);
    const float* dtb = dtg + (size_t)b * TT * NH + hh;
    const short* xb = xBC + (size_t)b * TT * CD;

#pragma unroll 1
    for (int f = 0; f < FPC; f++) {
        int t0 = cbase + f * FL;
        if (tid < 64) sdt[tid] = dtb[(size_t)(t0 + tid) * NH];
        {
            int r = tid >> 2, q = tid & 3;
            const short* bs = xb + (size_t)(t0 + r) * CD + DI + q * 32;
#pragma unroll
            for (int j = 0; j < 4; j++)
                *(bf16x8*)&BtL[r][q * 32 + j * 8] = *(const bf16x8*)(bs + j * 8);
        }
        __syncthreads();
        if (tid < 64) {
            float v = -expA * sdt[tid];
#pragma unroll
            for (int off = 1; off < 64; off <<= 1) {
                float u = __shfl_up(v, off);
                if (lane >= off) v += u;
            }
            sL[tid] = v;
            float lt = __shfl(v, 63);
            sW[tid] = expf(lt - v);
        }
        __syncthreads();
        {
            int s = tid & 63, pg2 = tid >> 6;
            const short* xs = xb + (size_t)(t0 + s) * CD + hh * HD + pg2 * 16;
            float dts = sdt[s];
            bf16x8 v0 = *(const bf16x8*)xs;
            bf16x8 v1 = *(const bf16x8*)(xs + 8);
#pragma unroll
            for (int j = 0; j < 8; j++) XdL[pg2 * 16 + j][s] = f2bs(b2f(v0[j]) * dts);
#pragma unroll
            for (int j = 0; j < 8; j++) XdL[pg2 * 16 + 8 + j][s] = f2bs(b2f(v1[j]) * dts);
        }
        __syncthreads();
        float Lft = sL[63];
        float Pf = expf(Lft);
        Lsum += Lft;
#pragma unroll
        for (int i = 0; i < 2; i++)
#pragma unroll
            for (int pq = 0; pq < 4; pq++) acc_h[i][pq] *= Pf;
#pragma unroll
        for (int ks = 0; ks < 2; ks++) {
            bf16x8 af2[2], bfw[4];
#pragma unroll
            for (int i = 0; i < 2; i++) {
                int nrow = wave * 32 + i * 16 + l16;
                short e[8];
#pragma unroll
                for (int j = 0; j < 8; j++) {
                    int s = ks * 32 + l4 * 8 + j;
                    e[j] = f2bs(b2f(BtL[s][nrow]) * sW[s]);
                }
                af2[i] = *(bf16x8*)e;
            }
#pragma unroll
            for (int pq = 0; pq < 4; pq++)
                bfw[pq] = *(const bf16x8*)&XdL[pq * 16 + l16][ks * 32 + l4 * 8];
#pragma unroll
            for (int i = 0; i < 2; i++)
#pragma unroll
                for (int pq = 0; pq < 4; pq++)
                    acc_h[i][pq] = __builtin_amdgcn_mfma_f32_16x16x32_bf16(af2[i], bfw[pq], acc_h[i][pq], 0, 0, 0);
        }
        __syncthreads();
    }

    float* Sp = S + (size_t)c * SELEMS + ((size_t)(b * NH + hh) * HD) * DSTATE;
#pragma unroll
    for (int i = 0; i < 2; i++)
#pragma unroll
        for (int pq = 0; pq < 4; pq++) {
            int nb = wave * 32 + i * 16 + (l4 << 2);
            int p = pq * 16 + l16;
            *(f32x4*)(Sp + (size_t)p * DSTATE + nb) = acc_h[i][pq];
        }
    if (tid == 0) P[(c * BB + b) * NH + hh] = expf(Lsum);
}

// ---------------- Kernel 5b: sequential chunk combine ----------------
__global__ __launch_bounds__(256) void scan_combine_kernel(const float* __restrict__ h0,
                                                           const float* __restrict__ P,
                                                           float* __restrict__ S,
                                                           float* __restrict__ hT) {
    size_t tid = (size_t)blockIdx.x * 256 + threadIdx.x;
    int hh = (int)((tid >> 13) & 31);
    int b = (int)(tid >> 18);
    float h = h0[tid];
#pragma unroll
    for (int c = 0; c < NC; c++) {
        float s = S[(size_t)c * SELEMS + tid];
        S[(size_t)c * SELEMS + tid] = h;
        h = fmaf(P[(c * BB + b) * NH + hh], h, s);
    }
    hT[tid] = h;
}

// ---------------- Kernel 5c: SSD emit (bf16 input, f32 y to ybuf) ----------------
__global__ __launch_bounds__(256, 2) void scan_emit_ssd(const short* __restrict__ xBC,
                                                        const float* __restrict__ dtg,
                                                        const float* __restrict__ A_log,
                                                        const float* __restrict__ S,
                                                        const float* __restrict__ Dp,
                                                        float* __restrict__ ybuf) {
    int tid = threadIdx.x;
    int wave = tid >> 6, lane = tid & 63;
    int l4 = lane >> 4, l16 = lane & 15;
    int c = blockIdx.x, hh = blockIdx.y, b = blockIdx.z;
    int cbase = c * CL;

    __shared__ __align__(16) short CtL[64][136];
    __shared__ __align__(16) short BtL[64][136];
    __shared__ __align__(16) short hL[64][132];
    __shared__ __align__(16) short XdL[64][72];
    __shared__ __align__(16) short ML[64][72];
    __shared__ __align__(16) float sdt[64];
    __shared__ __align__(16) float sL[64];
    __shared__ __align__(16) float sW[64];
    __shared__ __align__(16) float sRdt[64];

    f32x4 acc_h[2][4];
    {
        const float* Sp = S + (size_t)c * SELEMS + ((size_t)(b * NH + hh) * HD) * DSTATE;
#pragma unroll
        for (int i = 0; i < 2; i++)
#pragma unroll
            for (int pq = 0; pq < 4; pq++) {
                int nb = wave * 32 + i * 16 + (l4 << 2);
                int p = pq * 16 + l16;
                acc_h[i][pq] = *(const f32x4*)(Sp + (size_t)p * DSTATE + nb);
            }
    }

    float expA = expf(A_log[hh]);
    float Dh = Dp[hh];
    const float* dtb = dtg + (size_t)b * TT * NH + hh;
    const short* xb = xBC + (size_t)b * TT * CD;
    float* yb = ybuf + (size_t)b * TT * DI + hh * HD;

    int tg = wave >> 1;
    int sg = wave & 1;

#pragma unroll 1
    for (int f = 0; f < FPC; f++) {
        int t0 = cbase + f * FL;

        if (tid < 64) sdt[tid] = dtb[(size_t)(t0 + tid) * NH];
        {
            int r = tid >> 2, q = tid & 3;
            const short* cs = xb + (size_t)(t0 + r) * CD + DI + DSTATE + q * 32;
            const short* bs = xb + (size_t)(t0 + r) * CD + DI + q * 32;
#pragma unroll
            for (int j = 0; j < 4; j++) {
                *(bf16x8*)&CtL[r][q * 32 + j * 8] = *(const bf16x8*)(cs + j * 8);
                *(bf16x8*)&BtL[r][q * 32 + j * 8] = *(const bf16x8*)(bs + j * 8);
            }
        }
#pragma unroll
        for (int i = 0; i < 2; i++)
#pragma unroll
            for (int pq = 0; pq < 4; pq++) {
                int nb = wave * 32 + i * 16 + (l4 << 2);
                int p = pq * 16 + l16;
                *(short2*)&hL[p][nb] = make_short2(f2bs(acc_h[i][pq][0]), f2bs(acc_h[i][pq][1]));
                *(short2*)&hL[p][nb + 2] = make_short2(f2bs(acc_h[i][pq][2]), f2bs(acc_h[i][pq][3]));
            }
        __syncthreads();

        if (tid < 64) {
            float v = -expA * sdt[tid];
#pragma unroll
            for (int off = 1; off < 64; off <<= 1) {
                float u = __shfl_up(v, off);
                if (lane >= off) v += u;
            }
            sL[tid] = v;
            float lt = __shfl(v, 63);
            sW[tid] = expf(lt - v);
            sRdt[tid] = 1.f / sdt[tid];
        }
        __syncthreads();

        {
            int s = tid & 63, pg = tid >> 6;
            const short* xs = xb + (size_t)(t0 + s) * CD + hh * HD + pg * 16;
            float dts = sdt[s];
            bf16x8 v0 = *(const bf16x8*)xs;
            bf16x8 v1 = *(const bf16x8*)(xs + 8);
#pragma unroll
            for (int j = 0; j < 8; j++) XdL[pg * 16 + j][s] = f2bs(b2f(v0[j]) * dts);
#pragma unroll
            for (int j = 0; j < 8; j++) XdL[pg * 16 + 8 + j][s] = f2bs(b2f(v1[j]) * dts);
        }
        __syncthreads();

        {
            f32x4 g[2][2] = {};
#pragma unroll
            for (int ks = 0; ks < 4; ks++) {
                bf16x8 af[2], bfm[2];
#pragma unroll
                for (int i = 0; i < 2; i++)
                    af[i] = *(const bf16x8*)&CtL[tg * 32 + i * 16 + l16][ks * 32 + l4 * 8];
#pragma unroll
                for (int n = 0; n < 2; n++)
                    bfm[n] = *(const bf16x8*)&BtL[sg * 32 + n * 16 + l16][ks * 32 + l4 * 8];
#pragma unroll
                for (int i = 0; i < 2; i++)
#pragma unroll
                    for (int n = 0; n < 2; n++)
                        g[i][n] = __builtin_amdgcn_mfma_f32_16x16x32_bf16(af[i], bfm[n], g[i][n], 0, 0, 0);
            }
#pragma unroll
            for (int i = 0; i < 2; i++) {
                int tb2 = tg * 32 + i * 16 + (l4 << 2);
                float4 Lt = *(const float4*)&sL[tb2];
                float Ltr[4] = {Lt.x, Lt.y, Lt.z, Lt.w};
#pragma unroll
                for (int n = 0; n < 2; n++) {
                    int sE = sg * 32 + n * 16 + l16;
                    float Ls = sL[sE];
#pragma unroll
                    for (int r2 = 0; r2 < 4; r2++) {
                        float m = (sE <= tb2 + r2) ? g[i][n][r2] * expf(Ltr[r2] - Ls) : 0.f;
                        ML[tb2 + r2][sE] = f2bs(m);
                    }
                }
            }
        }
        __syncthreads();

        {
            f32x4 ay[2][2] = {};
            f32x4 ai[2][2] = {};
#pragma unroll
            for (int ks = 0; ks < 2; ks++) {
                bf16x8 af[2], bfp[2];
#pragma unroll
                for (int i = 0; i < 2; i++)
                    af[i] = *(const bf16x8*)&ML[tg * 32 + i * 16 + l16][ks * 32 + l4 * 8];
#pragma unroll
                for (int n = 0; n < 2; n++)
                    bfp[n] = *(const bf16x8*)&XdL[sg * 32 + n * 16 + l16][ks * 32 + l4 * 8];
#pragma unroll
                for (int i = 0; i < 2; i++)
#pragma unroll
                    for (int n = 0; n < 2; n++)
                        ay[i][n] = __builtin_amdgcn_mfma_f32_16x16x32_bf16(af[i], bfp[n], ay[i][n], 0, 0, 0);
            }
#pragma unroll
            for (int ks = 0; ks < 4; ks++) {
                bf16x8 af[2], bfh[2];
#pragma unroll
                for (int i = 0; i < 2; i++)
                    af[i] = *(const bf16x8*)&CtL[tg * 32 + i * 16 + l16][ks * 32 + l4 * 8];
#pragma unroll
                for (int n = 0; n < 2; n++) {
                    int prow = sg * 32 + n * 16 + l16;
                    int kb = ks * 32 + l4 * 8;
                    union { bf16x8 v; uint2 u2[2]; } hu;
                    hu.u2[0] = *(const uint2*)&hL[prow][kb];
                    hu.u2[1] = *(const uint2*)&hL[prow][kb + 4];
                    bfh[n] = hu.v;
                }
#pragma unroll
                for (int i = 0; i < 2; i++)
#pragma unroll
                    for (int n = 0; n < 2; n++)
                        ai[i][n] = __builtin_amdgcn_mfma_f32_16x16x32_bf16(af[i], bfh[n], ai[i][n], 0, 0, 0);
            }
            float Lft = sL[63];
#pragma unroll
            for (int i = 0; i < 2; i++) {
                int tb2 = tg * 32 + i * 16 + (l4 << 2);
                float4 Lt = *(const float4*)&sL[tb2];
                float4 Rt = *(const float4*)&sRdt[tb2];
                float Ltr[4] = {Lt.x, Lt.y, Lt.z, Lt.w};
                float Rtr[4] = {Rt.x, Rt.y, Rt.z, Rt.w};
#pragma unroll
                for (int n = 0; n < 2; n++) {
                    int p = sg * 32 + n * 16 + l16;
#pragma unroll
                    for (int r2 = 0; r2 < 4; r2++) {
                        float xv = b2f(XdL[p][tb2 + r2]) * Rtr[r2];
                        float yv = ay[i][n][r2] + expf(Ltr[r2]) * ai[i][n][r2] + Dh * xv;
                        yb[(size_t)(t0 + tb2 + r2) * DI + p] = yv;
                    }
                }
            }
            float Pf = expf(Lft);
#pragma unroll
            for (int i = 0; i < 2; i++)
#pragma unroll
                for (int pq = 0; pq < 4; pq++)
                    acc_h[i][pq] *= Pf;
#pragma unroll
            for (int ks = 0; ks < 2; ks++) {
                bf16x8 af2[2], bfw[4];
#pragma unroll
                for (int i = 0; i < 2; i++) {
                    int nrow = wave * 32 + i * 16 + l16;
                    short e[8];
#pragma unroll
                    for (int j = 0; j < 8; j++) {
                        int s = ks * 32 + l4 * 8 + j;
                        e[j] = f2bs(b2f(BtL[s][nrow]) * sW[s]);
                    }
                    af2[i] = *(bf16x8*)e;
                }
#pragma unroll
                for (int pq = 0; pq < 4; pq++)
                    bfw[pq] = *(const bf16x8*)&XdL[pq * 16 + l16][ks * 32 + l4 * 8];
#pragma unroll
                for (int i = 0; i < 2; i++)
#pragma unroll
                    for (int pq = 0; pq < 4; pq++)
                        acc_h[i][pq] = __builtin_amdgcn_mfma_f32_16x16x32_bf16(af2[i], bfw[pq], acc_h[i][pq], 0, 0, 0);
            }
        }
        __syncthreads();
    }
}

// ---------------- Kernel 6: gating + RMSNorm (f32 y, bf16 z) -> bf16 g ----------------
__global__ __launch_bounds__(256) void gate_rms_kernel(const float* __restrict__ ybuf,
                                                       const short* __restrict__ zx,
                                                       const float* __restrict__ rw,
                                                       __hip_bfloat16* __restrict__ gq) {
    int m = blockIdx.x;
    int tid = threadIdx.x;
    const float* yr = ybuf + (size_t)m * DI;
    const short* zr = zx + (size_t)m * DIP;
    int base = tid * 8;
    float gv[8];
    float ss = 0.f;
    float4 ya = *(const float4*)(yr + base);
    float4 yb4 = *(const float4*)(yr + base + 4);
    bf16x8 zv8 = *(const bf16x8*)(zr + base);
    float yv[8] = {ya.x, ya.y, ya.z, ya.w, yb4.x, yb4.y, yb4.z, yb4.w};
#pragma unroll
    for (int i = 0; i < 8; i++) {
        float z = b2f(zv8[i]);
        float sg = 1.f / (1.f + expf(-z));
        float gg = yv[i] * z * sg;
        gv[i] = gg;
        ss += gg * gg;
    }
#pragma unroll
    for (int off = 1; off < 64; off <<= 1) ss += __shfl_xor(ss, off);
    __shared__ float red[4];
    int w = tid >> 6;
    if ((tid & 63) == 0) red[w] = ss;
    __syncthreads();
    float tot = red[0] + red[1] + red[2] + red[3];
    float r = rsqrtf(tot * (1.f / DI) + 1e-5f);
#pragma unroll
    for (int i = 0; i < 8; i += 2) {
        __hip_bfloat162 p;
        p.x = __float2bfloat16(gv[i] * r * rw[base + i]);
        p.y = __float2bfloat16(gv[i + 1] * r * rw[base + i + 1]);
        *(__hip_bfloat162*)(gq + (size_t)m * DI + base + i) = p;
    }
}

// ---------------- Kernel 7: GEMM2 bf16 MFMA (T2 swizzle + T1 remap m-inner, transposed store) ----------------
__global__ __launch_bounds__(256) void gemm2_mfma(const __hip_bfloat16* __restrict__ gq,
                                                  const __hip_bfloat16* __restrict__ Wob,
                                                  float* __restrict__ out) {
    __shared__ short As[128][64];
    __shared__ short Bs[128][64];
    int tid = threadIdx.x;
    int lane = tid & 63;
    int wave = tid >> 6;
    int wr = wave >> 1, wc = wave & 1;
    int id = blockIdx.x;
    int xcd = id & 7;
    int pos = id >> 3;               // [0, 64)
    int j0 = (pos >> 3) * 128;       // j outer
    int m0 = (xcd * 8 + (pos & 7)) * 128;   // m inner
    int srow = tid >> 3;
    int skc = (((tid & 7) ^ ((tid >> 3) & 7)) * 8);

    f32x4 acc[4][4] = {};

    for (int k0 = 0; k0 < DI; k0 += 64) {
        __syncthreads();
#pragma unroll
        for (int q = 0; q < 4; q++) {
            gload16(gq + (size_t)(m0 + q * 32 + srow) * DI + k0 + skc,
                    ((short*)As) + q * 2048 + wave * 512);
            gload16(Wob + (size_t)(j0 + q * 32 + srow) * DI + k0 + skc,
                    ((short*)Bs) + q * 2048 + wave * 512);
        }
        asm volatile("s_waitcnt vmcnt(0)" ::: "memory");
        __syncthreads();
#pragma unroll
        for (int ks = 0; ks < 2; ks++) {
            int pch = (((ks * 4) + (lane >> 4)) ^ (lane & 7)) * 8;
            bf16x8 af[4], bfr[4];
#pragma unroll
            for (int i = 0; i < 4; i++)
                af[i] = *(const bf16x8*)&As[wr * 64 + i * 16 + (lane & 15)][pch];
#pragma unroll
            for (int n = 0; n < 4; n++)
                bfr[n] = *(const bf16x8*)&Bs[wc * 64 + n * 16 + (lane & 15)][pch];
#pragma unroll
            for (int i = 0; i < 4; i++)
#pragma unroll
                for (int n = 0; n < 4; n++)
                    acc[i][n] = __builtin_amdgcn_mfma_f32_16x16x32_bf16(af[i], bfr[n], acc[i][n], 0, 0, 0);
        }
    }
#pragma unroll
    for (int i = 0; i < 4; i++) {
        int m = m0 + wr * 64 + i * 16 + ((lane >> 4) << 2);
        int b = m >> 12;
        int t = m & 4095;
#pragma unroll
        for (int n = 0; n < 4; n++) {
            int j = j0 + wc * 64 + n * 16 + (lane & 15);
            *(f32x4*)(out + (size_t)b * DM * TT + (size_t)j * TT + t) = acc[i][n];
        }
    }
}

extern "C" void kernel_launch(void* const* d_in, const int* in_sizes, int n_in,
                              void* d_out, int out_size, void* d_ws, size_t ws_size,
                              hipStream_t stream) {
    const float* x       = (const float*)d_in[0];
    const float* ln_w    = (const float*)d_in[1];
    const float* ln_b    = (const float*)d_in[2];
    const float* W_in    = (const float*)d_in[3];
    const float* conv_w  = (const float*)d_in[4];
    const float* conv_b  = (const float*)d_in[5];
    const float* dt_bias = (const float*)d_in[6];
    const float* A_log   = (const float*)d_in[7];
    const float* Dp      = (const float*)d_in[8];
    const float* rms_w   = (const float*)d_in[9];
    const float* W_out   = (const float*)d_in[10];
    const float* h0      = (const float*)d_in[11];

    float* out = (float*)d_out;
    float* hT = out + (size_t)BB * DM * TT;

    char* ws = (char*)d_ws;
    // Workspace layout — total 194,578,432 bytes:
    float* mu   = (float*)(ws + 0);                       //      32,768
    float* rs   = (float*)(ws + 32768);                   //      32,768
    short* zxq  = (short*)(ws + 65536);                   //  71,827,456  (B,T,4384) bf16
    short* xBCq = (short*)(ws + 71892992);                //  37,748,736  (B,T,2304) bf16
    __hip_bfloat16* gq  = (__hip_bfloat16*)(ws + 71892992);        // overlays xBC (post-emit)
    __hip_bfloat16* Wob = (__hip_bfloat16*)(ws + 105447424);       // overlays xBC tail (post-emit)
    float* ybuf = (float*)(ws + 109641728);               //  67,108,864  (B,T,2048) f32
    __hip_bfloat16* Wb  = (__hip_bfloat16*)(ws + 109641728);       // overlays ybuf (pre-scan)
    float* dtv  = (float*)(ws + 176750592);               //   1,048,576
    __hip_bfloat16* xnb = (__hip_bfloat16*)(ws + 177799168);       //  16,777,216 (shares S)
    float* S    = (float*)(ws + 177799168);
    float* P    = (float*)(ws + 194576384);               //       2,048

    ln_stats_kernel<<<dim3(TT / 64, BB), 64, 0, stream>>>(x, mu, rs);
    xn_kernel<<<dim3(TT / 64, DM / 64, BB), 256, 0, stream>>>(x, mu, rs, ln_w, ln_b, xnb);
    cvt_pad_kernel<<<(NP1 * DM) / 1024, 256, 0, stream>>>(W_in, Wb, DIP * DM, NP1 * DM);
    gemm1_mfma<<<(NP1 / 128) * ((BB * TT) / 128), 256, 0, stream>>>(Wb, xnb, zxq);
    gemm1_strip<<<dim3(1, (BB * TT) / 64), 256, 0, stream>>>(x, mu, rs, ln_w, ln_b, W_in, dt_bias, dtv);
    conv_kernel<<<(int)(((size_t)BB * TT * CD) / 2048), 256, 0, stream>>>(zxq, conv_w, conv_b, xBCq);
    scan_reduce_ssd<<<dim3(NC, NH, BB), 256, 0, stream>>>(xBCq, dtv, A_log, S, P);
    scan_combine_kernel<<<(int)(SELEMS / 256), 256, 0, stream>>>(h0, P, S, hT);
    scan_emit_ssd<<<dim3(NC, NH, BB), 256, 0, stream>>>(xBCq, dtv, A_log, S, Dp, ybuf);
    cvt_pad_kernel<<<(DM * DI) / 1024, 256, 0, stream>>>(W_out, Wob, DM * DI, DM * DI);
    gate_rms_kernel<<<BB * TT, 256, 0, stream>>>(ybuf, zxq, rms_w, gq);
    gemm2_mfma<<<((BB * TT) / 128) * (DM / 128), 256, 0, stream>>>(gq, Wob, out);
}

// Round 14
// 405.616 us; speedup vs baseline: 5.4769x; 1.1300x over previous
//
#include <hip/hip_runtime.h>
#include <hip/hip_bf16.h>
#include <math.h>

// Problem constants
#define BB 2
#define TT 4096
#define DM 1024
#define DSTATE 128
#define DI 2048
#define HD 64
#define NH 32
#define DIP 4384   // 2*DI + 2*DSTATE + NH
#define CD 2304    // DI + 2*DSTATE

// Chunked scan parameters
#define NC 8
#define CL 512
#define FL 64            // SSD fine-chunk length
#define FPC (CL / FL)    // 8
#define SELEMS ((size_t)BB * NH * HD * DSTATE)   // 524288

#define NP1 4480   // DIP padded to multiple of 128 for MFMA staging
#define KSPLIT 8   // split-K factor for the dt strip GEMM

typedef __attribute__((ext_vector_type(8))) short bf16x8;
typedef __attribute__((ext_vector_type(4))) float f32x4;

__device__ inline void gload16(const void* g, void* l) {
    __builtin_amdgcn_global_load_lds(
        (const __attribute__((address_space(1))) void*)g,
        (__attribute__((address_space(3))) void*)l, 16, 0, 0);
}

__device__ inline short f2bs(float f) {
    __hip_bfloat16 h = __float2bfloat16(f);
    union { __hip_bfloat16 h; short s; } u;
    u.h = h;
    return u.s;
}
__device__ inline float b2f(short s) {
    union { float f; unsigned u; } u;
    u.u = ((unsigned)(unsigned short)s) << 16;
    return u.f;
}

// ---------------- Kernel 1: LayerNorm statistics ----------------
__global__ __launch_bounds__(64) void ln_stats_kernel(const float* __restrict__ x,
                                                      float* __restrict__ mu,
                                                      float* __restrict__ rs) {
    int t = blockIdx.x * 64 + threadIdx.x;
    int b = blockIdx.y;
    const float* xb = x + (size_t)b * DM * TT + t;
    float s = 0.f, ss = 0.f;
#pragma unroll 8
    for (int d = 0; d < DM; d++) {
        float v = xb[(size_t)d * TT];
        s += v;
        ss += v * v;
    }
    float m = s * (1.f / DM);
    float var = ss * (1.f / DM) - m * m;
    int idx = b * TT + t;
    mu[idx] = m;
    rs[idx] = rsqrtf(var + 1e-5f);
}

// ---------------- Kernel 1b: xn = LN(x) transposed to (m, k) in bf16 ----------------
__global__ __launch_bounds__(256) void xn_kernel(const float* __restrict__ x,
                                                 const float* __restrict__ mu,
                                                 const float* __restrict__ rs,
                                                 const float* __restrict__ ln_w,
                                                 const float* __restrict__ ln_b,
                                                 __hip_bfloat16* __restrict__ xn) {
    __shared__ float tile[64][65];
    int tid = threadIdx.x;
    int t0 = blockIdx.x * 64, d0 = blockIdx.y * 64, b = blockIdx.z;
#pragma unroll
    for (int i = 0; i < 64; i += 4) {
        int dl = i + (tid >> 6);
        tile[dl][tid & 63] = x[(size_t)b * DM * TT + (size_t)(d0 + dl) * TT + t0 + (tid & 63)];
    }
    __syncthreads();
#pragma unroll
    for (int i = 0; i < 64; i += 8) {
        int tl = i + (tid >> 5);
        int kk = (tid & 31) * 2;
        int m = b * TT + t0 + tl;
        float mu_m = mu[m], rs_m = rs[m];
        float v0 = (tile[kk][tl] - mu_m) * rs_m * ln_w[d0 + kk] + ln_b[d0 + kk];
        float v1 = (tile[kk + 1][tl] - mu_m) * rs_m * ln_w[d0 + kk + 1] + ln_b[d0 + kk + 1];
        __hip_bfloat162 pk;
        pk.x = __float2bfloat16(v0);
        pk.y = __float2bfloat16(v1);
        *(__hip_bfloat162*)(xn + (size_t)m * DM + d0 + kk) = pk;
    }
}

// ---------------- convert f32 -> bf16 with zero-padding ----------------
__global__ __launch_bounds__(256) void cvt_pad_kernel(const float* __restrict__ src,
                                                      __hip_bfloat16* __restrict__ dst,
                                                      int src_n, int tot_n) {
    int i = (blockIdx.x * 256 + threadIdx.x) * 4;
    if (i >= tot_n) return;
    float4 v = (i < src_n) ? *(const float4*)(src + i) : make_float4(0.f, 0.f, 0.f, 0.f);
    __hip_bfloat162 p0, p1;
    p0.x = __float2bfloat16(v.x); p0.y = __float2bfloat16(v.y);
    p1.x = __float2bfloat16(v.z); p1.y = __float2bfloat16(v.w);
    *(__hip_bfloat162*)(dst + i) = p0;
    *(__hip_bfloat162*)(dst + i + 2) = p1;
}

// ---------------- Kernel 2: GEMM1 bf16 MFMA (T2 swizzle + T1 remap, m-inner) ----------------
__global__ __launch_bounds__(256) void gemm1_mfma(const __hip_bfloat16* __restrict__ Wb,
                                                  const __hip_bfloat16* __restrict__ xn,
                                                  short* __restrict__ zx) {
    __shared__ short As[128][64];
    __shared__ short Bs[128][64];
    int tid = threadIdx.x;
    int lane = tid & 63;
    int wave = tid >> 6;
    int wr = wave >> 1, wc = wave & 1;
    int id = blockIdx.x;
    int xcd = id & 7;
    int pos = id >> 3;               // [0, 280)
    int j0 = (pos >> 3) * 128;       // j outer: 35 panels
    int m0 = (xcd * 8 + (pos & 7)) * 128;   // m inner: strip resident in L2
    int srow = tid >> 3;
    int skc = (((tid & 7) ^ ((tid >> 3) & 7)) * 8);   // pre-swizzled source k-chunk

    f32x4 acc[4][4] = {};

    for (int k0 = 0; k0 < DM; k0 += 64) {
        __syncthreads();
#pragma unroll
        for (int q = 0; q < 4; q++) {
            gload16(Wb + (size_t)(j0 + q * 32 + srow) * DM + k0 + skc,
                    ((short*)As) + q * 2048 + wave * 512);
            gload16(xn + (size_t)(m0 + q * 32 + srow) * DM + k0 + skc,
                    ((short*)Bs) + q * 2048 + wave * 512);
        }
        asm volatile("s_waitcnt vmcnt(0)" ::: "memory");
        __syncthreads();
#pragma unroll
        for (int ks = 0; ks < 2; ks++) {
            int pch = (((ks * 4) + (lane >> 4)) ^ (lane & 7)) * 8;
            bf16x8 af[4], bfr[4];
#pragma unroll
            for (int i = 0; i < 4; i++)
                af[i] = *(const bf16x8*)&As[wr * 64 + i * 16 + (lane & 15)][pch];
#pragma unroll
            for (int n = 0; n < 4; n++)
                bfr[n] = *(const bf16x8*)&Bs[wc * 64 + n * 16 + (lane & 15)][pch];
#pragma unroll
            for (int i = 0; i < 4; i++)
#pragma unroll
                for (int n = 0; n < 4; n++)
                    acc[i][n] = __builtin_amdgcn_mfma_f32_16x16x32_bf16(af[i], bfr[n], acc[i][n], 0, 0, 0);
        }
    }
#pragma unroll
    for (int i = 0; i < 4; i++) {
        int j = j0 + wr * 64 + i * 16 + ((lane >> 4) << 2);
        if (j < DIP) {
#pragma unroll
            for (int n = 0; n < 4; n++) {
                int m = m0 + wc * 64 + n * 16 + (lane & 15);
                short4 s4;
                s4.x = f2bs(acc[i][n][0]); s4.y = f2bs(acc[i][n][1]);
                s4.z = f2bs(acc[i][n][2]); s4.w = f2bs(acc[i][n][3]);
                *(short4*)(zx + (size_t)m * DIP + j) = s4;
            }
        }
    }
}

// ---------------- Kernel 2b: split-K f32 strip GEMM for dt cols -> partial sums ----------------
// grid (KSPLIT, 128). Block (kq, mtile) computes K-range [kq*128, kq*128+128).
__global__ __launch_bounds__(256) void gemm1_strip(const float* __restrict__ x,
                                                   const float* __restrict__ mu,
                                                   const float* __restrict__ rs,
                                                   const float* __restrict__ ln_w,
                                                   const float* __restrict__ ln_b,
                                                   const float* __restrict__ Win,
                                                   float* __restrict__ partial) {
    __shared__ float As[16][64];
    __shared__ float Ws[64][17];
    int tid = threadIdx.x;
    int tx = tid & 15;
    int ty = tid >> 4;
    int j0 = 4352;
    int kq = blockIdx.x;
    int m0 = blockIdx.y * 64;
    int b = m0 >> 12;
    int t0 = m0 & 4095;
    const float* Xb = x + (size_t)b * DM * TT + t0;

    int lr = tid >> 4;
    int lc = (tid & 15) * 4;
    int wr = tid >> 2;
    int wc = (tid & 3) * 4;

    float acc[4][4] = {};
    int kbeg = kq * (DM / KSPLIT);
    for (int k0 = kbeg; k0 < kbeg + DM / KSPLIT; k0 += 16) {
        float4 xv = *(const float4*)(Xb + (size_t)(k0 + lr) * TT + lc);
        float4 muv = *(const float4*)(&mu[m0 + lc]);
        float4 rsv = *(const float4*)(&rs[m0 + lc]);
        float lw = ln_w[k0 + lr], lb = ln_b[k0 + lr];
        As[lr][lc]     = (xv.x - muv.x) * rsv.x * lw + lb;
        As[lr][lc + 1] = (xv.y - muv.y) * rsv.y * lw + lb;
        As[lr][lc + 2] = (xv.z - muv.z) * rsv.z * lw + lb;
        As[lr][lc + 3] = (xv.w - muv.w) * rsv.w * lw + lb;

        int j = j0 + wr;
        float4 wv = make_float4(0.f, 0.f, 0.f, 0.f);
        if (j < DIP) wv = *(const float4*)(Win + (size_t)j * DM + k0 + wc);
        Ws[wr][wc] = wv.x; Ws[wr][wc + 1] = wv.y; Ws[wr][wc + 2] = wv.z; Ws[wr][wc + 3] = wv.w;
        __syncthreads();
#pragma unroll
        for (int kk = 0; kk < 16; kk++) {
            float4 a4 = *(const float4*)&As[kk][ty * 4];
            float a[4] = {a4.x, a4.y, a4.z, a4.w};
            float bv[4];
#pragma unroll
            for (int n = 0; n < 4; n++) bv[n] = Ws[tx * 4 + n][kk];
#pragma unroll
            for (int i = 0; i < 4; i++)
#pragma unroll
                for (int n = 0; n < 4; n++)
                    acc[i][n] = fmaf(a[i], bv[n], acc[i][n]);
        }
        __syncthreads();
    }
#pragma unroll
    for (int i = 0; i < 4; i++) {
        int m = m0 + ty * 4 + i;
        int hh = tx * 4;           // j - 4352, tx in [0,8) used
        if (hh < NH) {
            float4 v = make_float4(acc[i][0], acc[i][1], acc[i][2], acc[i][3]);
            *(float4*)(partial + ((size_t)kq * BB * TT + m) * NH + hh) = v;
        }
    }
}

// ---------------- Kernel 2c: reduce split-K partials + bias + softplus -> dtv ----------------
__global__ __launch_bounds__(256) void dt_reduce_kernel(const float* __restrict__ partial,
                                                        const float* __restrict__ dt_bias,
                                                        float* __restrict__ dtv) {
    int i = blockIdx.x * 256 + threadIdx.x;   // over BB*TT*NH = 262144
    int hh = i & (NH - 1);
    float s = 0.f;
#pragma unroll
    for (int kq = 0; kq < KSPLIT; kq++)
        s += partial[(size_t)kq * BB * TT * NH + i];
    float raw = s + dt_bias[hh];
    dtv[i] = (raw > 20.f) ? raw : log1pf(expf(raw));
}

// ---------------- Kernel 3: causal depthwise conv(4) + SiLU (bf16 in/out) ----------------
__global__ __launch_bounds__(256) void conv_kernel(const short* __restrict__ zx,
                                                   const float* __restrict__ cw,
                                                   const float* __restrict__ cb,
                                                   short* __restrict__ xBC) {
    size_t i = ((size_t)blockIdx.x * 256 + threadIdx.x) * 8;
    int c = (int)(i % CD);
    int t = (int)((i / CD) & (TT - 1));
    int b = (int)(i / ((size_t)CD * TT));
    const short* src = zx + (size_t)b * TT * DIP + DI + c;
    float acc[8];
#pragma unroll
    for (int e = 0; e < 8; e++) acc[e] = cb[c + e];
    float wv[8][4];
#pragma unroll
    for (int e = 0; e < 8; e++) {
        float4 w4 = *(const float4*)(cw + (c + e) * 4);
        wv[e][0] = w4.x; wv[e][1] = w4.y; wv[e][2] = w4.z; wv[e][3] = w4.w;
    }
#pragma unroll
    for (int k = 0; k < 4; k++) {
        int ts = t - 3 + k;
        if (ts >= 0) {
            bf16x8 v = *(const bf16x8*)(src + (size_t)ts * DIP);
#pragma unroll
            for (int e = 0; e < 8; e++)
                acc[e] = fmaf(wv[e][k], b2f(v[e]), acc[e]);
        }
    }
    short o[8];
#pragma unroll
    for (int e = 0; e < 8; e++) {
        float sg = 1.f / (1.f + expf(-acc[e]));
        o[e] = f2bs(acc[e] * sg);
    }
    *(bf16x8*)(xBC + i) = *(bf16x8*)o;
}

// ---------------- Kernel 5a: SSD chunk reduce — MFMA state-only pass (bf16 input) ----------------
__global__ __launch_bounds__(256, 2) void scan_reduce_ssd(const short* __restrict__ xBC,
                                                          const float* __restrict__ dtg,
                                                          const float* __restrict__ A_log,
                                                          float* __restrict__ S,
                                                          float* __restrict__ P) {
    int tid = threadIdx.x;
    int wave = tid >> 6, lane = tid & 63;
    int l4 = lane >> 4, l16 = lane & 15;
    int c = blockIdx.x, hh = blockIdx.y, b = blockIdx.z;
    int cbase = c * CL;

    __shared__ __align__(16) short BtL[64][136];
    __shared__ __align__(16) short XdL[64][72];
    __shared__ __align__(16) float sdt[64];
    __shared__ __align__(16) float sL[64];
    __shared__ __align__(16) float sW[64];

    f32x4 acc_h[2][4];
#pragma unroll
    for (int i = 0; i < 2; i++)
#pragma unroll
        for (int pq = 0; pq < 4; pq++) acc_h[i][pq] = (f32x4){0.f, 0.f, 0.f, 0.f};
    float Lsum = 0.f;

    float expA = expf(A_log[hh]);
    const float* dtb = dtg + (size_t)b * TT * NH + hh;
    const short* xb = xBC + (size_t)b * TT * CD;

#pragma unroll 1
    for (int f = 0; f < FPC; f++) {
        int t0 = cbase + f * FL;
        if (tid < 64) sdt[tid] = dtb[(size_t)(t0 + tid) * NH];
        {
            int r = tid >> 2, q = tid & 3;
            const short* bs = xb + (size_t)(t0 + r) * CD + DI + q * 32;
#pragma unroll
            for (int j = 0; j < 4; j++)
                *(bf16x8*)&BtL[r][q * 32 + j * 8] = *(const bf16x8*)(bs + j * 8);
        }
        __syncthreads();
        if (tid < 64) {
            float v = -expA * sdt[tid];
#pragma unroll
            for (int off = 1; off < 64; off <<= 1) {
                float u = __shfl_up(v, off);
                if (lane >= off) v += u;
            }
            sL[tid] = v;
            float lt = __shfl(v, 63);
            sW[tid] = expf(lt - v);
        }
        __syncthreads();
        {
            int s = tid & 63, pg2 = tid >> 6;
            const short* xs = xb + (size_t)(t0 + s) * CD + hh * HD + pg2 * 16;
            float dts = sdt[s];
            bf16x8 v0 = *(const bf16x8*)xs;
            bf16x8 v1 = *(const bf16x8*)(xs + 8);
#pragma unroll
            for (int j = 0; j < 8; j++) XdL[pg2 * 16 + j][s] = f2bs(b2f(v0[j]) * dts);
#pragma unroll
            for (int j = 0; j < 8; j++) XdL[pg2 * 16 + 8 + j][s] = f2bs(b2f(v1[j]) * dts);
        }
        __syncthreads();
        float Lft = sL[63];
        float Pf = expf(Lft);
        Lsum += Lft;
#pragma unroll
        for (int i = 0; i < 2; i++)
#pragma unroll
            for (int pq = 0; pq < 4; pq++) acc_h[i][pq] *= Pf;
#pragma unroll
        for (int ks = 0; ks < 2; ks++) {
            bf16x8 af2[2], bfw[4];
#pragma unroll
            for (int i = 0; i < 2; i++) {
                int nrow = wave * 32 + i * 16 + l16;
                short e[8];
#pragma unroll
                for (int j = 0; j < 8; j++) {
                    int s = ks * 32 + l4 * 8 + j;
                    e[j] = f2bs(b2f(BtL[s][nrow]) * sW[s]);
                }
                af2[i] = *(bf16x8*)e;
            }
#pragma unroll
            for (int pq = 0; pq < 4; pq++)
                bfw[pq] = *(const bf16x8*)&XdL[pq * 16 + l16][ks * 32 + l4 * 8];
#pragma unroll
            for (int i = 0; i < 2; i++)
#pragma unroll
                for (int pq = 0; pq < 4; pq++)
                    acc_h[i][pq] = __builtin_amdgcn_mfma_f32_16x16x32_bf16(af2[i], bfw[pq], acc_h[i][pq], 0, 0, 0);
        }
        __syncthreads();
    }

    float* Sp = S + (size_t)c * SELEMS + ((size_t)(b * NH + hh) * HD) * DSTATE;
#pragma unroll
    for (int i = 0; i < 2; i++)
#pragma unroll
        for (int pq = 0; pq < 4; pq++) {
            int nb = wave * 32 + i * 16 + (l4 << 2);
            int p = pq * 16 + l16;
            *(f32x4*)(Sp + (size_t)p * DSTATE + nb) = acc_h[i][pq];
        }
    if (tid == 0) P[(c * BB + b) * NH + hh] = expf(Lsum);
}

// ---------------- Kernel 5b: sequential chunk combine ----------------
__global__ __launch_bounds__(256) void scan_combine_kernel(const float* __restrict__ h0,
                                                           const float* __restrict__ P,
                                                           float* __restrict__ S,
                                                           float* __restrict__ hT) {
    size_t tid = (size_t)blockIdx.x * 256 + threadIdx.x;
    int hh = (int)((tid >> 13) & 31);
    int b = (int)(tid >> 18);
    float h = h0[tid];
#pragma unroll
    for (int c = 0; c < NC; c++) {
        float s = S[(size_t)c * SELEMS + tid];
        S[(size_t)c * SELEMS + tid] = h;
        h = fmaf(P[(c * BB + b) * NH + hh], h, s);
    }
    hT[tid] = h;
}

// ---------------- Kernel 5c: SSD emit (bf16 input, f32 y to ybuf) ----------------
__global__ __launch_bounds__(256, 2) void scan_emit_ssd(const short* __restrict__ xBC,
                                                        const float* __restrict__ dtg,
                                                        const float* __restrict__ A_log,
                                                        const float* __restrict__ S,
                                                        const float* __restrict__ Dp,
                                                        float* __restrict__ ybuf) {
    int tid = threadIdx.x;
    int wave = tid >> 6, lane = tid & 63;
    int l4 = lane >> 4, l16 = lane & 15;
    int c = blockIdx.x, hh = blockIdx.y, b = blockIdx.z;
    int cbase = c * CL;

    __shared__ __align__(16) short CtL[64][136];
    __shared__ __align__(16) short BtL[64][136];
    __shared__ __align__(16) short hL[64][132];
    __shared__ __align__(16) short XdL[64][72];
    __shared__ __align__(16) short ML[64][72];
    __shared__ __align__(16) float sdt[64];
    __shared__ __align__(16) float sL[64];
    __shared__ __align__(16) float sW[64];
    __shared__ __align__(16) float sRdt[64];

    f32x4 acc_h[2][4];
    {
        const float* Sp = S + (size_t)c * SELEMS + ((size_t)(b * NH + hh) * HD) * DSTATE;
#pragma unroll
        for (int i = 0; i < 2; i++)
#pragma unroll
            for (int pq = 0; pq < 4; pq++) {
                int nb = wave * 32 + i * 16 + (l4 << 2);
                int p = pq * 16 + l16;
                acc_h[i][pq] = *(const f32x4*)(Sp + (size_t)p * DSTATE + nb);
            }
    }

    float expA = expf(A_log[hh]);
    float Dh = Dp[hh];
    const float* dtb = dtg + (size_t)b * TT * NH + hh;
    const short* xb = xBC + (size_t)b * TT * CD;
    float* yb = ybuf + (size_t)b * TT * DI + hh * HD;

    int tg = wave >> 1;
    int sg = wave & 1;

#pragma unroll 1
    for (int f = 0; f < FPC; f++) {
        int t0 = cbase + f * FL;

        if (tid < 64) sdt[tid] = dtb[(size_t)(t0 + tid) * NH];
        {
            int r = tid >> 2, q = tid & 3;
            const short* cs = xb + (size_t)(t0 + r) * CD + DI + DSTATE + q * 32;
            const short* bs = xb + (size_t)(t0 + r) * CD + DI + q * 32;
#pragma unroll
            for (int j = 0; j < 4; j++) {
                *(bf16x8*)&CtL[r][q * 32 + j * 8] = *(const bf16x8*)(cs + j * 8);
                *(bf16x8*)&BtL[r][q * 32 + j * 8] = *(const bf16x8*)(bs + j * 8);
            }
        }
#pragma unroll
        for (int i = 0; i < 2; i++)
#pragma unroll
            for (int pq = 0; pq < 4; pq++) {
                int nb = wave * 32 + i * 16 + (l4 << 2);
                int p = pq * 16 + l16;
                *(short2*)&hL[p][nb] = make_short2(f2bs(acc_h[i][pq][0]), f2bs(acc_h[i][pq][1]));
                *(short2*)&hL[p][nb + 2] = make_short2(f2bs(acc_h[i][pq][2]), f2bs(acc_h[i][pq][3]));
            }
        __syncthreads();

        if (tid < 64) {
            float v = -expA * sdt[tid];
#pragma unroll
            for (int off = 1; off < 64; off <<= 1) {
                float u = __shfl_up(v, off);
                if (lane >= off) v += u;
            }
            sL[tid] = v;
            float lt = __shfl(v, 63);
            sW[tid] = expf(lt - v);
            sRdt[tid] = 1.f / sdt[tid];
        }
        __syncthreads();

        {
            int s = tid & 63, pg = tid >> 6;
            const short* xs = xb + (size_t)(t0 + s) * CD + hh * HD + pg * 16;
            float dts = sdt[s];
            bf16x8 v0 = *(const bf16x8*)xs;
            bf16x8 v1 = *(const bf16x8*)(xs + 8);
#pragma unroll
            for (int j = 0; j < 8; j++) XdL[pg * 16 + j][s] = f2bs(b2f(v0[j]) * dts);
#pragma unroll
            for (int j = 0; j < 8; j++) XdL[pg * 16 + 8 + j][s] = f2bs(b2f(v1[j]) * dts);
        }
        __syncthreads();

        {
            f32x4 g[2][2] = {};
#pragma unroll
            for (int ks = 0; ks < 4; ks++) {
                bf16x8 af[2], bfm[2];
#pragma unroll
                for (int i = 0; i < 2; i++)
                    af[i] = *(const bf16x8*)&CtL[tg * 32 + i * 16 + l16][ks * 32 + l4 * 8];
#pragma unroll
                for (int n = 0; n < 2; n++)
                    bfm[n] = *(const bf16x8*)&BtL[sg * 32 + n * 16 + l16][ks * 32 + l4 * 8];
#pragma unroll
                for (int i = 0; i < 2; i++)
#pragma unroll
                    for (int n = 0; n < 2; n++)
                        g[i][n] = __builtin_amdgcn_mfma_f32_16x16x32_bf16(af[i], bfm[n], g[i][n], 0, 0, 0);
            }
#pragma unroll
            for (int i = 0; i < 2; i++) {
                int tb2 = tg * 32 + i * 16 + (l4 << 2);
                float4 Lt = *(const float4*)&sL[tb2];
                float Ltr[4] = {Lt.x, Lt.y, Lt.z, Lt.w};
#pragma unroll
                for (int n = 0; n < 2; n++) {
                    int sE = sg * 32 + n * 16 + l16;
                    float Ls = sL[sE];
#pragma unroll
                    for (int r2 = 0; r2 < 4; r2++) {
                        float m = (sE <= tb2 + r2) ? g[i][n][r2] * expf(Ltr[r2] - Ls) : 0.f;
                        ML[tb2 + r2][sE] = f2bs(m);
                    }
                }
            }
        }
        __syncthreads();

        {
            f32x4 ay[2][2] = {};
            f32x4 ai[2][2] = {};
#pragma unroll
            for (int ks = 0; ks < 2; ks++) {
                bf16x8 af[2], bfp[2];
#pragma unroll
                for (int i = 0; i < 2; i++)
                    af[i] = *(const bf16x8*)&ML[tg * 32 + i * 16 + l16][ks * 32 + l4 * 8];
#pragma unroll
                for (int n = 0; n < 2; n++)
                    bfp[n] = *(const bf16x8*)&XdL[sg * 32 + n * 16 + l16][ks * 32 + l4 * 8];
#pragma unroll
                for (int i = 0; i < 2; i++)
#pragma unroll
                    for (int n = 0; n < 2; n++)
                        ay[i][n] = __builtin_amdgcn_mfma_f32_16x16x32_bf16(af[i], bfp[n], ay[i][n], 0, 0, 0);
            }
#pragma unroll
            for (int ks = 0; ks < 4; ks++) {
                bf16x8 af[2], bfh[2];
#pragma unroll
                for (int i = 0; i < 2; i++)
                    af[i] = *(const bf16x8*)&CtL[tg * 32 + i * 16 + l16][ks * 32 + l4 * 8];
#pragma unroll
                for (int n = 0; n < 2; n++) {
                    int prow = sg * 32 + n * 16 + l16;
                    int kb = ks * 32 + l4 * 8;
                    union { bf16x8 v; uint2 u2[2]; } hu;
                    hu.u2[0] = *(const uint2*)&hL[prow][kb];
                    hu.u2[1] = *(const uint2*)&hL[prow][kb + 4];
                    bfh[n] = hu.v;
                }
#pragma unroll
                for (int i = 0; i < 2; i++)
#pragma unroll
                    for (int n = 0; n < 2; n++)
                        ai[i][n] = __builtin_amdgcn_mfma_f32_16x16x32_bf16(af[i], bfh[n], ai[i][n], 0, 0, 0);
            }
            float Lft = sL[63];
#pragma unroll
            for (int i = 0; i < 2; i++) {
                int tb2 = tg * 32 + i * 16 + (l4 << 2);
                float4 Lt = *(const float4*)&sL[tb2];
                float4 Rt = *(const float4*)&sRdt[tb2];
                float Ltr[4] = {Lt.x, Lt.y, Lt.z, Lt.w};
                float Rtr[4] = {Rt.x, Rt.y, Rt.z, Rt.w};
#pragma unroll
                for (int n = 0; n < 2; n++) {
                    int p = sg * 32 + n * 16 + l16;
#pragma unroll
                    for (int r2 = 0; r2 < 4; r2++) {
                        float xv = b2f(XdL[p][tb2 + r2]) * Rtr[r2];
                        float yv = ay[i][n][r2] + expf(Ltr[r2]) * ai[i][n][r2] + Dh * xv;
                        yb[(size_t)(t0 + tb2 + r2) * DI + p] = yv;
                    }
                }
            }
            float Pf = expf(Lft);
#pragma unroll
            for (int i = 0; i < 2; i++)
#pragma unroll
                for (int pq = 0; pq < 4; pq++)
                    acc_h[i][pq] *= Pf;
#pragma unroll
            for (int ks = 0; ks < 2; ks++) {
                bf16x8 af2[2], bfw[4];
#pragma unroll
                for (int i = 0; i < 2; i++) {
                    int nrow = wave * 32 + i * 16 + l16;
                    short e[8];
#pragma unroll
                    for (int j = 0; j < 8; j++) {
                        int s = ks * 32 + l4 * 8 + j;
                        e[j] = f2bs(b2f(BtL[s][nrow]) * sW[s]);
                    }
                    af2[i] = *(bf16x8*)e;
                }
#pragma unroll
                for (int pq = 0; pq < 4; pq++)
                    bfw[pq] = *(const bf16x8*)&XdL[pq * 16 + l16][ks * 32 + l4 * 8];
#pragma unroll
                for (int i = 0; i < 2; i++)
#pragma unroll
                    for (int pq = 0; pq < 4; pq++)
                        acc_h[i][pq] = __builtin_amdgcn_mfma_f32_16x16x32_bf16(af2[i], bfw[pq], acc_h[i][pq], 0, 0, 0);
            }
        }
        __syncthreads();
    }
}

// ---------------- Kernel 6: gating + RMSNorm (f32 y, bf16 z) -> bf16 g ----------------
__global__ __launch_bounds__(256) void gate_rms_kernel(const float* __restrict__ ybuf,
                                                       const short* __restrict__ zx,
                                                       const float* __restrict__ rw,
                                                       __hip_bfloat16* __restrict__ gq) {
    int m = blockIdx.x;
    int tid = threadIdx.x;
    const float* yr = ybuf + (size_t)m * DI;
    const short* zr = zx + (size_t)m * DIP;
    int base = tid * 8;
    float gv[8];
    float ss = 0.f;
    float4 ya = *(const float4*)(yr + base);
    float4 yb4 = *(const float4*)(yr + base + 4);
    bf16x8 zv8 = *(const bf16x8*)(zr + base);
    float yv[8] = {ya.x, ya.y, ya.z, ya.w, yb4.x, yb4.y, yb4.z, yb4.w};
#pragma unroll
    for (int i = 0; i < 8; i++) {
        float z = b2f(zv8[i]);
        float sg = 1.f / (1.f + expf(-z));
        float gg = yv[i] * z * sg;
        gv[i] = gg;
        ss += gg * gg;
    }
#pragma unroll
    for (int off = 1; off < 64; off <<= 1) ss += __shfl_xor(ss, off);
    __shared__ float red[4];
    int w = tid >> 6;
    if ((tid & 63) == 0) red[w] = ss;
    __syncthreads();
    float tot = red[0] + red[1] + red[2] + red[3];
    float r = rsqrtf(tot * (1.f / DI) + 1e-5f);
#pragma unroll
    for (int i = 0; i < 8; i += 2) {
        __hip_bfloat162 p;
        p.x = __float2bfloat16(gv[i] * r * rw[base + i]);
        p.y = __float2bfloat16(gv[i + 1] * r * rw[base + i + 1]);
        *(__hip_bfloat162*)(gq + (size_t)m * DI + base + i) = p;
    }
}

// ---------------- Kernel 7: GEMM2 bf16 MFMA (T2 swizzle + T1 remap m-inner, transposed store) ----------------
__global__ __launch_bounds__(256) void gemm2_mfma(const __hip_bfloat16* __restrict__ gq,
                                                  const __hip_bfloat16* __restrict__ Wob,
                                                  float* __restrict__ out) {
    __shared__ short As[128][64];
    __shared__ short Bs[128][64];
    int tid = threadIdx.x;
    int lane = tid & 63;
    int wave = tid >> 6;
    int wr = wave >> 1, wc = wave & 1;
    int id = blockIdx.x;
    int xcd = id & 7;
    int pos = id >> 3;               // [0, 64)
    int j0 = (pos >> 3) * 128;       // j outer
    int m0 = (xcd * 8 + (pos & 7)) * 128;   // m inner
    int srow = tid >> 3;
    int skc = (((tid & 7) ^ ((tid >> 3) & 7)) * 8);

    f32x4 acc[4][4] = {};

    for (int k0 = 0; k0 < DI; k0 += 64) {
        __syncthreads();
#pragma unroll
        for (int q = 0; q < 4; q++) {
            gload16(gq + (size_t)(m0 + q * 32 + srow) * DI + k0 + skc,
                    ((short*)As) + q * 2048 + wave * 512);
            gload16(Wob + (size_t)(j0 + q * 32 + srow) * DI + k0 + skc,
                    ((short*)Bs) + q * 2048 + wave * 512);
        }
        asm volatile("s_waitcnt vmcnt(0)" ::: "memory");
        __syncthreads();
#pragma unroll
        for (int ks = 0; ks < 2; ks++) {
            int pch = (((ks * 4) + (lane >> 4)) ^ (lane & 7)) * 8;
            bf16x8 af[4], bfr[4];
#pragma unroll
            for (int i = 0; i < 4; i++)
                af[i] = *(const bf16x8*)&As[wr * 64 + i * 16 + (lane & 15)][pch];
#pragma unroll
            for (int n = 0; n < 4; n++)
                bfr[n] = *(const bf16x8*)&Bs[wc * 64 + n * 16 + (lane & 15)][pch];
#pragma unroll
            for (int i = 0; i < 4; i++)
#pragma unroll
                for (int n = 0; n < 4; n++)
                    acc[i][n] = __builtin_amdgcn_mfma_f32_16x16x32_bf16(af[i], bfr[n], acc[i][n], 0, 0, 0);
        }
    }
#pragma unroll
    for (int i = 0; i < 4; i++) {
        int m = m0 + wr * 64 + i * 16 + ((lane >> 4) << 2);
        int b = m >> 12;
        int t = m & 4095;
#pragma unroll
        for (int n = 0; n < 4; n++) {
            int j = j0 + wc * 64 + n * 16 + (lane & 15);
            *(f32x4*)(out + (size_t)b * DM * TT + (size_t)j * TT + t) = acc[i][n];
        }
    }
}

extern "C" void kernel_launch(void* const* d_in, const int* in_sizes, int n_in,
                              void* d_out, int out_size, void* d_ws, size_t ws_size,
                              hipStream_t stream) {
    const float* x       = (const float*)d_in[0];
    const float* ln_w    = (const float*)d_in[1];
    const float* ln_b    = (const float*)d_in[2];
    const float* W_in    = (const float*)d_in[3];
    const float* conv_w  = (const float*)d_in[4];
    const float* conv_b  = (const float*)d_in[5];
    const float* dt_bias = (const float*)d_in[6];
    const float* A_log   = (const float*)d_in[7];
    const float* Dp      = (const float*)d_in[8];
    const float* rms_w   = (const float*)d_in[9];
    const float* W_out   = (const float*)d_in[10];
    const float* h0      = (const float*)d_in[11];

    float* out = (float*)d_out;
    float* hT = out + (size_t)BB * DM * TT;

    char* ws = (char*)d_ws;
    // Workspace layout — total 202,967,040 bytes (under proven 238 MB):
    float* mu   = (float*)(ws + 0);                       //      32,768
    float* rs   = (float*)(ws + 32768);                   //      32,768
    short* zxq  = (short*)(ws + 65536);                   //  71,827,456  (B,T,4384) bf16
    short* xBCq = (short*)(ws + 71892992);                //  37,748,736  (B,T,2304) bf16
    __hip_bfloat16* gq  = (__hip_bfloat16*)(ws + 71892992);        // overlays xBC (post-emit)
    __hip_bfloat16* Wob = (__hip_bfloat16*)(ws + 105447424);       // overlays xBC tail (post-emit)
    float* ybuf = (float*)(ws + 109641728);               //  67,108,864  (B,T,2048) f32
    __hip_bfloat16* Wb  = (__hip_bfloat16*)(ws + 109641728);       // overlays ybuf (pre-scan)
    float* dtv  = (float*)(ws + 176750592);               //   1,048,576
    __hip_bfloat16* xnb = (__hip_bfloat16*)(ws + 177799168);       //  16,777,216 (shares S)
    float* S    = (float*)(ws + 177799168);
    float* P    = (float*)(ws + 194576384);               //       2,048
    float* dpart = (float*)(ws + 194578432);              //   8,388,608  (KSPLIT,B*T,NH)

    ln_stats_kernel<<<dim3(TT / 64, BB), 64, 0, stream>>>(x, mu, rs);
    xn_kernel<<<dim3(TT / 64, DM / 64, BB), 256, 0, stream>>>(x, mu, rs, ln_w, ln_b, xnb);
    cvt_pad_kernel<<<(NP1 * DM) / 1024, 256, 0, stream>>>(W_in, Wb, DIP * DM, NP1 * DM);
    gemm1_mfma<<<(NP1 / 128) * ((BB * TT) / 128), 256, 0, stream>>>(Wb, xnb, zxq);
    gemm1_strip<<<dim3(KSPLIT, (BB * TT) / 64), 256, 0, stream>>>(x, mu, rs, ln_w, ln_b, W_in, dpart);
    dt_reduce_kernel<<<(BB * TT * NH) / 256, 256, 0, stream>>>(dpart, dt_bias, dtv);
    conv_kernel<<<(int)(((size_t)BB * TT * CD) / 2048), 256, 0, stream>>>(zxq, conv_w, conv_b, xBCq);
    scan_reduce_ssd<<<dim3(NC, NH, BB), 256, 0, stream>>>(xBCq, dtv, A_log, S, P);
    scan_combine_kernel<<<(int)(SELEMS / 256), 256, 0, stream>>>(h0, P, S, hT);
    scan_emit_ssd<<<dim3(NC, NH, BB), 256, 0, stream>>>(xBCq, dtv, A_log, S, Dp, ybuf);
    cvt_pad_kernel<<<(DM * DI) / 1024, 256, 0, stream>>>(W_out, Wob, DM * DI, DM * DI);
    gate_rms_kernel<<<BB * TT, 256, 0, stream>>>(ybuf, zxq, rms_w, gq);
    gemm2_mfma<<<((BB * TT) / 128) * (DM / 128), 256, 0, stream>>>(gq, Wob, out);
}

// Round 15
// 366.446 us; speedup vs baseline: 6.0623x; 1.1069x over previous
//
#include <hip/hip_runtime.h>
#include <hip/hip_bf16.h>
#include <math.h>

// Problem constants
#define BB 2
#define TT 4096
#define DM 1024
#define DSTATE 128
#define DI 2048
#define HD 64
#define NH 32
#define DIP 4384   // 2*DI + 2*DSTATE + NH
#define CD 2304    // DI + 2*DSTATE

// Chunked scan parameters
#define NC 8
#define CL 512
#define FL 64            // SSD fine-chunk length
#define FPC (CL / FL)    // 8
#define SELEMS ((size_t)BB * NH * HD * DSTATE)   // 524288

#define NP1 4480   // DIP padded to multiple of 128 for MFMA staging
#define KSPLIT 16  // split-K factor for the dt strip GEMM

typedef __attribute__((ext_vector_type(8))) short bf16x8;
typedef __attribute__((ext_vector_type(4))) float f32x4;

__device__ inline void gload16(const void* g, void* l) {
    __builtin_amdgcn_global_load_lds(
        (const __attribute__((address_space(1))) void*)g,
        (__attribute__((address_space(3))) void*)l, 16, 0, 0);
}

__device__ inline short f2bs(float f) {
    __hip_bfloat16 h = __float2bfloat16(f);
    union { __hip_bfloat16 h; short s; } u;
    u.h = h;
    return u.s;
}
__device__ inline float b2f(short s) {
    union { float f; unsigned u; } u;
    u.u = ((unsigned)(unsigned short)s) << 16;
    return u.f;
}

// ---------------- Kernel 1: LayerNorm statistics (split-D, 256 blocks) ----------------
// Block = 32 tokens x 8 d-slices (128 d each), 256 threads. LDS combine.
__global__ __launch_bounds__(256) void ln_stats_kernel(const float* __restrict__ x,
                                                       float* __restrict__ mu,
                                                       float* __restrict__ rs) {
    __shared__ float sred[2][8][32];
    int tid = threadIdx.x;
    int tl = tid & 31;
    int ds = tid >> 5;               // 0..7
    int t = (blockIdx.x & 127) * 32 + tl;
    int b = blockIdx.x >> 7;
    const float* xb = x + (size_t)b * DM * TT + (size_t)ds * 128 * TT + t;
    float s = 0.f, ss = 0.f;
#pragma unroll 8
    for (int d = 0; d < 128; d++) {
        float v = xb[(size_t)d * TT];
        s += v;
        ss += v * v;
    }
    sred[0][ds][tl] = s;
    sred[1][ds][tl] = ss;
    __syncthreads();
    if (tid < 32) {
        float st = 0.f, sst = 0.f;
#pragma unroll
        for (int q = 0; q < 8; q++) { st += sred[0][q][tid]; sst += sred[1][q][tid]; }
        float m = st * (1.f / DM);
        float var = sst * (1.f / DM) - m * m;
        int idx = b * TT + (blockIdx.x & 127) * 32 + tid;
        mu[idx] = m;
        rs[idx] = rsqrtf(var + 1e-5f);
    }
}

// ---------------- Kernel 1b: xn = LN(x) transposed to (m, k) in bf16 ----------------
__global__ __launch_bounds__(256) void xn_kernel(const float* __restrict__ x,
                                                 const float* __restrict__ mu,
                                                 const float* __restrict__ rs,
                                                 const float* __restrict__ ln_w,
                                                 const float* __restrict__ ln_b,
                                                 __hip_bfloat16* __restrict__ xn) {
    __shared__ float tile[64][65];
    int tid = threadIdx.x;
    int t0 = blockIdx.x * 64, d0 = blockIdx.y * 64, b = blockIdx.z;
#pragma unroll
    for (int i = 0; i < 64; i += 4) {
        int dl = i + (tid >> 6);
        tile[dl][tid & 63] = x[(size_t)b * DM * TT + (size_t)(d0 + dl) * TT + t0 + (tid & 63)];
    }
    __syncthreads();
#pragma unroll
    for (int i = 0; i < 64; i += 8) {
        int tl = i + (tid >> 5);
        int kk = (tid & 31) * 2;
        int m = b * TT + t0 + tl;
        float mu_m = mu[m], rs_m = rs[m];
        float v0 = (tile[kk][tl] - mu_m) * rs_m * ln_w[d0 + kk] + ln_b[d0 + kk];
        float v1 = (tile[kk + 1][tl] - mu_m) * rs_m * ln_w[d0 + kk + 1] + ln_b[d0 + kk + 1];
        __hip_bfloat162 pk;
        pk.x = __float2bfloat16(v0);
        pk.y = __float2bfloat16(v1);
        *(__hip_bfloat162*)(xn + (size_t)m * DM + d0 + kk) = pk;
    }
}

// ---------------- convert f32 -> bf16 with zero-padding ----------------
__global__ __launch_bounds__(256) void cvt_pad_kernel(const float* __restrict__ src,
                                                      __hip_bfloat16* __restrict__ dst,
                                                      int src_n, int tot_n) {
    int i = (blockIdx.x * 256 + threadIdx.x) * 4;
    if (i >= tot_n) return;
    float4 v = (i < src_n) ? *(const float4*)(src + i) : make_float4(0.f, 0.f, 0.f, 0.f);
    __hip_bfloat162 p0, p1;
    p0.x = __float2bfloat16(v.x); p0.y = __float2bfloat16(v.y);
    p1.x = __float2bfloat16(v.z); p1.y = __float2bfloat16(v.w);
    *(__hip_bfloat162*)(dst + i) = p0;
    *(__hip_bfloat162*)(dst + i + 2) = p1;
}

// ---------------- Kernel 2: GEMM1 bf16 MFMA (T2 swizzle + T1 remap, m-inner) ----------------
__global__ __launch_bounds__(256) void gemm1_mfma(const __hip_bfloat16* __restrict__ Wb,
                                                  const __hip_bfloat16* __restrict__ xn,
                                                  short* __restrict__ zx) {
    __shared__ short As[128][64];
    __shared__ short Bs[128][64];
    int tid = threadIdx.x;
    int lane = tid & 63;
    int wave = tid >> 6;
    int wr = wave >> 1, wc = wave & 1;
    int id = blockIdx.x;
    int xcd = id & 7;
    int pos = id >> 3;               // [0, 280)
    int j0 = (pos >> 3) * 128;       // j outer: 35 panels
    int m0 = (xcd * 8 + (pos & 7)) * 128;   // m inner
    int srow = tid >> 3;
    int skc = (((tid & 7) ^ ((tid >> 3) & 7)) * 8);

    f32x4 acc[4][4] = {};

    for (int k0 = 0; k0 < DM; k0 += 64) {
        __syncthreads();
#pragma unroll
        for (int q = 0; q < 4; q++) {
            gload16(Wb + (size_t)(j0 + q * 32 + srow) * DM + k0 + skc,
                    ((short*)As) + q * 2048 + wave * 512);
            gload16(xn + (size_t)(m0 + q * 32 + srow) * DM + k0 + skc,
                    ((short*)Bs) + q * 2048 + wave * 512);
        }
        asm volatile("s_waitcnt vmcnt(0)" ::: "memory");
        __syncthreads();
#pragma unroll
        for (int ks = 0; ks < 2; ks++) {
            int pch = (((ks * 4) + (lane >> 4)) ^ (lane & 7)) * 8;
            bf16x8 af[4], bfr[4];
#pragma unroll
            for (int i = 0; i < 4; i++)
                af[i] = *(const bf16x8*)&As[wr * 64 + i * 16 + (lane & 15)][pch];
#pragma unroll
            for (int n = 0; n < 4; n++)
                bfr[n] = *(const bf16x8*)&Bs[wc * 64 + n * 16 + (lane & 15)][pch];
#pragma unroll
            for (int i = 0; i < 4; i++)
#pragma unroll
                for (int n = 0; n < 4; n++)
                    acc[i][n] = __builtin_amdgcn_mfma_f32_16x16x32_bf16(af[i], bfr[n], acc[i][n], 0, 0, 0);
        }
    }
#pragma unroll
    for (int i = 0; i < 4; i++) {
        int j = j0 + wr * 64 + i * 16 + ((lane >> 4) << 2);
        if (j < DIP) {
#pragma unroll
            for (int n = 0; n < 4; n++) {
                int m = m0 + wc * 64 + n * 16 + (lane & 15);
                short4 s4;
                s4.x = f2bs(acc[i][n][0]); s4.y = f2bs(acc[i][n][1]);
                s4.z = f2bs(acc[i][n][2]); s4.w = f2bs(acc[i][n][3]);
                *(short4*)(zx + (size_t)m * DIP + j) = s4;
            }
        }
    }
}

// ---------------- Kernel 2b: split-K f32 strip GEMM for dt cols -> partial sums ----------------
__global__ __launch_bounds__(256) void gemm1_strip(const float* __restrict__ x,
                                                   const float* __restrict__ mu,
                                                   const float* __restrict__ rs,
                                                   const float* __restrict__ ln_w,
                                                   const float* __restrict__ ln_b,
                                                   const float* __restrict__ Win,
                                                   float* __restrict__ partial) {
    __shared__ float As[16][64];
    __shared__ float Ws[64][17];
    int tid = threadIdx.x;
    int tx = tid & 15;
    int ty = tid >> 4;
    int j0 = 4352;
    int kq = blockIdx.x;
    int m0 = blockIdx.y * 64;
    int b = m0 >> 12;
    int t0 = m0 & 4095;
    const float* Xb = x + (size_t)b * DM * TT + t0;

    int lr = tid >> 4;
    int lc = (tid & 15) * 4;
    int wr = tid >> 2;
    int wc = (tid & 3) * 4;

    float acc[4][4] = {};
    int kbeg = kq * (DM / KSPLIT);
    for (int k0 = kbeg; k0 < kbeg + DM / KSPLIT; k0 += 16) {
        float4 xv = *(const float4*)(Xb + (size_t)(k0 + lr) * TT + lc);
        float4 muv = *(const float4*)(&mu[m0 + lc]);
        float4 rsv = *(const float4*)(&rs[m0 + lc]);
        float lw = ln_w[k0 + lr], lb = ln_b[k0 + lr];
        As[lr][lc]     = (xv.x - muv.x) * rsv.x * lw + lb;
        As[lr][lc + 1] = (xv.y - muv.y) * rsv.y * lw + lb;
        As[lr][lc + 2] = (xv.z - muv.z) * rsv.z * lw + lb;
        As[lr][lc + 3] = (xv.w - muv.w) * rsv.w * lw + lb;

        int j = j0 + wr;
        float4 wv = make_float4(0.f, 0.f, 0.f, 0.f);
        if (j < DIP) wv = *(const float4*)(Win + (size_t)j * DM + k0 + wc);
        Ws[wr][wc] = wv.x; Ws[wr][wc + 1] = wv.y; Ws[wr][wc + 2] = wv.z; Ws[wr][wc + 3] = wv.w;
        __syncthreads();
#pragma unroll
        for (int kk = 0; kk < 16; kk++) {
            float4 a4 = *(const float4*)&As[kk][ty * 4];
            float a[4] = {a4.x, a4.y, a4.z, a4.w};
            float bv[4];
#pragma unroll
            for (int n = 0; n < 4; n++) bv[n] = Ws[tx * 4 + n][kk];
#pragma unroll
            for (int i = 0; i < 4; i++)
#pragma unroll
                for (int n = 0; n < 4; n++)
                    acc[i][n] = fmaf(a[i], bv[n], acc[i][n]);
        }
        __syncthreads();
    }
#pragma unroll
    for (int i = 0; i < 4; i++) {
        int m = m0 + ty * 4 + i;
        int hh = tx * 4;
        if (hh < NH) {
            float4 v = make_float4(acc[i][0], acc[i][1], acc[i][2], acc[i][3]);
            *(float4*)(partial + ((size_t)kq * BB * TT + m) * NH + hh) = v;
        }
    }
}

// ---------------- Kernel 2c: reduce split-K partials + bias + softplus -> dtv ----------------
__global__ __launch_bounds__(256) void dt_reduce_kernel(const float* __restrict__ partial,
                                                        const float* __restrict__ dt_bias,
                                                        float* __restrict__ dtv) {
    int i = blockIdx.x * 256 + threadIdx.x;
    int hh = i & (NH - 1);
    float s = 0.f;
#pragma unroll
    for (int kq = 0; kq < KSPLIT; kq++)
        s += partial[(size_t)kq * BB * TT * NH + i];
    float raw = s + dt_bias[hh];
    dtv[i] = (raw > 20.f) ? raw : log1pf(expf(raw));
}

// ---------------- Kernel 3: causal depthwise conv(4) + SiLU (bf16 in/out) ----------------
__global__ __launch_bounds__(256) void conv_kernel(const short* __restrict__ zx,
                                                   const float* __restrict__ cw,
                                                   const float* __restrict__ cb,
                                                   short* __restrict__ xBC) {
    size_t i = ((size_t)blockIdx.x * 256 + threadIdx.x) * 8;
    int c = (int)(i % CD);
    int t = (int)((i / CD) & (TT - 1));
    int b = (int)(i / ((size_t)CD * TT));
    const short* src = zx + (size_t)b * TT * DIP + DI + c;
    float acc[8];
#pragma unroll
    for (int e = 0; e < 8; e++) acc[e] = cb[c + e];
    float wv[8][4];
#pragma unroll
    for (int e = 0; e < 8; e++) {
        float4 w4 = *(const float4*)(cw + (c + e) * 4);
        wv[e][0] = w4.x; wv[e][1] = w4.y; wv[e][2] = w4.z; wv[e][3] = w4.w;
    }
#pragma unroll
    for (int k = 0; k < 4; k++) {
        int ts = t - 3 + k;
        if (ts >= 0) {
            bf16x8 v = *(const bf16x8*)(src + (size_t)ts * DIP);
#pragma unroll
            for (int e = 0; e < 8; e++)
                acc[e] = fmaf(wv[e][k], b2f(v[e]), acc[e]);
        }
    }
    short o[8];
#pragma unroll
    for (int e = 0; e < 8; e++) {
        float sg = 1.f / (1.f + expf(-acc[e]));
        o[e] = f2bs(acc[e] * sg);
    }
    *(bf16x8*)(xBC + i) = *(bf16x8*)o;
}

// ---------------- Kernel 5a: SSD chunk reduce (W folded into Xd; raw B operand) ----------------
__global__ __launch_bounds__(256, 2) void scan_reduce_ssd(const short* __restrict__ xBC,
                                                          const float* __restrict__ dtg,
                                                          const float* __restrict__ A_log,
                                                          float* __restrict__ S,
                                                          float* __restrict__ P) {
    int tid = threadIdx.x;
    int wave = tid >> 6, lane = tid & 63;
    int l4 = lane >> 4, l16 = lane & 15;
    int c = blockIdx.x, hh = blockIdx.y, b = blockIdx.z;
    int cbase = c * CL;

    __shared__ __align__(16) short BtL[64][136];
    __shared__ __align__(16) short XdL[64][72];
    __shared__ __align__(16) float sdt[64];
    __shared__ __align__(16) float sL[64];
    __shared__ __align__(16) float sW[64];

    f32x4 acc_h[2][4];
#pragma unroll
    for (int i = 0; i < 2; i++)
#pragma unroll
        for (int pq = 0; pq < 4; pq++) acc_h[i][pq] = (f32x4){0.f, 0.f, 0.f, 0.f};
    float Lsum = 0.f;

    float expA = expf(A_log[hh]);
    const float* dtb = dtg + (size_t)b * TT * NH + hh;
    const short* xb = xBC + (size_t)b * TT * CD;

#pragma unroll 1
    for (int f = 0; f < FPC; f++) {
        int t0 = cbase + f * FL;
        if (tid < 64) sdt[tid] = dtb[(size_t)(t0 + tid) * NH];
        {
            int r = tid >> 2, q = tid & 3;
            const short* bs = xb + (size_t)(t0 + r) * CD + DI + q * 32;
#pragma unroll
            for (int j = 0; j < 4; j++)
                *(bf16x8*)&BtL[r][q * 32 + j * 8] = *(const bf16x8*)(bs + j * 8);
        }
        __syncthreads();
        if (tid < 64) {
            float v = -expA * sdt[tid];
#pragma unroll
            for (int off = 1; off < 64; off <<= 1) {
                float u = __shfl_up(v, off);
                if (lane >= off) v += u;
            }
            sL[tid] = v;
            float lt = __shfl(v, 63);
            sW[tid] = expf(lt - v);
        }
        __syncthreads();
        {
            int s = tid & 63, pg2 = tid >> 6;
            const short* xs = xb + (size_t)(t0 + s) * CD + hh * HD + pg2 * 16;
            float dw = sdt[s] * sW[s];     // fold decay weight into Xd
            bf16x8 v0 = *(const bf16x8*)xs;
            bf16x8 v1 = *(const bf16x8*)(xs + 8);
#pragma unroll
            for (int j = 0; j < 8; j++) XdL[pg2 * 16 + j][s] = f2bs(b2f(v0[j]) * dw);
#pragma unroll
            for (int j = 0; j < 8; j++) XdL[pg2 * 16 + 8 + j][s] = f2bs(b2f(v1[j]) * dw);
        }
        __syncthreads();
        float Lft = sL[63];
        float Pf = expf(Lft);
        Lsum += Lft;
#pragma unroll
        for (int i = 0; i < 2; i++)
#pragma unroll
            for (int pq = 0; pq < 4; pq++) acc_h[i][pq] *= Pf;
#pragma unroll
        for (int ks = 0; ks < 2; ks++) {
            bf16x8 af2[2], bfw[4];
#pragma unroll
            for (int i = 0; i < 2; i++) {
                int nrow = wave * 32 + i * 16 + l16;
                short e[8];
#pragma unroll
                for (int j = 0; j < 8; j++)
                    e[j] = BtL[ks * 32 + l4 * 8 + j][nrow];
                af2[i] = *(bf16x8*)e;
            }
#pragma unroll
            for (int pq = 0; pq < 4; pq++)
                bfw[pq] = *(const bf16x8*)&XdL[pq * 16 + l16][ks * 32 + l4 * 8];
#pragma unroll
            for (int i = 0; i < 2; i++)
#pragma unroll
                for (int pq = 0; pq < 4; pq++)
                    acc_h[i][pq] = __builtin_amdgcn_mfma_f32_16x16x32_bf16(af2[i], bfw[pq], acc_h[i][pq], 0, 0, 0);
        }
        __syncthreads();
    }

    float* Sp = S + (size_t)c * SELEMS + ((size_t)(b * NH + hh) * HD) * DSTATE;
#pragma unroll
    for (int i = 0; i < 2; i++)
#pragma unroll
        for (int pq = 0; pq < 4; pq++) {
            int nb = wave * 32 + i * 16 + (l4 << 2);
            int p = pq * 16 + l16;
            *(f32x4*)(Sp + (size_t)p * DSTATE + nb) = acc_h[i][pq];
        }
    if (tid == 0) P[(c * BB + b) * NH + hh] = expf(Lsum);
}

// ---------------- Kernel 5b: sequential chunk combine ----------------
__global__ __launch_bounds__(256) void scan_combine_kernel(const float* __restrict__ h0,
                                                           const float* __restrict__ P,
                                                           float* __restrict__ S,
                                                           float* __restrict__ hT) {
    size_t tid = (size_t)blockIdx.x * 256 + threadIdx.x;
    int hh = (int)((tid >> 13) & 31);
    int b = (int)(tid >> 18);
    float h = h0[tid];
#pragma unroll
    for (int c = 0; c < NC; c++) {
        float s = S[(size_t)c * SELEMS + tid];
        S[(size_t)c * SELEMS + tid] = h;
        h = fmaf(P[(c * BB + b) * NH + hh], h, s);
    }
    hT[tid] = h;
}

// ---------------- Kernel 5c: SSD emit (bf16 y out; scaled XdwL for state update) ----------------
__global__ __launch_bounds__(256, 2) void scan_emit_ssd(const short* __restrict__ xBC,
                                                        const float* __restrict__ dtg,
                                                        const float* __restrict__ A_log,
                                                        const float* __restrict__ S,
                                                        const float* __restrict__ Dp,
                                                        short* __restrict__ ybq) {
    int tid = threadIdx.x;
    int wave = tid >> 6, lane = tid & 63;
    int l4 = lane >> 4, l16 = lane & 15;
    int c = blockIdx.x, hh = blockIdx.y, b = blockIdx.z;
    int cbase = c * CL;

    __shared__ __align__(16) short CtL[64][136];
    __shared__ __align__(16) short BtL[64][136];
    __shared__ __align__(16) short hL[64][132];
    __shared__ __align__(16) short XdL[64][72];
    __shared__ __align__(16) short XdwL[64][72];
    __shared__ __align__(16) short ML[64][72];
    __shared__ __align__(16) float sdt[64];
    __shared__ __align__(16) float sL[64];
    __shared__ __align__(16) float sW[64];
    __shared__ __align__(16) float sRdt[64];

    f32x4 acc_h[2][4];
    {
        const float* Sp = S + (size_t)c * SELEMS + ((size_t)(b * NH + hh) * HD) * DSTATE;
#pragma unroll
        for (int i = 0; i < 2; i++)
#pragma unroll
            for (int pq = 0; pq < 4; pq++) {
                int nb = wave * 32 + i * 16 + (l4 << 2);
                int p = pq * 16 + l16;
                acc_h[i][pq] = *(const f32x4*)(Sp + (size_t)p * DSTATE + nb);
            }
    }

    float expA = expf(A_log[hh]);
    float Dh = Dp[hh];
    const float* dtb = dtg + (size_t)b * TT * NH + hh;
    const short* xb = xBC + (size_t)b * TT * CD;
    short* yb = ybq + (size_t)b * TT * DI + hh * HD;

    int tg = wave >> 1;
    int sg = wave & 1;

#pragma unroll 1
    for (int f = 0; f < FPC; f++) {
        int t0 = cbase + f * FL;

        if (tid < 64) sdt[tid] = dtb[(size_t)(t0 + tid) * NH];
        {
            int r = tid >> 2, q = tid & 3;
            const short* cs = xb + (size_t)(t0 + r) * CD + DI + DSTATE + q * 32;
            const short* bs = xb + (size_t)(t0 + r) * CD + DI + q * 32;
#pragma unroll
            for (int j = 0; j < 4; j++) {
                *(bf16x8*)&CtL[r][q * 32 + j * 8] = *(const bf16x8*)(cs + j * 8);
                *(bf16x8*)&BtL[r][q * 32 + j * 8] = *(const bf16x8*)(bs + j * 8);
            }
        }
#pragma unroll
        for (int i = 0; i < 2; i++)
#pragma unroll
            for (int pq = 0; pq < 4; pq++) {
                int nb = wave * 32 + i * 16 + (l4 << 2);
                int p = pq * 16 + l16;
                *(short2*)&hL[p][nb] = make_short2(f2bs(acc_h[i][pq][0]), f2bs(acc_h[i][pq][1]));
                *(short2*)&hL[p][nb + 2] = make_short2(f2bs(acc_h[i][pq][2]), f2bs(acc_h[i][pq][3]));
            }
        __syncthreads();

        if (tid < 64) {
            float v = -expA * sdt[tid];
#pragma unroll
            for (int off = 1; off < 64; off <<= 1) {
                float u = __shfl_up(v, off);
                if (lane >= off) v += u;
            }
            sL[tid] = v;
            float lt = __shfl(v, 63);
            sW[tid] = expf(lt - v);
            sRdt[tid] = 1.f / sdt[tid];
        }
        __syncthreads();

        {
            int s = tid & 63, pg = tid >> 6;
            const short* xs = xb + (size_t)(t0 + s) * CD + hh * HD + pg * 16;
            float dts = sdt[s];
            float dw = dts * sW[s];
            bf16x8 v0 = *(const bf16x8*)xs;
            bf16x8 v1 = *(const bf16x8*)(xs + 8);
#pragma unroll
            for (int j = 0; j < 8; j++) {
                float xv = b2f(v0[j]);
                XdL[pg * 16 + j][s] = f2bs(xv * dts);
                XdwL[pg * 16 + j][s] = f2bs(xv * dw);
            }
#pragma unroll
            for (int j = 0; j < 8; j++) {
                float xv = b2f(v1[j]);
                XdL[pg * 16 + 8 + j][s] = f2bs(xv * dts);
                XdwL[pg * 16 + 8 + j][s] = f2bs(xv * dw);
            }
        }
        __syncthreads();

        {
            f32x4 g[2][2] = {};
#pragma unroll
            for (int ks = 0; ks < 4; ks++) {
                bf16x8 af[2], bfm[2];
#pragma unroll
                for (int i = 0; i < 2; i++)
                    af[i] = *(const bf16x8*)&CtL[tg * 32 + i * 16 + l16][ks * 32 + l4 * 8];
#pragma unroll
                for (int n = 0; n < 2; n++)
                    bfm[n] = *(const bf16x8*)&BtL[sg * 32 + n * 16 + l16][ks * 32 + l4 * 8];
#pragma unroll
                for (int i = 0; i < 2; i++)
#pragma unroll
                    for (int n = 0; n < 2; n++)
                        g[i][n] = __builtin_amdgcn_mfma_f32_16x16x32_bf16(af[i], bfm[n], g[i][n], 0, 0, 0);
            }
#pragma unroll
            for (int i = 0; i < 2; i++) {
                int tb2 = tg * 32 + i * 16 + (l4 << 2);
                float4 Lt = *(const float4*)&sL[tb2];
                float Ltr[4] = {Lt.x, Lt.y, Lt.z, Lt.w};
#pragma unroll
                for (int n = 0; n < 2; n++) {
                    int sE = sg * 32 + n * 16 + l16;
                    float Ls = sL[sE];
#pragma unroll
                    for (int r2 = 0; r2 < 4; r2++) {
                        float m = (sE <= tb2 + r2) ? g[i][n][r2] * expf(Ltr[r2] - Ls) : 0.f;
                        ML[tb2 + r2][sE] = f2bs(m);
                    }
                }
            }
        }
        __syncthreads();

        {
            f32x4 ay[2][2] = {};
            f32x4 ai[2][2] = {};
#pragma unroll
            for (int ks = 0; ks < 2; ks++) {
                bf16x8 af[2], bfp[2];
#pragma unroll
                for (int i = 0; i < 2; i++)
                    af[i] = *(const bf16x8*)&ML[tg * 32 + i * 16 + l16][ks * 32 + l4 * 8];
#pragma unroll
                for (int n = 0; n < 2; n++)
                    bfp[n] = *(const bf16x8*)&XdL[sg * 32 + n * 16 + l16][ks * 32 + l4 * 8];
#pragma unroll
                for (int i = 0; i < 2; i++)
#pragma unroll
                    for (int n = 0; n < 2; n++)
                        ay[i][n] = __builtin_amdgcn_mfma_f32_16x16x32_bf16(af[i], bfp[n], ay[i][n], 0, 0, 0);
            }
#pragma unroll
            for (int ks = 0; ks < 4; ks++) {
                bf16x8 af[2], bfh[2];
#pragma unroll
                for (int i = 0; i < 2; i++)
                    af[i] = *(const bf16x8*)&CtL[tg * 32 + i * 16 + l16][ks * 32 + l4 * 8];
#pragma unroll
                for (int n = 0; n < 2; n++) {
                    int prow = sg * 32 + n * 16 + l16;
                    int kb = ks * 32 + l4 * 8;
                    union { bf16x8 v; uint2 u2[2]; } hu;
                    hu.u2[0] = *(const uint2*)&hL[prow][kb];
                    hu.u2[1] = *(const uint2*)&hL[prow][kb + 4];
                    bfh[n] = hu.v;
                }
#pragma unroll
                for (int i = 0; i < 2; i++)
#pragma unroll
                    for (int n = 0; n < 2; n++)
                        ai[i][n] = __builtin_amdgcn_mfma_f32_16x16x32_bf16(af[i], bfh[n], ai[i][n], 0, 0, 0);
            }
            float Lft = sL[63];
#pragma unroll
            for (int i = 0; i < 2; i++) {
                int tb2 = tg * 32 + i * 16 + (l4 << 2);
                float4 Lt = *(const float4*)&sL[tb2];
                float4 Rt = *(const float4*)&sRdt[tb2];
                float Ltr[4] = {Lt.x, Lt.y, Lt.z, Lt.w};
                float Rtr[4] = {Rt.x, Rt.y, Rt.z, Rt.w};
#pragma unroll
                for (int n = 0; n < 2; n++) {
                    int p = sg * 32 + n * 16 + l16;
#pragma unroll
                    for (int r2 = 0; r2 < 4; r2++) {
                        float xv = b2f(XdL[p][tb2 + r2]) * Rtr[r2];
                        float yv = ay[i][n][r2] + expf(Ltr[r2]) * ai[i][n][r2] + Dh * xv;
                        yb[(size_t)(t0 + tb2 + r2) * DI + p] = f2bs(yv);
                    }
                }
            }
            float Pf = expf(Lft);
#pragma unroll
            for (int i = 0; i < 2; i++)
#pragma unroll
                for (int pq = 0; pq < 4; pq++)
                    acc_h[i][pq] *= Pf;
#pragma unroll
            for (int ks = 0; ks < 2; ks++) {
                bf16x8 af2[2], bfw[4];
#pragma unroll
                for (int i = 0; i < 2; i++) {
                    int nrow = wave * 32 + i * 16 + l16;
                    short e[8];
#pragma unroll
                    for (int j = 0; j < 8; j++)
                        e[j] = BtL[ks * 32 + l4 * 8 + j][nrow];
                    af2[i] = *(bf16x8*)e;
                }
#pragma unroll
                for (int pq = 0; pq < 4; pq++)
                    bfw[pq] = *(const bf16x8*)&XdwL[pq * 16 + l16][ks * 32 + l4 * 8];
#pragma unroll
                for (int i = 0; i < 2; i++)
#pragma unroll
                    for (int pq = 0; pq < 4; pq++)
                        acc_h[i][pq] = __builtin_amdgcn_mfma_f32_16x16x32_bf16(af2[i], bfw[pq], acc_h[i][pq], 0, 0, 0);
            }
        }
        __syncthreads();
    }
}

// ---------------- Kernel 6: gating + RMSNorm (bf16 y, bf16 z) -> bf16 g ----------------
__global__ __launch_bounds__(256) void gate_rms_kernel(const short* __restrict__ ybq,
                                                       const short* __restrict__ zx,
                                                       const float* __restrict__ rw,
                                                       __hip_bfloat16* __restrict__ gq) {
    int m = blockIdx.x;
    int tid = threadIdx.x;
    const short* yr = ybq + (size_t)m * DI;
    const short* zr = zx + (size_t)m * DIP;
    int base = tid * 8;
    float gv[8];
    float ss = 0.f;
    bf16x8 yv8 = *(const bf16x8*)(yr + base);
    bf16x8 zv8 = *(const bf16x8*)(zr + base);
#pragma unroll
    for (int i = 0; i < 8; i++) {
        float y = b2f(yv8[i]);
        float z = b2f(zv8[i]);
        float sg = 1.f / (1.f + expf(-z));
        float gg = y * z * sg;
        gv[i] = gg;
        ss += gg * gg;
    }
#pragma unroll
    for (int off = 1; off < 64; off <<= 1) ss += __shfl_xor(ss, off);
    __shared__ float red[4];
    int w = tid >> 6;
    if ((tid & 63) == 0) red[w] = ss;
    __syncthreads();
    float tot = red[0] + red[1] + red[2] + red[3];
    float r = rsqrtf(tot * (1.f / DI) + 1e-5f);
#pragma unroll
    for (int i = 0; i < 8; i += 2) {
        __hip_bfloat162 p;
        p.x = __float2bfloat16(gv[i] * r * rw[base + i]);
        p.y = __float2bfloat16(gv[i + 1] * r * rw[base + i + 1]);
        *(__hip_bfloat162*)(gq + (size_t)m * DI + base + i) = p;
    }
}

// ---------------- Kernel 7: GEMM2 bf16 MFMA (T2 swizzle + T1 remap m-inner, transposed store) ----------------
__global__ __launch_bounds__(256) void gemm2_mfma(const __hip_bfloat16* __restrict__ gq,
                                                  const __hip_bfloat16* __restrict__ Wob,
                                                  float* __restrict__ out) {
    __shared__ short As[128][64];
    __shared__ short Bs[128][64];
    int tid = threadIdx.x;
    int lane = tid & 63;
    int wave = tid >> 6;
    int wr = wave >> 1, wc = wave & 1;
    int id = blockIdx.x;
    int xcd = id & 7;
    int pos = id >> 3;
    int j0 = (pos >> 3) * 128;
    int m0 = (xcd * 8 + (pos & 7)) * 128;
    int srow = tid >> 3;
    int skc = (((tid & 7) ^ ((tid >> 3) & 7)) * 8);

    f32x4 acc[4][4] = {};

    for (int k0 = 0; k0 < DI; k0 += 64) {
        __syncthreads();
#pragma unroll
        for (int q = 0; q < 4; q++) {
            gload16(gq + (size_t)(m0 + q * 32 + srow) * DI + k0 + skc,
                    ((short*)As) + q * 2048 + wave * 512);
            gload16(Wob + (size_t)(j0 + q * 32 + srow) * DI + k0 + skc,
                    ((short*)Bs) + q * 2048 + wave * 512);
        }
        asm volatile("s_waitcnt vmcnt(0)" ::: "memory");
        __syncthreads();
#pragma unroll
        for (int ks = 0; ks < 2; ks++) {
            int pch = (((ks * 4) + (lane >> 4)) ^ (lane & 7)) * 8;
            bf16x8 af[4], bfr[4];
#pragma unroll
            for (int i = 0; i < 4; i++)
                af[i] = *(const bf16x8*)&As[wr * 64 + i * 16 + (lane & 15)][pch];
#pragma unroll
            for (int n = 0; n < 4; n++)
                bfr[n] = *(const bf16x8*)&Bs[wc * 64 + n * 16 + (lane & 15)][pch];
#pragma unroll
            for (int i = 0; i < 4; i++)
#pragma unroll
                for (int n = 0; n < 4; n++)
                    acc[i][n] = __builtin_amdgcn_mfma_f32_16x16x32_bf16(af[i], bfr[n], acc[i][n], 0, 0, 0);
        }
    }
#pragma unroll
    for (int i = 0; i < 4; i++) {
        int m = m0 + wr * 64 + i * 16 + ((lane >> 4) << 2);
        int b = m >> 12;
        int t = m & 4095;
#pragma unroll
        for (int n = 0; n < 4; n++) {
            int j = j0 + wc * 64 + n * 16 + (lane & 15);
            *(f32x4*)(out + (size_t)b * DM * TT + (size_t)j * TT + t) = acc[i][n];
        }
    }
}

extern "C" void kernel_launch(void* const* d_in, const int* in_sizes, int n_in,
                              void* d_out, int out_size, void* d_ws, size_t ws_size,
                              hipStream_t stream) {
    const float* x       = (const float*)d_in[0];
    const float* ln_w    = (const float*)d_in[1];
    const float* ln_b    = (const float*)d_in[2];
    const float* W_in    = (const float*)d_in[3];
    const float* conv_w  = (const float*)d_in[4];
    const float* conv_b  = (const float*)d_in[5];
    const float* dt_bias = (const float*)d_in[6];
    const float* A_log   = (const float*)d_in[7];
    const float* Dp      = (const float*)d_in[8];
    const float* rms_w   = (const float*)d_in[9];
    const float* W_out   = (const float*)d_in[10];
    const float* h0      = (const float*)d_in[11];

    float* out = (float*)d_out;
    float* hT = out + (size_t)BB * DM * TT;

    char* ws = (char*)d_ws;
    // Workspace layout — total 211,355,648 bytes (under proven 238 MB):
    float* mu   = (float*)(ws + 0);                       //      32,768
    float* rs   = (float*)(ws + 32768);                   //      32,768
    short* zxq  = (short*)(ws + 65536);                   //  71,827,456  (B,T,4384) bf16
    short* xBCq = (short*)(ws + 71892992);                //  37,748,736  (B,T,2304) bf16
    __hip_bfloat16* gq  = (__hip_bfloat16*)(ws + 71892992);        // overlays xBC (post-emit)
    __hip_bfloat16* Wob = (__hip_bfloat16*)(ws + 105447424);       // overlays xBC tail
    short* ybq  = (short*)(ws + 109641728);               //  33,554,432  (B,T,2048) bf16
    __hip_bfloat16* Wb  = (__hip_bfloat16*)(ws + 109641728);       // overlays ybq (pre-scan)
    float* dtv  = (float*)(ws + 176750592);               //   1,048,576
    __hip_bfloat16* xnb = (__hip_bfloat16*)(ws + 177799168);       //  16,777,216 (shares S)
    float* S    = (float*)(ws + 177799168);
    float* P    = (float*)(ws + 194576384);               //       2,048
    float* dpart = (float*)(ws + 194578432);              //  16,777,216  (KSPLIT,B*T,NH)

    ln_stats_kernel<<<(TT / 32) * BB, 256, 0, stream>>>(x, mu, rs);
    xn_kernel<<<dim3(TT / 64, DM / 64, BB), 256, 0, stream>>>(x, mu, rs, ln_w, ln_b, xnb);
    cvt_pad_kernel<<<(NP1 * DM) / 1024, 256, 0, stream>>>(W_in, Wb, DIP * DM, NP1 * DM);
    gemm1_mfma<<<(NP1 / 128) * ((BB * TT) / 128), 256, 0, stream>>>(Wb, xnb, zxq);
    gemm1_strip<<<dim3(KSPLIT, (BB * TT) / 64), 256, 0, stream>>>(x, mu, rs, ln_w, ln_b, W_in, dpart);
    dt_reduce_kernel<<<(BB * TT * NH) / 256, 256, 0, stream>>>(dpart, dt_bias, dtv);
    conv_kernel<<<(int)(((size_t)BB * TT * CD) / 2048), 256, 0, stream>>>(zxq, conv_w, conv_b, xBCq);
    scan_reduce_ssd<<<dim3(NC, NH, BB), 256, 0, stream>>>(xBCq, dtv, A_log, S, P);
    scan_combine_kernel<<<(int)(SELEMS / 256), 256, 0, stream>>>(h0, P, S, hT);
    scan_emit_ssd<<<dim3(NC, NH, BB), 256, 0, stream>>>(xBCq, dtv, A_log, S, Dp, ybq);
    cvt_pad_kernel<<<(DM * DI) / 1024, 256, 0, stream>>>(W_out, Wob, DM * DI, DM * DI);
    gate_rms_kernel<<<BB * TT, 256, 0, stream>>>(ybq, zxq, rms_w, gq);
    gemm2_mfma<<<((BB * TT) / 128) * (DM / 128), 256, 0, stream>>>(gq, Wob, out);
}

// Round 16
// 317.171 us; speedup vs baseline: 7.0041x; 1.1554x over previous
//
#include <hip/hip_runtime.h>
#include <hip/hip_bf16.h>
#include <math.h>

// Problem constants
#define BB 2
#define TT 4096
#define DM 1024
#define DSTATE 128
#define DI 2048
#define HD 64
#define NH 32
#define DIP 4384   // 2*DI + 2*DSTATE + NH
#define CD 2304    // DI + 2*DSTATE

// Chunked scan parameters
#define NC 8
#define CL 512
#define FL 64            // SSD fine-chunk length
#define FPC (CL / FL)    // 8
#define SELEMS ((size_t)BB * NH * HD * DSTATE)   // 524288

#define NP1 4480   // DIP padded to multiple of 128 for MFMA staging
#define KSPLIT 16  // split-K factor for the dt strip GEMM

typedef __attribute__((ext_vector_type(8))) short bf16x8;
typedef __attribute__((ext_vector_type(4))) float f32x4;

__device__ inline void gload16(const void* g, void* l) {
    __builtin_amdgcn_global_load_lds(
        (const __attribute__((address_space(1))) void*)g,
        (__attribute__((address_space(3))) void*)l, 16, 0, 0);
}

__device__ inline short f2bs(float f) {
    __hip_bfloat16 h = __float2bfloat16(f);
    union { __hip_bfloat16 h; short s; } u;
    u.h = h;
    return u.s;
}
__device__ inline float b2f(short s) {
    union { float f; unsigned u; } u;
    u.u = ((unsigned)(unsigned short)s) << 16;
    return u.f;
}

// ---------------- Kernel 1: LayerNorm statistics (split-D, 256 blocks) ----------------
__global__ __launch_bounds__(256) void ln_stats_kernel(const float* __restrict__ x,
                                                       float* __restrict__ mu,
                                                       float* __restrict__ rs) {
    __shared__ float sred[2][8][32];
    int tid = threadIdx.x;
    int tl = tid & 31;
    int ds = tid >> 5;               // 0..7
    int t = (blockIdx.x & 127) * 32 + tl;
    int b = blockIdx.x >> 7;
    const float* xb = x + (size_t)b * DM * TT + (size_t)ds * 128 * TT + t;
    float s = 0.f, ss = 0.f;
#pragma unroll 8
    for (int d = 0; d < 128; d++) {
        float v = xb[(size_t)d * TT];
        s += v;
        ss += v * v;
    }
    sred[0][ds][tl] = s;
    sred[1][ds][tl] = ss;
    __syncthreads();
    if (tid < 32) {
        float st = 0.f, sst = 0.f;
#pragma unroll
        for (int q = 0; q < 8; q++) { st += sred[0][q][tid]; sst += sred[1][q][tid]; }
        float m = st * (1.f / DM);
        float var = sst * (1.f / DM) - m * m;
        int idx = b * TT + (blockIdx.x & 127) * 32 + tid;
        mu[idx] = m;
        rs[idx] = rsqrtf(var + 1e-5f);
    }
}

// ---------------- Kernel 1b: xn = LN(x) transposed to (m, k) in bf16 ----------------
__global__ __launch_bounds__(256) void xn_kernel(const float* __restrict__ x,
                                                 const float* __restrict__ mu,
                                                 const float* __restrict__ rs,
                                                 const float* __restrict__ ln_w,
                                                 const float* __restrict__ ln_b,
                                                 __hip_bfloat16* __restrict__ xn) {
    __shared__ float tile[64][65];
    int tid = threadIdx.x;
    int t0 = blockIdx.x * 64, d0 = blockIdx.y * 64, b = blockIdx.z;
#pragma unroll
    for (int i = 0; i < 64; i += 4) {
        int dl = i + (tid >> 6);
        tile[dl][tid & 63] = x[(size_t)b * DM * TT + (size_t)(d0 + dl) * TT + t0 + (tid & 63)];
    }
    __syncthreads();
#pragma unroll
    for (int i = 0; i < 64; i += 8) {
        int tl = i + (tid >> 5);
        int kk = (tid & 31) * 2;
        int m = b * TT + t0 + tl;
        float mu_m = mu[m], rs_m = rs[m];
        float v0 = (tile[kk][tl] - mu_m) * rs_m * ln_w[d0 + kk] + ln_b[d0 + kk];
        float v1 = (tile[kk + 1][tl] - mu_m) * rs_m * ln_w[d0 + kk + 1] + ln_b[d0 + kk + 1];
        __hip_bfloat162 pk;
        pk.x = __float2bfloat16(v0);
        pk.y = __float2bfloat16(v1);
        *(__hip_bfloat162*)(xn + (size_t)m * DM + d0 + kk) = pk;
    }
}

// ---------------- convert f32 -> bf16 with zero-padding ----------------
__global__ __launch_bounds__(256) void cvt_pad_kernel(const float* __restrict__ src,
                                                      __hip_bfloat16* __restrict__ dst,
                                                      int src_n, int tot_n) {
    int i = (blockIdx.x * 256 + threadIdx.x) * 4;
    if (i >= tot_n) return;
    float4 v = (i < src_n) ? *(const float4*)(src + i) : make_float4(0.f, 0.f, 0.f, 0.f);
    __hip_bfloat162 p0, p1;
    p0.x = __float2bfloat16(v.x); p0.y = __float2bfloat16(v.y);
    p1.x = __float2bfloat16(v.z); p1.y = __float2bfloat16(v.w);
    *(__hip_bfloat162*)(dst + i) = p0;
    *(__hip_bfloat162*)(dst + i + 2) = p1;
}

// ---------------- Kernel 2: GEMM1 bf16 MFMA (T2 swizzle + T1 remap, m-inner) ----------------
__global__ __launch_bounds__(256) void gemm1_mfma(const __hip_bfloat16* __restrict__ Wb,
                                                  const __hip_bfloat16* __restrict__ xn,
                                                  short* __restrict__ zx) {
    __shared__ short As[128][64];
    __shared__ short Bs[128][64];
    int tid = threadIdx.x;
    int lane = tid & 63;
    int wave = tid >> 6;
    int wr = wave >> 1, wc = wave & 1;
    int id = blockIdx.x;
    int xcd = id & 7;
    int pos = id >> 3;               // [0, 280)
    int j0 = (pos >> 3) * 128;       // j outer: 35 panels
    int m0 = (xcd * 8 + (pos & 7)) * 128;   // m inner
    int srow = tid >> 3;
    int skc = (((tid & 7) ^ ((tid >> 3) & 7)) * 8);

    f32x4 acc[4][4] = {};

    for (int k0 = 0; k0 < DM; k0 += 64) {
        __syncthreads();
#pragma unroll
        for (int q = 0; q < 4; q++) {
            gload16(Wb + (size_t)(j0 + q * 32 + srow) * DM + k0 + skc,
                    ((short*)As) + q * 2048 + wave * 512);
            gload16(xn + (size_t)(m0 + q * 32 + srow) * DM + k0 + skc,
                    ((short*)Bs) + q * 2048 + wave * 512);
        }
        asm volatile("s_waitcnt vmcnt(0)" ::: "memory");
        __syncthreads();
#pragma unroll
        for (int ks = 0; ks < 2; ks++) {
            int pch = (((ks * 4) + (lane >> 4)) ^ (lane & 7)) * 8;
            bf16x8 af[4], bfr[4];
#pragma unroll
            for (int i = 0; i < 4; i++)
                af[i] = *(const bf16x8*)&As[wr * 64 + i * 16 + (lane & 15)][pch];
#pragma unroll
            for (int n = 0; n < 4; n++)
                bfr[n] = *(const bf16x8*)&Bs[wc * 64 + n * 16 + (lane & 15)][pch];
#pragma unroll
            for (int i = 0; i < 4; i++)
#pragma unroll
                for (int n = 0; n < 4; n++)
                    acc[i][n] = __builtin_amdgcn_mfma_f32_16x16x32_bf16(af[i], bfr[n], acc[i][n], 0, 0, 0);
        }
    }
#pragma unroll
    for (int i = 0; i < 4; i++) {
        int j = j0 + wr * 64 + i * 16 + ((lane >> 4) << 2);
        if (j < DIP) {
#pragma unroll
            for (int n = 0; n < 4; n++) {
                int m = m0 + wc * 64 + n * 16 + (lane & 15);
                short4 s4;
                s4.x = f2bs(acc[i][n][0]); s4.y = f2bs(acc[i][n][1]);
                s4.z = f2bs(acc[i][n][2]); s4.w = f2bs(acc[i][n][3]);
                *(short4*)(zx + (size_t)m * DIP + j) = s4;
            }
        }
    }
}

// ---------------- Kernel 2b: split-K f32 strip GEMM for dt cols -> partial sums ----------------
__global__ __launch_bounds__(256) void gemm1_strip(const float* __restrict__ x,
                                                   const float* __restrict__ mu,
                                                   const float* __restrict__ rs,
                                                   const float* __restrict__ ln_w,
                                                   const float* __restrict__ ln_b,
                                                   const float* __restrict__ Win,
                                                   float* __restrict__ partial) {
    __shared__ float As[16][64];
    __shared__ float Ws[64][17];
    int tid = threadIdx.x;
    int tx = tid & 15;
    int ty = tid >> 4;
    int j0 = 4352;
    int kq = blockIdx.x;
    int m0 = blockIdx.y * 64;
    int b = m0 >> 12;
    int t0 = m0 & 4095;
    const float* Xb = x + (size_t)b * DM * TT + t0;

    int lr = tid >> 4;
    int lc = (tid & 15) * 4;
    int wr = tid >> 2;
    int wc = (tid & 3) * 4;

    float acc[4][4] = {};
    int kbeg = kq * (DM / KSPLIT);
    for (int k0 = kbeg; k0 < kbeg + DM / KSPLIT; k0 += 16) {
        float4 xv = *(const float4*)(Xb + (size_t)(k0 + lr) * TT + lc);
        float4 muv = *(const float4*)(&mu[m0 + lc]);
        float4 rsv = *(const float4*)(&rs[m0 + lc]);
        float lw = ln_w[k0 + lr], lb = ln_b[k0 + lr];
        As[lr][lc]     = (xv.x - muv.x) * rsv.x * lw + lb;
        As[lr][lc + 1] = (xv.y - muv.y) * rsv.y * lw + lb;
        As[lr][lc + 2] = (xv.z - muv.z) * rsv.z * lw + lb;
        As[lr][lc + 3] = (xv.w - muv.w) * rsv.w * lw + lb;

        int j = j0 + wr;
        float4 wv = make_float4(0.f, 0.f, 0.f, 0.f);
        if (j < DIP) wv = *(const float4*)(Win + (size_t)j * DM + k0 + wc);
        Ws[wr][wc] = wv.x; Ws[wr][wc + 1] = wv.y; Ws[wr][wc + 2] = wv.z; Ws[wr][wc + 3] = wv.w;
        __syncthreads();
#pragma unroll
        for (int kk = 0; kk < 16; kk++) {
            float4 a4 = *(const float4*)&As[kk][ty * 4];
            float a[4] = {a4.x, a4.y, a4.z, a4.w};
            float bv[4];
#pragma unroll
            for (int n = 0; n < 4; n++) bv[n] = Ws[tx * 4 + n][kk];
#pragma unroll
            for (int i = 0; i < 4; i++)
#pragma unroll
                for (int n = 0; n < 4; n++)
                    acc[i][n] = fmaf(a[i], bv[n], acc[i][n]);
        }
        __syncthreads();
    }
#pragma unroll
    for (int i = 0; i < 4; i++) {
        int m = m0 + ty * 4 + i;
        int hh = tx * 4;
        if (hh < NH) {
            float4 v = make_float4(acc[i][0], acc[i][1], acc[i][2], acc[i][3]);
            *(float4*)(partial + ((size_t)kq * BB * TT + m) * NH + hh) = v;
        }
    }
}

// ---------------- Kernel 2c: reduce split-K partials + bias + softplus -> dtv ----------------
__global__ __launch_bounds__(256) void dt_reduce_kernel(const float* __restrict__ partial,
                                                        const float* __restrict__ dt_bias,
                                                        float* __restrict__ dtv) {
    int i = blockIdx.x * 256 + threadIdx.x;
    int hh = i & (NH - 1);
    float s = 0.f;
#pragma unroll
    for (int kq = 0; kq < KSPLIT; kq++)
        s += partial[(size_t)kq * BB * TT * NH + i];
    float raw = s + dt_bias[hh];
    dtv[i] = (raw > 20.f) ? raw : log1pf(expf(raw));
}

// ---------------- Kernel 3: causal depthwise conv(4) + SiLU — 4t x 8ch register reuse ----------------
// Thread computes outputs (tb..tb+3) x 8 channels from 7 row-loads (vs 16).
__global__ __launch_bounds__(256) void conv_kernel(const short* __restrict__ zx,
                                                   const float* __restrict__ cw,
                                                   const float* __restrict__ cb,
                                                   short* __restrict__ xBC) {
    int gid = blockIdx.x * 256 + threadIdx.x;      // over BB*(TT/4)*(CD/8) = 589824
    int cq = gid % (CD / 8);
    int tq = (gid / (CD / 8)) % (TT / 4);
    int b  = gid / ((CD / 8) * (TT / 4));
    int c = cq * 8, tb = tq * 4;
    const short* src = zx + (size_t)b * TT * DIP + DI + c;

    float wv[8][4];
    float acc[4][8];
#pragma unroll
    for (int e = 0; e < 8; e++) {
        float4 w4 = *(const float4*)(cw + (c + e) * 4);
        wv[e][0] = w4.x; wv[e][1] = w4.y; wv[e][2] = w4.z; wv[e][3] = w4.w;
        float bias = cb[c + e];
#pragma unroll
        for (int o = 0; o < 4; o++) acc[o][e] = bias;
    }

#pragma unroll
    for (int r = 0; r < 7; r++) {
        int ts = tb - 3 + r;
        if (ts >= 0) {
            bf16x8 v = *(const bf16x8*)(src + (size_t)ts * DIP);
            float rowf[8];
#pragma unroll
            for (int e = 0; e < 8; e++) rowf[e] = b2f(v[e]);
#pragma unroll
            for (int o = 0; o < 4; o++) {
                if (o <= r && r <= o + 3) {
                    int k = r - o;
#pragma unroll
                    for (int e = 0; e < 8; e++)
                        acc[o][e] = fmaf(wv[e][k], rowf[e], acc[o][e]);
                }
            }
        }
    }
#pragma unroll
    for (int o = 0; o < 4; o++) {
        short out[8];
#pragma unroll
        for (int e = 0; e < 8; e++) {
            float sg = 1.f / (1.f + expf(-acc[o][e]));
            out[e] = f2bs(acc[o][e] * sg);
        }
        *(bf16x8*)(xBC + ((size_t)b * TT + tb + o) * CD + c) = *(bf16x8*)out;
    }
}

// ---------------- Kernel 5a: SSD chunk reduce (prefix fused into P0; 3 barriers/fc) ----------------
__global__ __launch_bounds__(256, 2) void scan_reduce_ssd(const short* __restrict__ xBC,
                                                          const float* __restrict__ dtg,
                                                          const float* __restrict__ A_log,
                                                          float* __restrict__ S,
                                                          float* __restrict__ P) {
    int tid = threadIdx.x;
    int wave = tid >> 6, lane = tid & 63;
    int l4 = lane >> 4, l16 = lane & 15;
    int c = blockIdx.x, hh = blockIdx.y, b = blockIdx.z;
    int cbase = c * CL;

    __shared__ __align__(16) short BtL[64][136];
    __shared__ __align__(16) short XdL[64][72];
    __shared__ __align__(16) float sdt[64];
    __shared__ __align__(16) float sL[64];
    __shared__ __align__(16) float sW[64];

    f32x4 acc_h[2][4];
#pragma unroll
    for (int i = 0; i < 2; i++)
#pragma unroll
        for (int pq = 0; pq < 4; pq++) acc_h[i][pq] = (f32x4){0.f, 0.f, 0.f, 0.f};
    float Lsum = 0.f;

    float expA = expf(A_log[hh]);
    const float* dtb = dtg + (size_t)b * TT * NH + hh;
    const short* xb = xBC + (size_t)b * TT * CD;

#pragma unroll 1
    for (int f = 0; f < FPC; f++) {
        int t0 = cbase + f * FL;
        // P0: wave0 computes dt + decay prefix; all waves stage B rows.
        if (tid < 64) {
            float val = dtb[(size_t)(t0 + tid) * NH];
            sdt[tid] = val;
            float v = -expA * val;
#pragma unroll
            for (int off = 1; off < 64; off <<= 1) {
                float u = __shfl_up(v, off);
                if (lane >= off) v += u;
            }
            sL[tid] = v;
            float lt = __shfl(v, 63);
            sW[tid] = expf(lt - v);
        }
        {
            int r = tid >> 2, q = tid & 3;
            const short* bs = xb + (size_t)(t0 + r) * CD + DI + q * 32;
#pragma unroll
            for (int j = 0; j < 4; j++)
                *(bf16x8*)&BtL[r][q * 32 + j * 8] = *(const bf16x8*)(bs + j * 8);
        }
        __syncthreads();
        // P2: stage Xd with decay weight folded in.
        {
            int s = tid & 63, pg2 = tid >> 6;
            const short* xs = xb + (size_t)(t0 + s) * CD + hh * HD + pg2 * 16;
            float dw = sdt[s] * sW[s];
            bf16x8 v0 = *(const bf16x8*)xs;
            bf16x8 v1 = *(const bf16x8*)(xs + 8);
#pragma unroll
            for (int j = 0; j < 8; j++) XdL[pg2 * 16 + j][s] = f2bs(b2f(v0[j]) * dw);
#pragma unroll
            for (int j = 0; j < 8; j++) XdL[pg2 * 16 + 8 + j][s] = f2bs(b2f(v1[j]) * dw);
        }
        __syncthreads();
        float Lft = sL[63];
        float Pf = expf(Lft);
        Lsum += Lft;
#pragma unroll
        for (int i = 0; i < 2; i++)
#pragma unroll
            for (int pq = 0; pq < 4; pq++) acc_h[i][pq] *= Pf;
#pragma unroll
        for (int ks = 0; ks < 2; ks++) {
            bf16x8 af2[2], bfw[4];
#pragma unroll
            for (int i = 0; i < 2; i++) {
                int nrow = wave * 32 + i * 16 + l16;
                short e[8];
#pragma unroll
                for (int j = 0; j < 8; j++)
                    e[j] = BtL[ks * 32 + l4 * 8 + j][nrow];
                af2[i] = *(bf16x8*)e;
            }
#pragma unroll
            for (int pq = 0; pq < 4; pq++)
                bfw[pq] = *(const bf16x8*)&XdL[pq * 16 + l16][ks * 32 + l4 * 8];
#pragma unroll
            for (int i = 0; i < 2; i++)
#pragma unroll
                for (int pq = 0; pq < 4; pq++)
                    acc_h[i][pq] = __builtin_amdgcn_mfma_f32_16x16x32_bf16(af2[i], bfw[pq], acc_h[i][pq], 0, 0, 0);
        }
        __syncthreads();
    }

    float* Sp = S + (size_t)c * SELEMS + ((size_t)(b * NH + hh) * HD) * DSTATE;
#pragma unroll
    for (int i = 0; i < 2; i++)
#pragma unroll
        for (int pq = 0; pq < 4; pq++) {
            int nb = wave * 32 + i * 16 + (l4 << 2);
            int p = pq * 16 + l16;
            *(f32x4*)(Sp + (size_t)p * DSTATE + nb) = acc_h[i][pq];
        }
    if (tid == 0) P[(c * BB + b) * NH + hh] = expf(Lsum);
}

// ---------------- Kernel 5b: sequential chunk combine ----------------
__global__ __launch_bounds__(256) void scan_combine_kernel(const float* __restrict__ h0,
                                                           const float* __restrict__ P,
                                                           float* __restrict__ S,
                                                           float* __restrict__ hT) {
    size_t tid = (size_t)blockIdx.x * 256 + threadIdx.x;
    int hh = (int)((tid >> 13) & 31);
    int b = (int)(tid >> 18);
    float h = h0[tid];
#pragma unroll
    for (int c = 0; c < NC; c++) {
        float s = S[(size_t)c * SELEMS + tid];
        S[(size_t)c * SELEMS + tid] = h;
        h = fmaf(P[(c * BB + b) * NH + hh], h, s);
    }
    hT[tid] = h;
}

// ---------------- Kernel 5c: SSD emit (prefix fused into P0; 4 barriers/fc) ----------------
__global__ __launch_bounds__(256, 2) void scan_emit_ssd(const short* __restrict__ xBC,
                                                        const float* __restrict__ dtg,
                                                        const float* __restrict__ A_log,
                                                        const float* __restrict__ S,
                                                        const float* __restrict__ Dp,
                                                        short* __restrict__ ybq) {
    int tid = threadIdx.x;
    int wave = tid >> 6, lane = tid & 63;
    int l4 = lane >> 4, l16 = lane & 15;
    int c = blockIdx.x, hh = blockIdx.y, b = blockIdx.z;
    int cbase = c * CL;

    __shared__ __align__(16) short CtL[64][136];
    __shared__ __align__(16) short BtL[64][136];
    __shared__ __align__(16) short hL[64][132];
    __shared__ __align__(16) short XdL[64][72];
    __shared__ __align__(16) short XdwL[64][72];
    __shared__ __align__(16) short ML[64][72];
    __shared__ __align__(16) float sdt[64];
    __shared__ __align__(16) float sL[64];
    __shared__ __align__(16) float sW[64];
    __shared__ __align__(16) float sRdt[64];

    f32x4 acc_h[2][4];
    {
        const float* Sp = S + (size_t)c * SELEMS + ((size_t)(b * NH + hh) * HD) * DSTATE;
#pragma unroll
        for (int i = 0; i < 2; i++)
#pragma unroll
            for (int pq = 0; pq < 4; pq++) {
                int nb = wave * 32 + i * 16 + (l4 << 2);
                int p = pq * 16 + l16;
                acc_h[i][pq] = *(const f32x4*)(Sp + (size_t)p * DSTATE + nb);
            }
    }

    float expA = expf(A_log[hh]);
    float Dh = Dp[hh];
    const float* dtb = dtg + (size_t)b * TT * NH + hh;
    const short* xb = xBC + (size_t)b * TT * CD;
    short* yb = ybq + (size_t)b * TT * DI + hh * HD;

    int tg = wave >> 1;
    int sg = wave & 1;

#pragma unroll 1
    for (int f = 0; f < FPC; f++) {
        int t0 = cbase + f * FL;

        // P0: wave0 computes dt + decay prefix; all waves stage Ct/Bt/hL.
        if (tid < 64) {
            float val = dtb[(size_t)(t0 + tid) * NH];
            sdt[tid] = val;
            float v = -expA * val;
#pragma unroll
            for (int off = 1; off < 64; off <<= 1) {
                float u = __shfl_up(v, off);
                if (lane >= off) v += u;
            }
            sL[tid] = v;
            float lt = __shfl(v, 63);
            sW[tid] = expf(lt - v);
            sRdt[tid] = 1.f / val;
        }
        {
            int r = tid >> 2, q = tid & 3;
            const short* cs = xb + (size_t)(t0 + r) * CD + DI + DSTATE + q * 32;
            const short* bs = xb + (size_t)(t0 + r) * CD + DI + q * 32;
#pragma unroll
            for (int j = 0; j < 4; j++) {
                *(bf16x8*)&CtL[r][q * 32 + j * 8] = *(const bf16x8*)(cs + j * 8);
                *(bf16x8*)&BtL[r][q * 32 + j * 8] = *(const bf16x8*)(bs + j * 8);
            }
        }
#pragma unroll
        for (int i = 0; i < 2; i++)
#pragma unroll
            for (int pq = 0; pq < 4; pq++) {
                int nb = wave * 32 + i * 16 + (l4 << 2);
                int p = pq * 16 + l16;
                *(short2*)&hL[p][nb] = make_short2(f2bs(acc_h[i][pq][0]), f2bs(acc_h[i][pq][1]));
                *(short2*)&hL[p][nb + 2] = make_short2(f2bs(acc_h[i][pq][2]), f2bs(acc_h[i][pq][3]));
            }
        __syncthreads();

        // P2: stage XdL (plain) and XdwL (decay-weighted).
        {
            int s = tid & 63, pg = tid >> 6;
            const short* xs = xb + (size_t)(t0 + s) * CD + hh * HD + pg * 16;
            float dts = sdt[s];
            float dw = dts * sW[s];
            bf16x8 v0 = *(const bf16x8*)xs;
            bf16x8 v1 = *(const bf16x8*)(xs + 8);
#pragma unroll
            for (int j = 0; j < 8; j++) {
                float xv = b2f(v0[j]);
                XdL[pg * 16 + j][s] = f2bs(xv * dts);
                XdwL[pg * 16 + j][s] = f2bs(xv * dw);
            }
#pragma unroll
            for (int j = 0; j < 8; j++) {
                float xv = b2f(v1[j]);
                XdL[pg * 16 + 8 + j][s] = f2bs(xv * dts);
                XdwL[pg * 16 + 8 + j][s] = f2bs(xv * dw);
            }
        }
        __syncthreads();

        // P3: G = C@B^T, mask+decay -> ML.
        {
            f32x4 g[2][2] = {};
#pragma unroll
            for (int ks = 0; ks < 4; ks++) {
                bf16x8 af[2], bfm[2];
#pragma unroll
                for (int i = 0; i < 2; i++)
                    af[i] = *(const bf16x8*)&CtL[tg * 32 + i * 16 + l16][ks * 32 + l4 * 8];
#pragma unroll
                for (int n = 0; n < 2; n++)
                    bfm[n] = *(const bf16x8*)&BtL[sg * 32 + n * 16 + l16][ks * 32 + l4 * 8];
#pragma unroll
                for (int i = 0; i < 2; i++)
#pragma unroll
                    for (int n = 0; n < 2; n++)
                        g[i][n] = __builtin_amdgcn_mfma_f32_16x16x32_bf16(af[i], bfm[n], g[i][n], 0, 0, 0);
            }
#pragma unroll
            for (int i = 0; i < 2; i++) {
                int tb2 = tg * 32 + i * 16 + (l4 << 2);
                float4 Lt = *(const float4*)&sL[tb2];
                float Ltr[4] = {Lt.x, Lt.y, Lt.z, Lt.w};
#pragma unroll
                for (int n = 0; n < 2; n++) {
                    int sE = sg * 32 + n * 16 + l16;
                    float Ls = sL[sE];
#pragma unroll
                    for (int r2 = 0; r2 < 4; r2++) {
                        float m = (sE <= tb2 + r2) ? g[i][n][r2] * expf(Ltr[r2] - Ls) : 0.f;
                        ML[tb2 + r2][sE] = f2bs(m);
                    }
                }
            }
        }
        __syncthreads();

        // P4: Y = M@Xd + exp(L)*(C@h_in) + Dh*x ; state update with XdwL.
        {
            f32x4 ay[2][2] = {};
            f32x4 ai[2][2] = {};
#pragma unroll
            for (int ks = 0; ks < 2; ks++) {
                bf16x8 af[2], bfp[2];
#pragma unroll
                for (int i = 0; i < 2; i++)
                    af[i] = *(const bf16x8*)&ML[tg * 32 + i * 16 + l16][ks * 32 + l4 * 8];
#pragma unroll
                for (int n = 0; n < 2; n++)
                    bfp[n] = *(const bf16x8*)&XdL[sg * 32 + n * 16 + l16][ks * 32 + l4 * 8];
#pragma unroll
                for (int i = 0; i < 2; i++)
#pragma unroll
                    for (int n = 0; n < 2; n++)
                        ay[i][n] = __builtin_amdgcn_mfma_f32_16x16x32_bf16(af[i], bfp[n], ay[i][n], 0, 0, 0);
            }
#pragma unroll
            for (int ks = 0; ks < 4; ks++) {
                bf16x8 af[2], bfh[2];
#pragma unroll
                for (int i = 0; i < 2; i++)
                    af[i] = *(const bf16x8*)&CtL[tg * 32 + i * 16 + l16][ks * 32 + l4 * 8];
#pragma unroll
                for (int n = 0; n < 2; n++) {
                    int prow = sg * 32 + n * 16 + l16;
                    int kb = ks * 32 + l4 * 8;
                    union { bf16x8 v; uint2 u2[2]; } hu;
                    hu.u2[0] = *(const uint2*)&hL[prow][kb];
                    hu.u2[1] = *(const uint2*)&hL[prow][kb + 4];
                    bfh[n] = hu.v;
                }
#pragma unroll
                for (int i = 0; i < 2; i++)
#pragma unroll
                    for (int n = 0; n < 2; n++)
                        ai[i][n] = __builtin_amdgcn_mfma_f32_16x16x32_bf16(af[i], bfh[n], ai[i][n], 0, 0, 0);
            }
            float Lft = sL[63];
#pragma unroll
            for (int i = 0; i < 2; i++) {
                int tb2 = tg * 32 + i * 16 + (l4 << 2);
                float4 Lt = *(const float4*)&sL[tb2];
                float4 Rt = *(const float4*)&sRdt[tb2];
                float Ltr[4] = {Lt.x, Lt.y, Lt.z, Lt.w};
                float Rtr[4] = {Rt.x, Rt.y, Rt.z, Rt.w};
#pragma unroll
                for (int n = 0; n < 2; n++) {
                    int p = sg * 32 + n * 16 + l16;
#pragma unroll
                    for (int r2 = 0; r2 < 4; r2++) {
                        float xv = b2f(XdL[p][tb2 + r2]) * Rtr[r2];
                        float yv = ay[i][n][r2] + expf(Ltr[r2]) * ai[i][n][r2] + Dh * xv;
                        yb[(size_t)(t0 + tb2 + r2) * DI + p] = f2bs(yv);
                    }
                }
            }
            float Pf = expf(Lft);
#pragma unroll
            for (int i = 0; i < 2; i++)
#pragma unroll
                for (int pq = 0; pq < 4; pq++)
                    acc_h[i][pq] *= Pf;
#pragma unroll
            for (int ks = 0; ks < 2; ks++) {
                bf16x8 af2[2], bfw[4];
#pragma unroll
                for (int i = 0; i < 2; i++) {
                    int nrow = wave * 32 + i * 16 + l16;
                    short e[8];
#pragma unroll
                    for (int j = 0; j < 8; j++)
                        e[j] = BtL[ks * 32 + l4 * 8 + j][nrow];
                    af2[i] = *(bf16x8*)e;
                }
#pragma unroll
                for (int pq = 0; pq < 4; pq++)
                    bfw[pq] = *(const bf16x8*)&XdwL[pq * 16 + l16][ks * 32 + l4 * 8];
#pragma unroll
                for (int i = 0; i < 2; i++)
#pragma unroll
                    for (int pq = 0; pq < 4; pq++)
                        acc_h[i][pq] = __builtin_amdgcn_mfma_f32_16x16x32_bf16(af2[i], bfw[pq], acc_h[i][pq], 0, 0, 0);
            }
        }
        __syncthreads();
    }
}

// ---------------- Kernel 6: gating + RMSNorm (bf16 y, bf16 z) -> bf16 g ----------------
__global__ __launch_bounds__(256) void gate_rms_kernel(const short* __restrict__ ybq,
                                                       const short* __restrict__ zx,
                                                       const float* __restrict__ rw,
                                                       __hip_bfloat16* __restrict__ gq) {
    int m = blockIdx.x;
    int tid = threadIdx.x;
    const short* yr = ybq + (size_t)m * DI;
    const short* zr = zx + (size_t)m * DIP;
    int base = tid * 8;
    float gv[8];
    float ss = 0.f;
    bf16x8 yv8 = *(const bf16x8*)(yr + base);
    bf16x8 zv8 = *(const bf16x8*)(zr + base);
#pragma unroll
    for (int i = 0; i < 8; i++) {
        float y = b2f(yv8[i]);
        float z = b2f(zv8[i]);
        float sg = 1.f / (1.f + expf(-z));
        float gg = y * z * sg;
        gv[i] = gg;
        ss += gg * gg;
    }
#pragma unroll
    for (int off = 1; off < 64; off <<= 1) ss += __shfl_xor(ss, off);
    __shared__ float red[4];
    int w = tid >> 6;
    if ((tid & 63) == 0) red[w] = ss;
    __syncthreads();
    float tot = red[0] + red[1] + red[2] + red[3];
    float r = rsqrtf(tot * (1.f / DI) + 1e-5f);
#pragma unroll
    for (int i = 0; i < 8; i += 2) {
        __hip_bfloat162 p;
        p.x = __float2bfloat16(gv[i] * r * rw[base + i]);
        p.y = __float2bfloat16(gv[i + 1] * r * rw[base + i + 1]);
        *(__hip_bfloat162*)(gq + (size_t)m * DI + base + i) = p;
    }
}

// ---------------- Kernel 7: GEMM2 bf16 MFMA (T2 swizzle + T1 remap m-inner, transposed store) ----------------
__global__ __launch_bounds__(256) void gemm2_mfma(const __hip_bfloat16* __restrict__ gq,
                                                  const __hip_bfloat16* __restrict__ Wob,
                                                  float* __restrict__ out) {
    __shared__ short As[128][64];
    __shared__ short Bs[128][64];
    int tid = threadIdx.x;
    int lane = tid & 63;
    int wave = tid >> 6;
    int wr = wave >> 1, wc = wave & 1;
    int id = blockIdx.x;
    int xcd = id & 7;
    int pos = id >> 3;
    int j0 = (pos >> 3) * 128;
    int m0 = (xcd * 8 + (pos & 7)) * 128;
    int srow = tid >> 3;
    int skc = (((tid & 7) ^ ((tid >> 3) & 7)) * 8);

    f32x4 acc[4][4] = {};

    for (int k0 = 0; k0 < DI; k0 += 64) {
        __syncthreads();
#pragma unroll
        for (int q = 0; q < 4; q++) {
            gload16(gq + (size_t)(m0 + q * 32 + srow) * DI + k0 + skc,
                    ((short*)As) + q * 2048 + wave * 512);
            gload16(Wob + (size_t)(j0 + q * 32 + srow) * DI + k0 + skc,
                    ((short*)Bs) + q * 2048 + wave * 512);
        }
        asm volatile("s_waitcnt vmcnt(0)" ::: "memory");
        __syncthreads();
#pragma unroll
        for (int ks = 0; ks < 2; ks++) {
            int pch = (((ks * 4) + (lane >> 4)) ^ (lane & 7)) * 8;
            bf16x8 af[4], bfr[4];
#pragma unroll
            for (int i = 0; i < 4; i++)
                af[i] = *(const bf16x8*)&As[wr * 64 + i * 16 + (lane & 15)][pch];
#pragma unroll
            for (int n = 0; n < 4; n++)
                bfr[n] = *(const bf16x8*)&Bs[wc * 64 + n * 16 + (lane & 15)][pch];
#pragma unroll
            for (int i = 0; i < 4; i++)
#pragma unroll
                for (int n = 0; n < 4; n++)
                    acc[i][n] = __builtin_amdgcn_mfma_f32_16x16x32_bf16(af[i], bfr[n], acc[i][n], 0, 0, 0);
        }
    }
#pragma unroll
    for (int i = 0; i < 4; i++) {
        int m = m0 + wr * 64 + i * 16 + ((lane >> 4) << 2);
        int b = m >> 12;
        int t = m & 4095;
#pragma unroll
        for (int n = 0; n < 4; n++) {
            int j = j0 + wc * 64 + n * 16 + (lane & 15);
            *(f32x4*)(out + (size_t)b * DM * TT + (size_t)j * TT + t) = acc[i][n];
        }
    }
}

extern "C" void kernel_launch(void* const* d_in, const int* in_sizes, int n_in,
                              void* d_out, int out_size, void* d_ws, size_t ws_size,
                              hipStream_t stream) {
    const float* x       = (const float*)d_in[0];
    const float* ln_w    = (const float*)d_in[1];
    const float* ln_b    = (const float*)d_in[2];
    const float* W_in    = (const float*)d_in[3];
    const float* conv_w  = (const float*)d_in[4];
    const float* conv_b  = (const float*)d_in[5];
    const float* dt_bias = (const float*)d_in[6];
    const float* A_log   = (const float*)d_in[7];
    const float* Dp      = (const float*)d_in[8];
    const float* rms_w   = (const float*)d_in[9];
    const float* W_out   = (const float*)d_in[10];
    const float* h0      = (const float*)d_in[11];

    float* out = (float*)d_out;
    float* hT = out + (size_t)BB * DM * TT;

    char* ws = (char*)d_ws;
    // Workspace layout — total 211,355,648 bytes (under proven 238 MB):
    float* mu   = (float*)(ws + 0);                       //      32,768
    float* rs   = (float*)(ws + 32768);                   //      32,768
    short* zxq  = (short*)(ws + 65536);                   //  71,827,456  (B,T,4384) bf16
    short* xBCq = (short*)(ws + 71892992);                //  37,748,736  (B,T,2304) bf16
    __hip_bfloat16* gq  = (__hip_bfloat16*)(ws + 71892992);        // overlays xBC (post-emit)
    __hip_bfloat16* Wob = (__hip_bfloat16*)(ws + 105447424);       // overlays xBC tail
    short* ybq  = (short*)(ws + 109641728);               //  33,554,432  (B,T,2048) bf16
    __hip_bfloat16* Wb  = (__hip_bfloat16*)(ws + 109641728);       // overlays ybq (pre-scan)
    float* dtv  = (float*)(ws + 176750592);               //   1,048,576
    __hip_bfloat16* xnb = (__hip_bfloat16*)(ws + 177799168);       //  16,777,216 (shares S)
    float* S    = (float*)(ws + 177799168);
    float* P    = (float*)(ws + 194576384);               //       2,048
    float* dpart = (float*)(ws + 194578432);              //  16,777,216  (KSPLIT,B*T,NH)

    ln_stats_kernel<<<(TT / 32) * BB, 256, 0, stream>>>(x, mu, rs);
    xn_kernel<<<dim3(TT / 64, DM / 64, BB), 256, 0, stream>>>(x, mu, rs, ln_w, ln_b, xnb);
    cvt_pad_kernel<<<(NP1 * DM) / 1024, 256, 0, stream>>>(W_in, Wb, DIP * DM, NP1 * DM);
    gemm1_mfma<<<(NP1 / 128) * ((BB * TT) / 128), 256, 0, stream>>>(Wb, xnb, zxq);
    gemm1_strip<<<dim3(KSPLIT, (BB * TT) / 64), 256, 0, stream>>>(x, mu, rs, ln_w, ln_b, W_in, dpart);
    dt_reduce_kernel<<<(BB * TT * NH) / 256, 256, 0, stream>>>(dpart, dt_bias, dtv);
    conv_kernel<<<(BB * (TT / 4) * (CD / 8)) / 256, 256, 0, stream>>>(zxq, conv_w, conv_b, xBCq);
    scan_reduce_ssd<<<dim3(NC, NH, BB), 256, 0, stream>>>(xBCq, dtv, A_log, S, P);
    scan_combine_kernel<<<(int)(SELEMS / 256), 256, 0, stream>>>(h0, P, S, hT);
    scan_emit_ssd<<<dim3(NC, NH, BB), 256, 0, stream>>>(xBCq, dtv, A_log, S, Dp, ybq);
    cvt_pad_kernel<<<(DM * DI) / 1024, 256, 0, stream>>>(W_out, Wob, DM * DI, DM * DI);
    gate_rms_kernel<<<BB * TT, 256, 0, stream>>>(ybq, zxq, rms_w, gq);
    gemm2_mfma<<<((BB * TT) / 128) * (DM / 128), 256, 0, stream>>>(gq, Wob, out);
}